// Round 1
// baseline (3773.679 us; speedup 1.0000x reference)
//
#include <hip/hip_runtime.h>
#include <hip/hip_bf16.h>
#include <math.h>

#define NB 32
#define NS 512
#define NH 1024
#define NT 37
#define NLP 39
#define NM (NB*NS)   // 16384

__device__ __forceinline__ float bf2f(unsigned short u) {
    unsigned int x = ((unsigned int)u) << 16;
    float f;
    __builtin_memcpy(&f, &x, 4);
    return f;
}
__device__ __forceinline__ unsigned short f2bf(float f) {
    __hip_bfloat16 hb = __float2bfloat16(f);
    unsigned short u;
    __builtin_memcpy(&u, &hb, 2);
    return u;
}

// ---------------------------------------------------------------------------
// Kernel A: scores = h @ bio^T / sqrt(H); attn = softmax(scores); aware = attn @ bio
// 32 rows per block, 256 threads.
// ---------------------------------------------------------------------------
__global__ __launch_bounds__(256) void kA(const float* __restrict__ h,
                                          const float* __restrict__ bio,
                                          unsigned short* __restrict__ aware) {
    __shared__ float bio_t[37 * 66];
    __shared__ float h_t[32 * 66];
    __shared__ float Sm[32 * 40];

    const int tid = threadIdx.x;
    const int m0 = blockIdx.x * 32;
    const int r = tid >> 3;    // 0..31 row within tile
    const int tg = tid & 7;    // t-group

    float acc[5] = {0.f, 0.f, 0.f, 0.f, 0.f};

    for (int k0 = 0; k0 < NH; k0 += 64) {
        __syncthreads();
        for (int idx = tid; idx < 37 * 64; idx += 256) {
            int t = idx >> 6, kk = idx & 63;
            bio_t[t * 66 + kk] = bio[t * NH + k0 + kk];
        }
        for (int idx = tid; idx < 32 * 64; idx += 256) {
            int rr = idx >> 6, kk = idx & 63;
            h_t[rr * 66 + kk] = h[(size_t)(m0 + rr) * NH + k0 + kk];
        }
        __syncthreads();
        for (int kk = 0; kk < 64; ++kk) {
            float hv = h_t[r * 66 + kk];
#pragma unroll
            for (int j = 0; j < 5; ++j) {
                int t = tg + 8 * j;
                if (t < 37) acc[j] = fmaf(hv, bio_t[t * 66 + kk], acc[j]);
            }
        }
    }
#pragma unroll
    for (int j = 0; j < 5; ++j) {
        int t = tg + 8 * j;
        if (t < 37) Sm[r * 40 + t] = acc[j] * 0.03125f;  // 1/sqrt(1024)
    }
    __syncthreads();
    if (tid < 32) {
        float mx = -1e30f;
        for (int t = 0; t < 37; ++t) mx = fmaxf(mx, Sm[tid * 40 + t]);
        float s = 0.f;
        for (int t = 0; t < 37; ++t) s += __expf(Sm[tid * 40 + t] - mx);
        float inv = 1.0f / s;
        for (int t = 0; t < 37; ++t) Sm[tid * 40 + t] = __expf(Sm[tid * 40 + t] - mx) * inv;
    }
    __syncthreads();

    // phase 3: aware = attn @ bio  (32 x 1024)
    const int ty = tid >> 6;     // 0..3
    const int lane = tid & 63;
    for (int rr = ty; rr < 32; rr += 4) {
        for (int c4 = lane; c4 < 256; c4 += 64) {
            float4 av = make_float4(0.f, 0.f, 0.f, 0.f);
            for (int t = 0; t < 37; ++t) {
                float a = Sm[rr * 40 + t];
                const float4 bv = reinterpret_cast<const float4*>(bio)[t * 256 + c4];
                av.x = fmaf(a, bv.x, av.x);
                av.y = fmaf(a, bv.y, av.y);
                av.z = fmaf(a, bv.z, av.z);
                av.w = fmaf(a, bv.w, av.w);
            }
            size_t row = (size_t)(m0 + rr);
            ushort4 pk;
            pk.x = f2bf(av.x); pk.y = f2bf(av.y); pk.z = f2bf(av.z); pk.w = f2bf(av.w);
            *reinterpret_cast<ushort4*>(aware + row * NH + c4 * 4) = pk;
        }
    }
}

// ---------------------------------------------------------------------------
// Kernel B: x2 = gelu([h, aware, h*aware] @ W_cat + b_cat)   fp32 tiled GEMM
// 64x64 tile, 256 threads (16x16, 4x4 micro-tile), K = 3072 virtual.
// ---------------------------------------------------------------------------
__global__ __launch_bounds__(256) void kB(const float* __restrict__ h,
                                          const unsigned short* __restrict__ aware,
                                          const float* __restrict__ Wcat,
                                          const float* __restrict__ bcat,
                                          unsigned short* __restrict__ x2) {
    __shared__ float As[32 * 72];  // [kk][m], padded
    __shared__ float Bs[32 * 64];  // [kk][n]

    const int tid = threadIdx.x;
    const int m0 = blockIdx.y * 64;
    const int n0 = blockIdx.x * 64;
    const int tm = tid >> 4, tn = tid & 15;

    float acc[4][4] = {};

    for (int kt = 0; kt < 3072; kt += 32) {
        const int region = kt >> 10;
        const int kbase = kt & 1023;
        __syncthreads();
#pragma unroll
        for (int i = 0; i < 8; ++i) {
            int idx = tid + i * 256;
            int rr = idx >> 5, c = idx & 31;
            size_t row = (size_t)(m0 + rr);
            int gk = kbase + c;
            float v;
            if (region == 0)      v = h[row * NH + gk];
            else if (region == 1) v = bf2f(aware[row * NH + gk]);
            else                  v = h[row * NH + gk] * bf2f(aware[row * NH + gk]);
            As[c * 72 + rr] = v;
        }
#pragma unroll
        for (int i = 0; i < 8; ++i) {
            int idx = tid + i * 256;
            int kk = idx >> 6, n = idx & 63;
            Bs[kk * 64 + n] = Wcat[(size_t)(kt + kk) * NH + n0 + n];
        }
        __syncthreads();
#pragma unroll
        for (int kk = 0; kk < 32; ++kk) {
            float4 a4 = *reinterpret_cast<const float4*>(&As[kk * 72 + tm * 4]);
            float4 b4 = *reinterpret_cast<const float4*>(&Bs[kk * 64 + tn * 4]);
            float aa[4] = {a4.x, a4.y, a4.z, a4.w};
            float bb[4] = {b4.x, b4.y, b4.z, b4.w};
#pragma unroll
            for (int i = 0; i < 4; ++i)
#pragma unroll
                for (int j = 0; j < 4; ++j)
                    acc[i][j] = fmaf(aa[i], bb[j], acc[i][j]);
        }
    }
#pragma unroll
    for (int i = 0; i < 4; ++i) {
        size_t row = (size_t)(m0 + tm * 4 + i);
#pragma unroll
        for (int j = 0; j < 4; ++j) {
            int n = n0 + tn * 4 + j;
            float x = acc[i][j] + bcat[n];
            float g = 0.5f * x * (1.0f + erff(x * 0.70710678118654752f));
            x2[row * NH + n] = f2bf(g);
        }
    }
}

// ---------------------------------------------------------------------------
// Kernel C: logits = x2 @ W_crf + b_crf; ner_scores = [logits, -10000, -10000]
// 32 rows per block, 256 threads.
// ---------------------------------------------------------------------------
__global__ __launch_bounds__(256) void kC(const unsigned short* __restrict__ x2,
                                          const float* __restrict__ Wcrf,
                                          const float* __restrict__ bcrf,
                                          float* __restrict__ out) {
    __shared__ unsigned short xt[32 * 66];
    __shared__ float Wt[64 * 37];

    const int tid = threadIdx.x;
    const int m0 = blockIdx.x * 32;
    const int r = tid >> 3, tg = tid & 7;

    float acc[5] = {0.f, 0.f, 0.f, 0.f, 0.f};

    for (int k0 = 0; k0 < NH; k0 += 64) {
        __syncthreads();
        for (int idx = tid; idx < 32 * 64; idx += 256) {
            int rr = idx >> 6, kk = idx & 63;
            xt[rr * 66 + kk] = x2[(size_t)(m0 + rr) * NH + k0 + kk];
        }
        for (int idx = tid; idx < 64 * 37; idx += 256) {
            int kk = idx / 37, t = idx - kk * 37;
            Wt[kk * 37 + t] = Wcrf[(size_t)(k0 + kk) * NT + t];
        }
        __syncthreads();
        for (int kk = 0; kk < 64; ++kk) {
            float xv = bf2f(xt[r * 66 + kk]);
#pragma unroll
            for (int j = 0; j < 5; ++j) {
                int t = tg + 8 * j;
                if (t < 37) acc[j] = fmaf(xv, Wt[kk * 37 + t], acc[j]);
            }
        }
    }
    size_t row = (size_t)(m0 + r);
#pragma unroll
    for (int j = 0; j < 5; ++j) {
        int t = tg + 8 * j;
        if (t < 37)      out[row * NLP + t] = acc[j] + bcrf[t];
        else if (t < 39) out[row * NLP + t] = -10000.0f;
    }
}

// ---------------------------------------------------------------------------
// Kernel D: CRF log-likelihood. One wave (64 threads) per batch element.
// lane = 'to' label (0..38 active). alpha in LDS, trans row in registers.
// ---------------------------------------------------------------------------
__global__ __launch_bounds__(64) void kD(const float* __restrict__ scores,
                                         const int* __restrict__ labels,
                                         const int* __restrict__ lens,
                                         const float* __restrict__ trans,
                                         float* __restrict__ loss) {
    __shared__ float trL[39 * 41];
    __shared__ float alphaS[40];

    const int b = blockIdx.x;
    const int lane = threadIdx.x;

    for (int idx = lane; idx < 39 * 39; idx += 64) {
        int to = idx / 39, f = idx - to * 39;
        trL[to * 41 + f] = trans[idx];
    }
    if (lane < 39) alphaS[lane] = (lane == 37) ? 0.0f : -100.0f;
    __syncthreads();

    const int len = lens[b];

    // gold path score: unary + transitions
    float g = 0.0f;
    for (int t = lane; t < len; t += 64) {
        int lab = labels[b * NS + t];
        g += scores[((size_t)(b * NS + t)) * NLP + lab];
    }
    for (int i = lane; i <= len; i += 64) {
        int frm = (i == 0) ? 37 : labels[b * NS + i - 1];
        int to  = (i == len) ? 38 : labels[b * NS + i];
        g += trL[to * 41 + frm];
    }
#pragma unroll
    for (int off = 32; off > 0; off >>= 1) g += __shfl_xor(g, off, 64);

    // cache this lane's transition row trans[to=lane][frm=0..38]
    const int myrow = (lane < 39) ? lane : 0;
    float tr[39];
#pragma unroll
    for (int f = 0; f < 39; ++f) tr[f] = trL[myrow * 41 + f];

    // forward recursion
    for (int t = 0; t < len; ++t) {
        float logit = (lane < 39) ? scores[((size_t)(b * NS + t)) * NLP + lane] : -1e30f;
        float v[39];
#pragma unroll
        for (int f = 0; f < 39; ++f) v[f] = alphaS[f] + tr[f];
        // tree max
        float t0[20];
#pragma unroll
        for (int i = 0; i < 19; ++i) t0[i] = fmaxf(v[2 * i], v[2 * i + 1]);
        t0[19] = v[38];
        float t1[10];
#pragma unroll
        for (int i = 0; i < 10; ++i) t1[i] = fmaxf(t0[2 * i], t0[2 * i + 1]);
        float t2[5];
#pragma unroll
        for (int i = 0; i < 5; ++i) t2[i] = fmaxf(t1[2 * i], t1[2 * i + 1]);
        float m = fmaxf(fmaxf(fmaxf(t2[0], t2[1]), fmaxf(t2[2], t2[3])), t2[4]);
        // tree sum of exp
        float e[39];
#pragma unroll
        for (int f = 0; f < 39; ++f) e[f] = __expf(v[f] - m);
        float s0[20];
#pragma unroll
        for (int i = 0; i < 19; ++i) s0[i] = e[2 * i] + e[2 * i + 1];
        s0[19] = e[38];
        float s1[10];
#pragma unroll
        for (int i = 0; i < 10; ++i) s1[i] = s0[2 * i] + s0[2 * i + 1];
        float s2[5];
#pragma unroll
        for (int i = 0; i < 5; ++i) s2[i] = s1[2 * i] + s1[2 * i + 1];
        float ssum = ((s2[0] + s2[1]) + (s2[2] + s2[3])) + s2[4];

        float anew = logit + m + __logf(ssum);
        __syncthreads();
        if (lane < 39) alphaS[lane] = anew;
        __syncthreads();
    }

    float aend = (lane < 39) ? alphaS[lane] + trL[38 * 41 + lane] : -1e30f;
    float mx = aend;
#pragma unroll
    for (int off = 32; off > 0; off >>= 1) mx = fmaxf(mx, __shfl_xor(mx, off, 64));
    float es = (lane < 39) ? __expf(aend - mx) : 0.0f;
#pragma unroll
    for (int off = 32; off > 0; off >>= 1) es += __shfl_xor(es, off, 64);
    float norm = mx + __logf(es);

    if (lane == 0) loss[b] = g - norm;
}

// ---------------------------------------------------------------------------
extern "C" void kernel_launch(void* const* d_in, const int* in_sizes, int n_in,
                              void* d_out, int out_size, void* d_ws, size_t ws_size,
                              hipStream_t stream) {
    const float* h      = (const float*)d_in[0];
    // d_in[1] = token_masks (unused; all ones semantics handled via token_nums)
    const int* token_nums = (const int*)d_in[2];
    const int* labels     = (const int*)d_in[3];
    const float* bio    = (const float*)d_in[4];
    const float* Wcat   = (const float*)d_in[5];
    const float* bcat   = (const float*)d_in[6];
    const float* Wcrf   = (const float*)d_in[7];
    const float* bcrf   = (const float*)d_in[8];
    const float* trans  = (const float*)d_in[9];

    float* out = (float*)d_out;

    unsigned short* aware = (unsigned short*)d_ws;              // 16384x1024 bf16 (32 MB)
    unsigned short* x2    = aware + (size_t)NM * NH;            // 16384x1024 bf16 (32 MB)

    hipLaunchKernelGGL(kA, dim3(NM / 32), dim3(256), 0, stream, h, bio, aware);
    hipLaunchKernelGGL(kB, dim3(NH / 64, NM / 64), dim3(256), 0, stream, h, aware, Wcat, bcat, x2);
    hipLaunchKernelGGL(kC, dim3(NM / 32), dim3(256), 0, stream, x2, Wcrf, bcrf, out);
    hipLaunchKernelGGL(kD, dim3(NB), dim3(64), 0, stream, out, labels, token_nums, trans,
                       out + (size_t)NM * NLP);
}

// Round 2
// 703.789 us; speedup vs baseline: 5.3619x; 5.3619x over previous
//
#include <hip/hip_runtime.h>
#include <hip/hip_bf16.h>
#include <math.h>

#define NB 32
#define NS 512
#define NH 1024
#define NT 37
#define NLP 39
#define NM (NB*NS)   // 16384

typedef __attribute__((ext_vector_type(8))) short bf16x8;
typedef __attribute__((ext_vector_type(4))) float f32x4;

__device__ __forceinline__ float bf2f(unsigned int u) {
    unsigned int x = u << 16;
    float f;
    __builtin_memcpy(&f, &x, 4);
    return f;
}
__device__ __forceinline__ unsigned short f2bf(float f) {
    __hip_bfloat16 hb = __float2bfloat16(f);
    unsigned short u;
    __builtin_memcpy(&u, &hb, 2);
    return u;
}
__device__ __forceinline__ unsigned int pk2(float lo, float hi) {
    return ((unsigned int)f2bf(hi) << 16) | (unsigned int)f2bf(lo);
}
// XOR swizzle for [row][stride] bf16 tiles; spreads column reads across banks.
__device__ __forceinline__ int SW64(int b)  { return b ^ ((b >> 2) & 0x70); }  // row stride 64B
__device__ __forceinline__ int SW128(int b) { return b ^ ((b >> 3) & 0x70); }  // row stride 128B

// ---------------------------------------------------------------------------
// Kernel A (fused): scores = h@bio^T /32 -> softmax -> aware = attn@bio (bf16 out)
// 128 rows/block, 256 threads = 4 waves; wave owns 32 rows.
// ---------------------------------------------------------------------------
__global__ __launch_bounds__(256) void kA(const float* __restrict__ h,
                                          const float* __restrict__ bio,
                                          unsigned short* __restrict__ aware) {
    __shared__ __align__(16) char attn_s[128 * 128];  // [row][64 bf16], SW128
    __shared__ __align__(16) char scratch[16384];     // ph1: As(8K)+Bs1(3K); ph3: bioT(16K)
    char* Asl = scratch;
    char* Bs1 = scratch + 8192;

    const int tid  = threadIdx.x;
    const int lane = tid & 63;
    const int wid  = tid >> 6;
    const int lr   = lane & 15;
    const int lk   = lane >> 4;
    const int m0   = blockIdx.x * 128;

    const int am = tid >> 1;
    const int ak = (tid & 1) * 16;
    const int brow = tid >> 1;          // for tid<96: 0..47
    const int bkh  = (tid & 1) * 16;

    f32x4 sacc[2][3];
#pragma unroll
    for (int i = 0; i < 2; ++i)
#pragma unroll
        for (int j = 0; j < 3; ++j) sacc[i][j] = (f32x4){0.f, 0.f, 0.f, 0.f};

    const float* hrow = h + (size_t)(m0 + am) * NH + ak;

    // ---- phase 1: scores ----
    for (int kt = 0; kt < NH; kt += 32) {
        float hv[16];
        {
            const float4* hp = (const float4*)(hrow + kt);
            float4 a = hp[0], b = hp[1], c = hp[2], d = hp[3];
            hv[0]=a.x; hv[1]=a.y; hv[2]=a.z; hv[3]=a.w;
            hv[4]=b.x; hv[5]=b.y; hv[6]=b.z; hv[7]=b.w;
            hv[8]=c.x; hv[9]=c.y; hv[10]=c.z; hv[11]=c.w;
            hv[12]=d.x; hv[13]=d.y; hv[14]=d.z; hv[15]=d.w;
        }
        float bv[16];
        if (tid < 96) {
            if (brow < NT) {
                const float4* bp = (const float4*)(bio + (size_t)brow * NH + kt + bkh);
                float4 a = bp[0], b = bp[1], c = bp[2], d = bp[3];
                bv[0]=a.x; bv[1]=a.y; bv[2]=a.z; bv[3]=a.w;
                bv[4]=b.x; bv[5]=b.y; bv[6]=b.z; bv[7]=b.w;
                bv[8]=c.x; bv[9]=c.y; bv[10]=c.z; bv[11]=c.w;
                bv[12]=d.x; bv[13]=d.y; bv[14]=d.z; bv[15]=d.w;
            } else {
#pragma unroll
                for (int i = 0; i < 16; ++i) bv[i] = 0.f;
            }
        }
        __syncthreads();
        {
            unsigned int p[8];
#pragma unroll
            for (int i = 0; i < 8; ++i) p[i] = pk2(hv[2*i], hv[2*i+1]);
            *(int4*)(Asl + SW64(am*64 + ak*2))      = make_int4(p[0], p[1], p[2], p[3]);
            *(int4*)(Asl + SW64(am*64 + ak*2 + 16)) = make_int4(p[4], p[5], p[6], p[7]);
        }
        if (tid < 96) {
            unsigned int p[8];
#pragma unroll
            for (int i = 0; i < 8; ++i) p[i] = pk2(bv[2*i], bv[2*i+1]);
            *(int4*)(Bs1 + SW64(brow*64 + bkh*2))      = make_int4(p[0], p[1], p[2], p[3]);
            *(int4*)(Bs1 + SW64(brow*64 + bkh*2 + 16)) = make_int4(p[4], p[5], p[6], p[7]);
        }
        __syncthreads();
        bf16x8 af[2], bfr[3];
#pragma unroll
        for (int mf = 0; mf < 2; ++mf)
            af[mf] = *(const bf16x8*)(Asl + SW64((wid*32 + mf*16 + lr)*64 + lk*16));
#pragma unroll
        for (int nf = 0; nf < 3; ++nf)
            bfr[nf] = *(const bf16x8*)(Bs1 + SW64((nf*16 + lr)*64 + lk*16));
#pragma unroll
        for (int mf = 0; mf < 2; ++mf)
#pragma unroll
            for (int nf = 0; nf < 3; ++nf)
                sacc[mf][nf] = __builtin_amdgcn_mfma_f32_16x16x32_bf16(af[mf], bfr[nf], sacc[mf][nf], 0, 0, 0);
    }
    __syncthreads();

    // zero attn t in [48,64)
    for (int i = tid; i < 256; i += 256) {
        int row = i >> 1, part = i & 1;
        *(int4*)(attn_s + SW128(row*128 + 96 + part*16)) = make_int4(0, 0, 0, 0);
    }
    // softmax per row (16-lane group), write attn (bf16) to attn_s
#pragma unroll
    for (int mf = 0; mf < 2; ++mf) {
#pragma unroll
        for (int r = 0; r < 4; ++r) {
            const int row = wid*32 + mf*16 + lk*4 + r;
            float s0 = sacc[mf][0][r] * 0.03125f;
            float s1 = sacc[mf][1][r] * 0.03125f;
            float s2 = sacc[mf][2][r] * 0.03125f;
            const bool v2 = (lr < 5);
            float mx = fmaxf(fmaxf(s0, s1), v2 ? s2 : -1e30f);
#pragma unroll
            for (int d = 1; d < 16; d <<= 1) mx = fmaxf(mx, __shfl_xor(mx, d, 64));
            float e0 = __expf(s0 - mx), e1 = __expf(s1 - mx);
            float e2 = v2 ? __expf(s2 - mx) : 0.f;
            float sm = e0 + e1 + e2;
#pragma unroll
            for (int d = 1; d < 16; d <<= 1) sm += __shfl_xor(sm, d, 64);
            float inv = 1.f / sm;
            *(unsigned short*)(attn_s + SW128(row*128 + (lr)*2))      = f2bf(e0 * inv);
            *(unsigned short*)(attn_s + SW128(row*128 + (16+lr)*2))   = f2bf(e1 * inv);
            *(unsigned short*)(attn_s + SW128(row*128 + (32+lr)*2))   = f2bf(e2 * inv);
        }
    }
    __syncthreads();
    // zero bioT region (covers t>=37 padding)
    for (int i = tid; i < 1024; i += 256) *(int4*)(scratch + i*16) = make_int4(0, 0, 0, 0);

    // ---- phase 3: aware = attn @ bio, in 8 column chunks of 128 ----
    for (int nc = 0; nc < NH; nc += 128) {
        __syncthreads();
        for (int i = tid; i < NT*128; i += 256) {
            int t = i >> 7, n = i & 127;
            float v = bio[(size_t)t * NH + nc + n];
            *(unsigned short*)(scratch + SW128(n*128 + t*2)) = f2bf(v);
        }
        __syncthreads();
        f32x4 pacc[2][8];
#pragma unroll
        for (int i = 0; i < 2; ++i)
#pragma unroll
            for (int j = 0; j < 8; ++j) pacc[i][j] = (f32x4){0.f, 0.f, 0.f, 0.f};
#pragma unroll
        for (int ks = 0; ks < 2; ++ks) {
            bf16x8 af2[2];
#pragma unroll
            for (int mf = 0; mf < 2; ++mf)
                af2[mf] = *(const bf16x8*)(attn_s + SW128((wid*32 + mf*16 + lr)*128 + ks*64 + lk*16));
#pragma unroll
            for (int nf = 0; nf < 8; ++nf) {
                bf16x8 bb = *(const bf16x8*)(scratch + SW128((nf*16 + lr)*128 + ks*64 + lk*16));
#pragma unroll
                for (int mf = 0; mf < 2; ++mf)
                    pacc[mf][nf] = __builtin_amdgcn_mfma_f32_16x16x32_bf16(af2[mf], bb, pacc[mf][nf], 0, 0, 0);
            }
        }
#pragma unroll
        for (int mf = 0; mf < 2; ++mf)
#pragma unroll
            for (int nf = 0; nf < 8; ++nf)
#pragma unroll
                for (int r = 0; r < 4; ++r) {
                    size_t row = (size_t)(m0 + wid*32 + mf*16 + lk*4 + r);
                    aware[row * NH + nc + nf*16 + lr] = f2bf(pacc[mf][nf][r]);
                }
    }
}

// ---------------------------------------------------------------------------
// Kernel B: x2 = gelu([h, aware, h*aware] @ W_cat + b_cat), bf16 MFMA GEMM
// 128x128 tile, BK=32, 256 threads = 4 waves (2x2), per-wave 64x64 (4x4 frags).
// ---------------------------------------------------------------------------
__global__ __launch_bounds__(256) void kB(const float* __restrict__ h,
                                          const unsigned short* __restrict__ aware,
                                          const float* __restrict__ Wcat,
                                          const float* __restrict__ bcat,
                                          unsigned short* __restrict__ x2) {
    __shared__ __align__(16) char lds[16384];
    char* Asl = lds;
    char* Bsl = lds + 8192;

    const int tid  = threadIdx.x;
    const int lane = tid & 63;
    const int wid  = tid >> 6;
    const int wm   = (wid >> 1) * 64;
    const int wn   = (wid & 1) * 64;
    const int lr   = lane & 15;
    const int lk   = lane >> 4;
    const int m0   = blockIdx.y * 128;
    const int n0   = blockIdx.x * 128;

    const int am = tid >> 1;
    const int ak = (tid & 1) * 16;
    const int bn = tid & 127;
    const int bk = (tid >> 7) * 16;

    f32x4 acc[4][4];
#pragma unroll
    for (int i = 0; i < 4; ++i)
#pragma unroll
        for (int j = 0; j < 4; ++j) acc[i][j] = (f32x4){0.f, 0.f, 0.f, 0.f};

    const float*          hrow = h     + (size_t)(m0 + am) * NH + ak;
    const unsigned short* arow = aware + (size_t)(m0 + am) * NH + ak;
    const float*          wcol = Wcat  + (size_t)bk * NH + n0 + bn;

    for (int kt = 0; kt < 3072; kt += 32) {
        const int region = kt >> 10;
        const int kb = kt & 1023;

        float hv[16];
        if (region != 1) {
            const float4* hp = (const float4*)(hrow + kb);
            float4 a = hp[0], b = hp[1], c = hp[2], d = hp[3];
            hv[0]=a.x; hv[1]=a.y; hv[2]=a.z; hv[3]=a.w;
            hv[4]=b.x; hv[5]=b.y; hv[6]=b.z; hv[7]=b.w;
            hv[8]=c.x; hv[9]=c.y; hv[10]=c.z; hv[11]=c.w;
            hv[12]=d.x; hv[13]=d.y; hv[14]=d.z; hv[15]=d.w;
        }
        unsigned int aw[8];
        if (region >= 1) {
            const uint4* ap = (const uint4*)(arow + kb);
            uint4 a0 = ap[0], a1 = ap[1];
            aw[0]=a0.x; aw[1]=a0.y; aw[2]=a0.z; aw[3]=a0.w;
            aw[4]=a1.x; aw[5]=a1.y; aw[6]=a1.z; aw[7]=a1.w;
        }
        float wv[16];
        {
            const float* wp = wcol + (size_t)kt * NH;
#pragma unroll
            for (int j = 0; j < 16; ++j) wv[j] = wp[(size_t)j * NH];
        }

        __syncthreads();
        {
            unsigned int p[8];
            if (region == 0) {
#pragma unroll
                for (int i = 0; i < 8; ++i) p[i] = pk2(hv[2*i], hv[2*i+1]);
            } else if (region == 1) {
#pragma unroll
                for (int i = 0; i < 8; ++i) p[i] = aw[i];
            } else {
#pragma unroll
                for (int i = 0; i < 8; ++i) {
                    float lo = hv[2*i]   * bf2f(aw[i] & 0xffffu);
                    float hi = hv[2*i+1] * bf2f(aw[i] >> 16);
                    p[i] = pk2(lo, hi);
                }
            }
            *(int4*)(Asl + SW64(am*64 + ak*2))      = make_int4(p[0], p[1], p[2], p[3]);
            *(int4*)(Asl + SW64(am*64 + ak*2 + 16)) = make_int4(p[4], p[5], p[6], p[7]);
        }
        {
            unsigned int p[8];
#pragma unroll
            for (int i = 0; i < 8; ++i) p[i] = pk2(wv[2*i], wv[2*i+1]);
            *(int4*)(Bsl + SW64(bn*64 + bk*2))      = make_int4(p[0], p[1], p[2], p[3]);
            *(int4*)(Bsl + SW64(bn*64 + bk*2 + 16)) = make_int4(p[4], p[5], p[6], p[7]);
        }
        __syncthreads();

        bf16x8 af[4], bfr[4];
#pragma unroll
        for (int mf = 0; mf < 4; ++mf)
            af[mf] = *(const bf16x8*)(Asl + SW64((wm + mf*16 + lr)*64 + lk*16));
#pragma unroll
        for (int nf = 0; nf < 4; ++nf)
            bfr[nf] = *(const bf16x8*)(Bsl + SW64((wn + nf*16 + lr)*64 + lk*16));
#pragma unroll
        for (int mf = 0; mf < 4; ++mf)
#pragma unroll
            for (int nf = 0; nf < 4; ++nf)
                acc[mf][nf] = __builtin_amdgcn_mfma_f32_16x16x32_bf16(af[mf], bfr[nf], acc[mf][nf], 0, 0, 0);
    }

#pragma unroll
    for (int nf = 0; nf < 4; ++nf) {
        const int col = n0 + wn + nf*16 + lr;
        const float bc = bcat[col];
#pragma unroll
        for (int mf = 0; mf < 4; ++mf)
#pragma unroll
            for (int r = 0; r < 4; ++r) {
                size_t row = (size_t)(m0 + wm + mf*16 + lk*4 + r);
                float x = acc[mf][nf][r] + bc;
                float g = 0.5f * x * (1.0f + erff(x * 0.70710678118654752f));
                x2[row * NH + col] = f2bf(g);
            }
    }
}

// ---------------------------------------------------------------------------
// Kernel C: ner_scores = [x2 @ W_crf + b_crf, -10000, -10000]  (MFMA, N=48)
// 128 rows/block, 4 waves (wave = 32 rows), K=1024.
// ---------------------------------------------------------------------------
__global__ __launch_bounds__(256) void kC(const unsigned short* __restrict__ x2,
                                          const float* __restrict__ Wcrf,
                                          const float* __restrict__ bcrf,
                                          float* __restrict__ out) {
    __shared__ __align__(16) char Asl[8192];   // [128][32] bf16 SW64
    __shared__ __align__(16) char Bsl[3072];   // [48][32] bf16 SW64

    const int tid  = threadIdx.x;
    const int lane = tid & 63;
    const int wid  = tid >> 6;
    const int lr   = lane & 15;
    const int lk   = lane >> 4;
    const int m0   = blockIdx.x * 128;
    const int am   = tid >> 1;
    const int ak   = (tid & 1) * 16;

    for (int i = tid; i < 192; i += 256) *(int4*)(Bsl + i*16) = make_int4(0, 0, 0, 0);

    f32x4 acc[2][3];
#pragma unroll
    for (int i = 0; i < 2; ++i)
#pragma unroll
        for (int j = 0; j < 3; ++j) acc[i][j] = (f32x4){0.f, 0.f, 0.f, 0.f};

    const unsigned short* xrow = x2 + (size_t)(m0 + am) * NH + ak;

    for (int kt = 0; kt < NH; kt += 32) {
        const uint4* xp = (const uint4*)(xrow + kt);
        uint4 x0 = xp[0], x1 = xp[1];
        float wv[5];
#pragma unroll
        for (int p = 0; p < 5; ++p) {
            int i = tid + p * 256;
            wv[p] = (i < 32*NT) ? Wcrf[(size_t)kt * NT + i] : 0.f;
        }
        __syncthreads();
        *(uint4*)(Asl + SW64(am*64 + ak*2))      = x0;
        *(uint4*)(Asl + SW64(am*64 + ak*2 + 16)) = x1;
#pragma unroll
        for (int p = 0; p < 5; ++p) {
            int i = tid + p * 256;
            if (i < 32*NT) {
                int kk = i / NT;
                int t  = i - kk * NT;
                *(unsigned short*)(Bsl + SW64(t*64 + kk*2)) = f2bf(wv[p]);
            }
        }
        __syncthreads();
        bf16x8 af[2], bfr[3];
#pragma unroll
        for (int mf = 0; mf < 2; ++mf)
            af[mf] = *(const bf16x8*)(Asl + SW64((wid*32 + mf*16 + lr)*64 + lk*16));
#pragma unroll
        for (int nf = 0; nf < 3; ++nf)
            bfr[nf] = *(const bf16x8*)(Bsl + SW64((nf*16 + lr)*64 + lk*16));
#pragma unroll
        for (int mf = 0; mf < 2; ++mf)
#pragma unroll
            for (int nf = 0; nf < 3; ++nf)
                acc[mf][nf] = __builtin_amdgcn_mfma_f32_16x16x32_bf16(af[mf], bfr[nf], acc[mf][nf], 0, 0, 0);
    }

#pragma unroll
    for (int nf = 0; nf < 3; ++nf) {
        const int t = nf*16 + lr;
        const float bc = (t < NT) ? bcrf[t] : 0.f;
#pragma unroll
        for (int mf = 0; mf < 2; ++mf)
#pragma unroll
            for (int r = 0; r < 4; ++r) {
                size_t row = (size_t)(m0 + wid*32 + mf*16 + lk*4 + r);
                if (t < NT)       out[row * NLP + t] = acc[mf][nf][r] + bc;
                else if (t < NLP) out[row * NLP + t] = -10000.0f;
            }
    }
}

// ---------------------------------------------------------------------------
// Kernel D: CRF log-likelihood. One wave per batch element; logit prefetch.
// ---------------------------------------------------------------------------
__global__ __launch_bounds__(64) void kD(const float* __restrict__ scores,
                                         const int* __restrict__ labels,
                                         const int* __restrict__ lens,
                                         const float* __restrict__ trans,
                                         float* __restrict__ loss) {
    __shared__ float trL[39 * 41];
    __shared__ float alphaS[40];

    const int b = blockIdx.x;
    const int lane = threadIdx.x;

    for (int idx = lane; idx < 39 * 39; idx += 64) {
        int to = idx / 39, f = idx - to * 39;
        trL[to * 41 + f] = trans[idx];
    }
    if (lane < 39) alphaS[lane] = (lane == 37) ? 0.0f : -100.0f;
    __syncthreads();

    const int len = lens[b];

    float g = 0.0f;
    for (int t = lane; t < len; t += 64) {
        int lab = labels[b * NS + t];
        g += scores[((size_t)(b * NS + t)) * NLP + lab];
    }
    for (int i = lane; i <= len; i += 64) {
        int frm = (i == 0) ? 37 : labels[b * NS + i - 1];
        int to  = (i == len) ? 38 : labels[b * NS + i];
        g += trL[to * 41 + frm];
    }
#pragma unroll
    for (int off = 32; off > 0; off >>= 1) g += __shfl_xor(g, off, 64);

    const int myrow = (lane < 39) ? lane : 0;
    float tr[39];
#pragma unroll
    for (int f = 0; f < 39; ++f) tr[f] = trL[myrow * 41 + f];

    float logit_next = (lane < 39 && len > 0)
        ? scores[((size_t)(b * NS)) * NLP + lane] : -1e30f;

    for (int t = 0; t < len; ++t) {
        float logit = logit_next;
        if (t + 1 < len && lane < 39)
            logit_next = scores[((size_t)(b * NS + t + 1)) * NLP + lane];
        float v[39];
#pragma unroll
        for (int f = 0; f < 39; ++f) v[f] = alphaS[f] + tr[f];
        float t0[20];
#pragma unroll
        for (int i = 0; i < 19; ++i) t0[i] = fmaxf(v[2 * i], v[2 * i + 1]);
        t0[19] = v[38];
        float t1[10];
#pragma unroll
        for (int i = 0; i < 10; ++i) t1[i] = fmaxf(t0[2 * i], t0[2 * i + 1]);
        float t2[5];
#pragma unroll
        for (int i = 0; i < 5; ++i) t2[i] = fmaxf(t1[2 * i], t1[2 * i + 1]);
        float m = fmaxf(fmaxf(fmaxf(t2[0], t2[1]), fmaxf(t2[2], t2[3])), t2[4]);
        float e[39];
#pragma unroll
        for (int f = 0; f < 39; ++f) e[f] = __expf(v[f] - m);
        float s0[20];
#pragma unroll
        for (int i = 0; i < 19; ++i) s0[i] = e[2 * i] + e[2 * i + 1];
        s0[19] = e[38];
        float s1[10];
#pragma unroll
        for (int i = 0; i < 10; ++i) s1[i] = s0[2 * i] + s0[2 * i + 1];
        float s2[5];
#pragma unroll
        for (int i = 0; i < 5; ++i) s2[i] = s1[2 * i] + s1[2 * i + 1];
        float ssum = ((s2[0] + s2[1]) + (s2[2] + s2[3])) + s2[4];

        float anew = logit + m + __logf(ssum);
        __syncthreads();
        if (lane < 39) alphaS[lane] = anew;
        __syncthreads();
    }

    float aend = (lane < 39) ? alphaS[lane] + trL[38 * 41 + lane] : -1e30f;
    float mx = aend;
#pragma unroll
    for (int off = 32; off > 0; off >>= 1) mx = fmaxf(mx, __shfl_xor(mx, off, 64));
    float es = (lane < 39) ? __expf(aend - mx) : 0.0f;
#pragma unroll
    for (int off = 32; off > 0; off >>= 1) es += __shfl_xor(es, off, 64);
    float norm = mx + __logf(es);

    if (lane == 0) loss[b] = g - norm;
}

// ---------------------------------------------------------------------------
extern "C" void kernel_launch(void* const* d_in, const int* in_sizes, int n_in,
                              void* d_out, int out_size, void* d_ws, size_t ws_size,
                              hipStream_t stream) {
    const float* h        = (const float*)d_in[0];
    const int* token_nums = (const int*)d_in[2];
    const int* labels     = (const int*)d_in[3];
    const float* bio      = (const float*)d_in[4];
    const float* Wcat     = (const float*)d_in[5];
    const float* bcat     = (const float*)d_in[6];
    const float* Wcrf     = (const float*)d_in[7];
    const float* bcrf     = (const float*)d_in[8];
    const float* trans    = (const float*)d_in[9];

    float* out = (float*)d_out;

    unsigned short* aware = (unsigned short*)d_ws;       // 16384x1024 bf16 (32 MB)
    unsigned short* x2    = aware + (size_t)NM * NH;     // 16384x1024 bf16 (32 MB)

    hipLaunchKernelGGL(kA, dim3(NM / 128), dim3(256), 0, stream, h, bio, aware);
    hipLaunchKernelGGL(kB, dim3(NH / 128, NM / 128), dim3(256), 0, stream, h, aware, Wcat, bcat, x2);
    hipLaunchKernelGGL(kC, dim3(NM / 128), dim3(256), 0, stream, x2, Wcrf, bcrf, out);
    hipLaunchKernelGGL(kD, dim3(NB), dim3(64), 0, stream, out, labels, token_nums, trans,
                       out + (size_t)NM * NLP);
}

// Round 3
// 666.123 us; speedup vs baseline: 5.6651x; 1.0565x over previous
//
#include <hip/hip_runtime.h>
#include <hip/hip_bf16.h>
#include <math.h>

#define NB 32
#define NS 512
#define NH 1024
#define NT 37
#define NLP 39
#define NM (NB*NS)   // 16384

typedef __attribute__((ext_vector_type(8))) short bf16x8;
typedef __attribute__((ext_vector_type(4))) float f32x4;

__device__ __forceinline__ float bf2f(unsigned int u) {
    unsigned int x = u << 16;
    float f;
    __builtin_memcpy(&f, &x, 4);
    return f;
}
__device__ __forceinline__ unsigned short f2bf(float f) {
    __hip_bfloat16 hb = __float2bfloat16(f);
    unsigned short u;
    __builtin_memcpy(&u, &hb, 2);
    return u;
}
__device__ __forceinline__ unsigned int pk2(float lo, float hi) {
    return ((unsigned int)f2bf(hi) << 16) | (unsigned int)f2bf(lo);
}
// bijective XOR swizzle for [row][64B] bf16 LDS tiles (write & read both apply it)
__device__ __forceinline__ int SW64(int b)  { return b ^ ((b >> 2) & 0x70); }
// lane-broadcast via readlane (wave-uniform result)
__device__ __forceinline__ float rl(float x, int l) {
    return __int_as_float(__builtin_amdgcn_readlane(__float_as_int(x), l));
}

// ---------------------------------------------------------------------------
// Kernel A1: scores = h@bio^T /32 -> softmax -> attn (bf16, [NM][64], zero-pad)
// 64 rows/block, 256 threads = 4 waves; wave owns 16 rows.
// ---------------------------------------------------------------------------
__global__ __launch_bounds__(256) void kA1(const float* __restrict__ h,
                                           const float* __restrict__ bio,
                                           unsigned short* __restrict__ attn) {
    __shared__ __align__(16) char Asl[64 * 64];   // [64][32] bf16 SW64
    __shared__ __align__(16) char Bsl[48 * 64];   // [48][32] bf16 SW64

    const int tid  = threadIdx.x;
    const int lane = tid & 63;
    const int wid  = tid >> 6;
    const int lr   = lane & 15;
    const int lk   = lane >> 4;
    const int m0   = blockIdx.x * 64;

    const int arow = tid >> 2;
    const int aq   = (tid & 3) * 8;
    const int brow = tid >> 1;          // tid<96: 0..47
    const int bkh  = (tid & 1) * 16;

    f32x4 sacc[3];
#pragma unroll
    for (int j = 0; j < 3; ++j) sacc[j] = (f32x4){0.f, 0.f, 0.f, 0.f};

    const float* hrow = h + (size_t)(m0 + arow) * NH + aq;

    for (int kt = 0; kt < NH; kt += 32) {
        float hv[8];
        {
            const float4* hp = (const float4*)(hrow + kt);
            float4 a = hp[0], b = hp[1];
            hv[0]=a.x; hv[1]=a.y; hv[2]=a.z; hv[3]=a.w;
            hv[4]=b.x; hv[5]=b.y; hv[6]=b.z; hv[7]=b.w;
        }
        float bv[16];
        if (tid < 96) {
            if (brow < NT) {
                const float4* bp = (const float4*)(bio + (size_t)brow * NH + kt + bkh);
                float4 a = bp[0], b = bp[1], c = bp[2], d = bp[3];
                bv[0]=a.x; bv[1]=a.y; bv[2]=a.z; bv[3]=a.w;
                bv[4]=b.x; bv[5]=b.y; bv[6]=b.z; bv[7]=b.w;
                bv[8]=c.x; bv[9]=c.y; bv[10]=c.z; bv[11]=c.w;
                bv[12]=d.x; bv[13]=d.y; bv[14]=d.z; bv[15]=d.w;
            } else {
#pragma unroll
                for (int i = 0; i < 16; ++i) bv[i] = 0.f;
            }
        }
        __syncthreads();
        {
            unsigned int p[4];
#pragma unroll
            for (int i = 0; i < 4; ++i) p[i] = pk2(hv[2*i], hv[2*i+1]);
            *(int4*)(Asl + SW64(arow*64 + aq*2)) = make_int4(p[0], p[1], p[2], p[3]);
        }
        if (tid < 96) {
            unsigned int p[8];
#pragma unroll
            for (int i = 0; i < 8; ++i) p[i] = pk2(bv[2*i], bv[2*i+1]);
            *(int4*)(Bsl + SW64(brow*64 + bkh*2))      = make_int4(p[0], p[1], p[2], p[3]);
            *(int4*)(Bsl + SW64(brow*64 + bkh*2 + 16)) = make_int4(p[4], p[5], p[6], p[7]);
        }
        __syncthreads();
        bf16x8 af = *(const bf16x8*)(Asl + SW64((wid*16 + lr)*64 + lk*16));
#pragma unroll
        for (int nf = 0; nf < 3; ++nf) {
            bf16x8 bfr = *(const bf16x8*)(Bsl + SW64((nf*16 + lr)*64 + lk*16));
            sacc[nf] = __builtin_amdgcn_mfma_f32_16x16x32_bf16(af, bfr, sacc[nf], 0, 0, 0);
        }
    }

#pragma unroll
    for (int r = 0; r < 4; ++r) {
        const int row = wid*16 + lk*4 + r;
        float s0 = sacc[0][r] * 0.03125f;
        float s1 = sacc[1][r] * 0.03125f;
        float s2 = sacc[2][r] * 0.03125f;
        const bool v2 = (lr < 5);
        float mx = fmaxf(fmaxf(s0, s1), v2 ? s2 : -1e30f);
#pragma unroll
        for (int d = 1; d < 16; d <<= 1) mx = fmaxf(mx, __shfl_xor(mx, d, 64));
        float e0 = __expf(s0 - mx), e1 = __expf(s1 - mx);
        float e2 = v2 ? __expf(s2 - mx) : 0.f;
        float sm = e0 + e1 + e2;
#pragma unroll
        for (int d = 1; d < 16; d <<= 1) sm += __shfl_xor(sm, d, 64);
        float inv = 1.f / sm;
        size_t g = (size_t)(m0 + row) * 64;
        attn[g + lr]      = f2bf(e0 * inv);
        attn[g + 16 + lr] = f2bf(e1 * inv);
        attn[g + 32 + lr] = f2bf(e2 * inv);   // 0 for t>=37
        attn[g + 48 + lr] = 0;
    }
}

// ---------------------------------------------------------------------------
// Kernel A2: aware = attn @ bio  (M=16384, K=64(padded t), N=1024), bf16 out.
// 128x128 tiles; A-frags direct from global (attn is L2-resident, 2MB).
// ---------------------------------------------------------------------------
__global__ __launch_bounds__(256) void kA2(const unsigned short* __restrict__ attn,
                                           const float* __restrict__ bio,
                                           unsigned short* __restrict__ aware) {
    __shared__ __align__(16) char Bsl[128 * 64];  // [128 n][32 k] bf16 SW64

    const int tid  = threadIdx.x;
    const int lane = tid & 63;
    const int wid  = tid >> 6;
    const int wm   = (wid >> 1) * 64;
    const int wn   = (wid & 1) * 64;
    const int lr   = lane & 15;
    const int lk   = lane >> 4;
    const int n0   = blockIdx.x * 128;
    const int m0   = blockIdx.y * 128;

    const int bn = tid & 127;
    const int bq = (tid >> 7) * 16;

    f32x4 acc[4][4];
#pragma unroll
    for (int i = 0; i < 4; ++i)
#pragma unroll
        for (int j = 0; j < 4; ++j) acc[i][j] = (f32x4){0.f, 0.f, 0.f, 0.f};

#pragma unroll
    for (int ks = 0; ks < 2; ++ks) {
        unsigned int p[8];
#pragma unroll
        for (int i = 0; i < 8; ++i) {
            int t0 = ks*32 + bq + 2*i;
            float lo = (t0     < NT) ? bio[(size_t)t0 * NH + n0 + bn]       : 0.f;
            float hi = (t0 + 1 < NT) ? bio[(size_t)(t0+1) * NH + n0 + bn]   : 0.f;
            p[i] = pk2(lo, hi);
        }
        __syncthreads();
        *(int4*)(Bsl + SW64(bn*64 + bq*2))      = make_int4(p[0], p[1], p[2], p[3]);
        *(int4*)(Bsl + SW64(bn*64 + bq*2 + 16)) = make_int4(p[4], p[5], p[6], p[7]);
        __syncthreads();

        bf16x8 af[4];
#pragma unroll
        for (int mf = 0; mf < 4; ++mf)
            af[mf] = *(const bf16x8*)(attn + (size_t)(m0 + wm + mf*16 + lr) * 64 + ks*32 + lk*8);
#pragma unroll
        for (int nf = 0; nf < 4; ++nf) {
            bf16x8 bb = *(const bf16x8*)(Bsl + SW64((wn + nf*16 + lr)*64 + lk*16));
#pragma unroll
            for (int mf = 0; mf < 4; ++mf)
                acc[mf][nf] = __builtin_amdgcn_mfma_f32_16x16x32_bf16(af[mf], bb, acc[mf][nf], 0, 0, 0);
        }
    }

#pragma unroll
    for (int mf = 0; mf < 4; ++mf)
#pragma unroll
        for (int nf = 0; nf < 4; ++nf)
#pragma unroll
            for (int r = 0; r < 4; ++r) {
                size_t row = (size_t)(m0 + wm + mf*16 + lk*4 + r);
                aware[row * NH + n0 + wn + nf*16 + lr] = f2bf(acc[mf][nf][r]);
            }
}

// ---------------------------------------------------------------------------
// Kernel B: x2 = gelu([h, aware, h*aware] @ W_cat + b_cat), bf16 MFMA GEMM
// 128x128 tile, BK=32. 1D grid with XCD-aware swizzle: xcd owns 16 m-tiles x
// all 8 n-tiles (n-fastest) -> A-side fetched once per XCD slice.
// ---------------------------------------------------------------------------
__global__ __launch_bounds__(256) void kB(const float* __restrict__ h,
                                          const unsigned short* __restrict__ aware,
                                          const float* __restrict__ Wcat,
                                          const float* __restrict__ bcat,
                                          unsigned short* __restrict__ x2) {
    __shared__ __align__(16) char lds[16384];
    char* Asl = lds;
    char* Bsl = lds + 8192;

    const int tid  = threadIdx.x;
    const int lane = tid & 63;
    const int wid  = tid >> 6;
    const int wm   = (wid >> 1) * 64;
    const int wn   = (wid & 1) * 64;
    const int lr   = lane & 15;
    const int lk   = lane >> 4;

    const int id   = blockIdx.x;
    const int xcd  = id & 7;
    const int slot = id >> 3;                  // 0..127
    const int m0   = (xcd * 16 + (slot >> 3)) * 128;
    const int n0   = (slot & 7) * 128;

    const int am = tid >> 1;
    const int ak = (tid & 1) * 16;
    const int bn = tid & 127;
    const int bk = (tid >> 7) * 16;

    f32x4 acc[4][4];
#pragma unroll
    for (int i = 0; i < 4; ++i)
#pragma unroll
        for (int j = 0; j < 4; ++j) acc[i][j] = (f32x4){0.f, 0.f, 0.f, 0.f};

    const float*          hrow = h     + (size_t)(m0 + am) * NH + ak;
    const unsigned short* arow = aware + (size_t)(m0 + am) * NH + ak;
    const float*          wcol = Wcat  + (size_t)bk * NH + n0 + bn;

    for (int kt = 0; kt < 3072; kt += 32) {
        const int region = kt >> 10;
        const int kb = kt & 1023;

        float hv[16];
        if (region != 1) {
            const float4* hp = (const float4*)(hrow + kb);
            float4 a = hp[0], b = hp[1], c = hp[2], d = hp[3];
            hv[0]=a.x; hv[1]=a.y; hv[2]=a.z; hv[3]=a.w;
            hv[4]=b.x; hv[5]=b.y; hv[6]=b.z; hv[7]=b.w;
            hv[8]=c.x; hv[9]=c.y; hv[10]=c.z; hv[11]=c.w;
            hv[12]=d.x; hv[13]=d.y; hv[14]=d.z; hv[15]=d.w;
        }
        unsigned int aw[8];
        if (region >= 1) {
            const uint4* ap = (const uint4*)(arow + kb);
            uint4 a0 = ap[0], a1 = ap[1];
            aw[0]=a0.x; aw[1]=a0.y; aw[2]=a0.z; aw[3]=a0.w;
            aw[4]=a1.x; aw[5]=a1.y; aw[6]=a1.z; aw[7]=a1.w;
        }
        float wv[16];
        {
            const float* wp = wcol + (size_t)kt * NH;
#pragma unroll
            for (int j = 0; j < 16; ++j) wv[j] = wp[(size_t)j * NH];
        }

        __syncthreads();
        {
            unsigned int p[8];
            if (region == 0) {
#pragma unroll
                for (int i = 0; i < 8; ++i) p[i] = pk2(hv[2*i], hv[2*i+1]);
            } else if (region == 1) {
#pragma unroll
                for (int i = 0; i < 8; ++i) p[i] = aw[i];
            } else {
#pragma unroll
                for (int i = 0; i < 8; ++i) {
                    float lo = hv[2*i]   * bf2f(aw[i] & 0xffffu);
                    float hi = hv[2*i+1] * bf2f(aw[i] >> 16);
                    p[i] = pk2(lo, hi);
                }
            }
            *(int4*)(Asl + SW64(am*64 + ak*2))      = make_int4(p[0], p[1], p[2], p[3]);
            *(int4*)(Asl + SW64(am*64 + ak*2 + 16)) = make_int4(p[4], p[5], p[6], p[7]);
        }
        {
            unsigned int p[8];
#pragma unroll
            for (int i = 0; i < 8; ++i) p[i] = pk2(wv[2*i], wv[2*i+1]);
            *(int4*)(Bsl + SW64(bn*64 + bk*2))      = make_int4(p[0], p[1], p[2], p[3]);
            *(int4*)(Bsl + SW64(bn*64 + bk*2 + 16)) = make_int4(p[4], p[5], p[6], p[7]);
        }
        __syncthreads();

        bf16x8 af[4], bfr[4];
#pragma unroll
        for (int mf = 0; mf < 4; ++mf)
            af[mf] = *(const bf16x8*)(Asl + SW64((wm + mf*16 + lr)*64 + lk*16));
#pragma unroll
        for (int nf = 0; nf < 4; ++nf)
            bfr[nf] = *(const bf16x8*)(Bsl + SW64((wn + nf*16 + lr)*64 + lk*16));
#pragma unroll
        for (int mf = 0; mf < 4; ++mf)
#pragma unroll
            for (int nf = 0; nf < 4; ++nf)
                acc[mf][nf] = __builtin_amdgcn_mfma_f32_16x16x32_bf16(af[mf], bfr[nf], acc[mf][nf], 0, 0, 0);
    }

#pragma unroll
    for (int nf = 0; nf < 4; ++nf) {
        const int col = n0 + wn + nf*16 + lr;
        const float bc = bcat[col];
#pragma unroll
        for (int mf = 0; mf < 4; ++mf)
#pragma unroll
            for (int r = 0; r < 4; ++r) {
                size_t row = (size_t)(m0 + wm + mf*16 + lk*4 + r);
                float x = acc[mf][nf][r] + bc;
                float g = 0.5f * x * (1.0f + erff(x * 0.70710678118654752f));
                x2[row * NH + col] = f2bf(g);
            }
    }
}

// ---------------------------------------------------------------------------
// Kernel C: ner_scores = [x2 @ W_crf + b_crf, -10000, -10000]  (MFMA, N=48)
// ---------------------------------------------------------------------------
__global__ __launch_bounds__(256) void kC(const unsigned short* __restrict__ x2,
                                          const float* __restrict__ Wcrf,
                                          const float* __restrict__ bcrf,
                                          float* __restrict__ out) {
    __shared__ __align__(16) char Asl[8192];   // [128][32] bf16 SW64
    __shared__ __align__(16) char Bsl[3072];   // [48][32] bf16 SW64

    const int tid  = threadIdx.x;
    const int lane = tid & 63;
    const int wid  = tid >> 6;
    const int lr   = lane & 15;
    const int lk   = lane >> 4;
    const int m0   = blockIdx.x * 128;
    const int am   = tid >> 1;
    const int ak   = (tid & 1) * 16;

    for (int i = tid; i < 192; i += 256) *(int4*)(Bsl + i*16) = make_int4(0, 0, 0, 0);

    f32x4 acc[2][3];
#pragma unroll
    for (int i = 0; i < 2; ++i)
#pragma unroll
        for (int j = 0; j < 3; ++j) acc[i][j] = (f32x4){0.f, 0.f, 0.f, 0.f};

    const unsigned short* xrow = x2 + (size_t)(m0 + am) * NH + ak;

    for (int kt = 0; kt < NH; kt += 32) {
        const uint4* xp = (const uint4*)(xrow + kt);
        uint4 x0 = xp[0], x1 = xp[1];
        float wv[5];
#pragma unroll
        for (int p = 0; p < 5; ++p) {
            int i = tid + p * 256;
            wv[p] = (i < 32*NT) ? Wcrf[(size_t)kt * NT + i] : 0.f;
        }
        __syncthreads();
        *(uint4*)(Asl + SW64(am*64 + ak*2))      = x0;
        *(uint4*)(Asl + SW64(am*64 + ak*2 + 16)) = x1;
#pragma unroll
        for (int p = 0; p < 5; ++p) {
            int i = tid + p * 256;
            if (i < 32*NT) {
                int kk = i / NT;
                int t  = i - kk * NT;
                *(unsigned short*)(Bsl + SW64(t*64 + kk*2)) = f2bf(wv[p]);
            }
        }
        __syncthreads();
        bf16x8 af[2], bfr[3];
#pragma unroll
        for (int mf = 0; mf < 2; ++mf)
            af[mf] = *(const bf16x8*)(Asl + SW64((wid*32 + mf*16 + lr)*64 + lk*16));
#pragma unroll
        for (int nf = 0; nf < 3; ++nf)
            bfr[nf] = *(const bf16x8*)(Bsl + SW64((nf*16 + lr)*64 + lk*16));
#pragma unroll
        for (int mf = 0; mf < 2; ++mf)
#pragma unroll
            for (int nf = 0; nf < 3; ++nf)
                acc[mf][nf] = __builtin_amdgcn_mfma_f32_16x16x32_bf16(af[mf], bfr[nf], acc[mf][nf], 0, 0, 0);
    }

#pragma unroll
    for (int nf = 0; nf < 3; ++nf) {
        const int t = nf*16 + lr;
        const float bc = (t < NT) ? bcrf[t] : 0.f;
#pragma unroll
        for (int mf = 0; mf < 2; ++mf)
#pragma unroll
            for (int r = 0; r < 4; ++r) {
                size_t row = (size_t)(m0 + wid*32 + mf*16 + lk*4 + r);
                if (t < NT)       out[row * NLP + t] = acc[mf][nf][r] + bc;
                else if (t < NLP) out[row * NLP + t] = -10000.0f;
            }
    }
}

// ---------------------------------------------------------------------------
// Kernel D: CRF log-likelihood. One wave per batch; alpha broadcast via
// v_readlane (wave-synchronous, no LDS round-trip / barriers in the loop).
// ---------------------------------------------------------------------------
__global__ __launch_bounds__(64) void kD(const float* __restrict__ scores,
                                         const int* __restrict__ labels,
                                         const int* __restrict__ lens,
                                         const float* __restrict__ trans,
                                         float* __restrict__ loss) {
    __shared__ float trL[39 * 41];

    const int b = blockIdx.x;
    const int lane = threadIdx.x;

    for (int idx = lane; idx < 39 * 39; idx += 64) {
        int to = idx / 39, f = idx - to * 39;
        trL[to * 41 + f] = trans[idx];
    }
    __syncthreads();

    const int len = lens[b];

    float g = 0.0f;
    for (int t = lane; t < len; t += 64) {
        int lab = labels[b * NS + t];
        g += scores[((size_t)(b * NS + t)) * NLP + lab];
    }
    for (int i = lane; i <= len; i += 64) {
        int frm = (i == 0) ? 37 : labels[b * NS + i - 1];
        int to  = (i == len) ? 38 : labels[b * NS + i];
        g += trL[to * 41 + frm];
    }
#pragma unroll
    for (int off = 32; off > 0; off >>= 1) g += __shfl_xor(g, off, 64);

    const int myrow = (lane < 39) ? lane : 0;
    float tr[39];
#pragma unroll
    for (int f = 0; f < 39; ++f) tr[f] = trL[myrow * 41 + f];
    const float trEnd = (lane < 39) ? trL[38 * 41 + lane] : 0.f;

    float anew = (lane == 37) ? 0.0f : -100.0f;   // alpha0 per lane

    float logit_next = (lane < 39 && len > 0)
        ? scores[((size_t)(b * NS)) * NLP + lane] : -1e30f;

    for (int t = 0; t < len; ++t) {
        float logit = logit_next;
        if (t + 1 < len && lane < 39)
            logit_next = scores[((size_t)(b * NS + t + 1)) * NLP + lane];

        float v[39];
#pragma unroll
        for (int f = 0; f < 39; ++f) v[f] = rl(anew, f) + tr[f];
        float t0[20];
#pragma unroll
        for (int i = 0; i < 19; ++i) t0[i] = fmaxf(v[2 * i], v[2 * i + 1]);
        t0[19] = v[38];
        float t1[10];
#pragma unroll
        for (int i = 0; i < 10; ++i) t1[i] = fmaxf(t0[2 * i], t0[2 * i + 1]);
        float t2[5];
#pragma unroll
        for (int i = 0; i < 5; ++i) t2[i] = fmaxf(t1[2 * i], t1[2 * i + 1]);
        float m = fmaxf(fmaxf(fmaxf(t2[0], t2[1]), fmaxf(t2[2], t2[3])), t2[4]);
        float e[39];
#pragma unroll
        for (int f = 0; f < 39; ++f) e[f] = __expf(v[f] - m);
        float s0[20];
#pragma unroll
        for (int i = 0; i < 19; ++i) s0[i] = e[2 * i] + e[2 * i + 1];
        s0[19] = e[38];
        float s1[10];
#pragma unroll
        for (int i = 0; i < 10; ++i) s1[i] = s0[2 * i] + s0[2 * i + 1];
        float s2[5];
#pragma unroll
        for (int i = 0; i < 5; ++i) s2[i] = s1[2 * i] + s1[2 * i + 1];
        float ssum = ((s2[0] + s2[1]) + (s2[2] + s2[3])) + s2[4];

        anew = logit + m + __logf(ssum);
    }

    float aend = (lane < 39) ? anew + trEnd : -1e30f;
    float mx = aend;
#pragma unroll
    for (int off = 32; off > 0; off >>= 1) mx = fmaxf(mx, __shfl_xor(mx, off, 64));
    float es = (lane < 39) ? __expf(aend - mx) : 0.0f;
#pragma unroll
    for (int off = 32; off > 0; off >>= 1) es += __shfl_xor(es, off, 64);
    float norm = mx + __logf(es);

    if (lane == 0) loss[b] = g - norm;
}

// ---------------------------------------------------------------------------
extern "C" void kernel_launch(void* const* d_in, const int* in_sizes, int n_in,
                              void* d_out, int out_size, void* d_ws, size_t ws_size,
                              hipStream_t stream) {
    const float* h        = (const float*)d_in[0];
    const int* token_nums = (const int*)d_in[2];
    const int* labels     = (const int*)d_in[3];
    const float* bio      = (const float*)d_in[4];
    const float* Wcat     = (const float*)d_in[5];
    const float* bcat     = (const float*)d_in[6];
    const float* Wcrf     = (const float*)d_in[7];
    const float* bcrf     = (const float*)d_in[8];
    const float* trans    = (const float*)d_in[9];

    float* out = (float*)d_out;

    unsigned short* aware = (unsigned short*)d_ws;       // 16384x1024 bf16 (32 MB)
    unsigned short* x2    = aware + (size_t)NM * NH;     // 16384x1024 bf16 (32 MB)
    // attn scratch lives in d_out (2 MB < 2.55 MB ner_scores region, fully
    // overwritten by kC afterwards -> deterministic)
    unsigned short* attn  = (unsigned short*)d_out;

    hipLaunchKernelGGL(kA1, dim3(NM / 64), dim3(256), 0, stream, h, bio, attn);
    hipLaunchKernelGGL(kA2, dim3(NH / 128, NM / 128), dim3(256), 0, stream, attn, bio, aware);
    hipLaunchKernelGGL(kB, dim3((NH / 128) * (NM / 128)), dim3(256), 0, stream, h, aware, Wcat, bcat, x2);
    hipLaunchKernelGGL(kC, dim3(NM / 128), dim3(256), 0, stream, x2, Wcrf, bcrf, out);
    hipLaunchKernelGGL(kD, dim3(NB), dim3(64), 0, stream, out, labels, token_nums, trans,
                       out + (size_t)NM * NLP);
}

// Round 4
// 470.127 us; speedup vs baseline: 8.0269x; 1.4169x over previous
//
#include <hip/hip_runtime.h>
#include <hip/hip_bf16.h>
#include <math.h>

#define NB 32
#define NS 512
#define NH 1024
#define NT 37
#define NLP 39
#define NM (NB*NS)   // 16384

typedef __attribute__((ext_vector_type(8))) short bf16x8;
typedef __attribute__((ext_vector_type(4))) float f32x4;

__device__ __forceinline__ float bf2f(unsigned int u) {
    unsigned int x = u << 16;
    float f;
    __builtin_memcpy(&f, &x, 4);
    return f;
}
__device__ __forceinline__ unsigned short f2bf(float f) {
    __hip_bfloat16 hb = __float2bfloat16(f);
    unsigned short u;
    __builtin_memcpy(&u, &hb, 2);
    return u;
}
__device__ __forceinline__ unsigned int pk2(float lo, float hi) {
    return ((unsigned int)f2bf(hi) << 16) | (unsigned int)f2bf(lo);
}
// bijective XOR swizzle for [row][64B] bf16 LDS tiles (write & read both apply it)
__device__ __forceinline__ int SW64(int b)  { return b ^ ((b >> 2) & 0x70); }
// lane-broadcast via readlane (wave-uniform result)
__device__ __forceinline__ float rl(float x, int l) {
    return __int_as_float(__builtin_amdgcn_readlane(__float_as_int(x), l));
}

// ---------------------------------------------------------------------------
// Kernel A1: scores = h@bio^T /32 -> softmax -> attn (bf16, [NM][64], zero-pad)
// ---------------------------------------------------------------------------
__global__ __launch_bounds__(256) void kA1(const float* __restrict__ h,
                                           const float* __restrict__ bio,
                                           unsigned short* __restrict__ attn) {
    __shared__ __align__(16) char Asl[64 * 64];   // [64][32] bf16 SW64
    __shared__ __align__(16) char Bsl[48 * 64];   // [48][32] bf16 SW64

    const int tid  = threadIdx.x;
    const int lane = tid & 63;
    const int wid  = tid >> 6;
    const int lr   = lane & 15;
    const int lk   = lane >> 4;
    const int m0   = blockIdx.x * 64;

    const int arow = tid >> 2;
    const int aq   = (tid & 3) * 8;
    const int brow = tid >> 1;          // tid<96: 0..47
    const int bkh  = (tid & 1) * 16;

    f32x4 sacc[3];
#pragma unroll
    for (int j = 0; j < 3; ++j) sacc[j] = (f32x4){0.f, 0.f, 0.f, 0.f};

    const float* hrow = h + (size_t)(m0 + arow) * NH + aq;

    for (int kt = 0; kt < NH; kt += 32) {
        float hv[8];
        {
            const float4* hp = (const float4*)(hrow + kt);
            float4 a = hp[0], b = hp[1];
            hv[0]=a.x; hv[1]=a.y; hv[2]=a.z; hv[3]=a.w;
            hv[4]=b.x; hv[5]=b.y; hv[6]=b.z; hv[7]=b.w;
        }
        float bv[16];
        if (tid < 96) {
            if (brow < NT) {
                const float4* bp = (const float4*)(bio + (size_t)brow * NH + kt + bkh);
                float4 a = bp[0], b = bp[1], c = bp[2], d = bp[3];
                bv[0]=a.x; bv[1]=a.y; bv[2]=a.z; bv[3]=a.w;
                bv[4]=b.x; bv[5]=b.y; bv[6]=b.z; bv[7]=b.w;
                bv[8]=c.x; bv[9]=c.y; bv[10]=c.z; bv[11]=c.w;
                bv[12]=d.x; bv[13]=d.y; bv[14]=d.z; bv[15]=d.w;
            } else {
#pragma unroll
                for (int i = 0; i < 16; ++i) bv[i] = 0.f;
            }
        }
        __syncthreads();
        {
            unsigned int p[4];
#pragma unroll
            for (int i = 0; i < 4; ++i) p[i] = pk2(hv[2*i], hv[2*i+1]);
            *(int4*)(Asl + SW64(arow*64 + aq*2)) = make_int4(p[0], p[1], p[2], p[3]);
        }
        if (tid < 96) {
            unsigned int p[8];
#pragma unroll
            for (int i = 0; i < 8; ++i) p[i] = pk2(bv[2*i], bv[2*i+1]);
            *(int4*)(Bsl + SW64(brow*64 + bkh*2))      = make_int4(p[0], p[1], p[2], p[3]);
            *(int4*)(Bsl + SW64(brow*64 + bkh*2 + 16)) = make_int4(p[4], p[5], p[6], p[7]);
        }
        __syncthreads();
        bf16x8 af = *(const bf16x8*)(Asl + SW64((wid*16 + lr)*64 + lk*16));
#pragma unroll
        for (int nf = 0; nf < 3; ++nf) {
            bf16x8 bfr = *(const bf16x8*)(Bsl + SW64((nf*16 + lr)*64 + lk*16));
            sacc[nf] = __builtin_amdgcn_mfma_f32_16x16x32_bf16(af, bfr, sacc[nf], 0, 0, 0);
        }
    }

#pragma unroll
    for (int r = 0; r < 4; ++r) {
        const int row = wid*16 + lk*4 + r;
        float s0 = sacc[0][r] * 0.03125f;
        float s1 = sacc[1][r] * 0.03125f;
        float s2 = sacc[2][r] * 0.03125f;
        const bool v2 = (lr < 5);
        float mx = fmaxf(fmaxf(s0, s1), v2 ? s2 : -1e30f);
#pragma unroll
        for (int d = 1; d < 16; d <<= 1) mx = fmaxf(mx, __shfl_xor(mx, d, 64));
        float e0 = __expf(s0 - mx), e1 = __expf(s1 - mx);
        float e2 = v2 ? __expf(s2 - mx) : 0.f;
        float sm = e0 + e1 + e2;
#pragma unroll
        for (int d = 1; d < 16; d <<= 1) sm += __shfl_xor(sm, d, 64);
        float inv = 1.f / sm;
        size_t g = (size_t)(m0 + row) * 64;
        attn[g + lr]      = f2bf(e0 * inv);
        attn[g + 16 + lr] = f2bf(e1 * inv);
        attn[g + 32 + lr] = f2bf(e2 * inv);   // 0 for t>=37
        attn[g + 48 + lr] = 0;
    }
}

// ---------------------------------------------------------------------------
// Kernel A2: aware = attn @ bio  (M=16384, K=64(padded t), N=1024), bf16 out.
// ---------------------------------------------------------------------------
__global__ __launch_bounds__(256) void kA2(const unsigned short* __restrict__ attn,
                                           const float* __restrict__ bio,
                                           unsigned short* __restrict__ aware) {
    __shared__ __align__(16) char Bsl[128 * 64];  // [128 n][32 k] bf16 SW64

    const int tid  = threadIdx.x;
    const int lane = tid & 63;
    const int wid  = tid >> 6;
    const int wm   = (wid >> 1) * 64;
    const int wn   = (wid & 1) * 64;
    const int lr   = lane & 15;
    const int lk   = lane >> 4;
    const int n0   = blockIdx.x * 128;
    const int m0   = blockIdx.y * 128;

    const int bn = tid & 127;
    const int bq = (tid >> 7) * 16;

    f32x4 acc[4][4];
#pragma unroll
    for (int i = 0; i < 4; ++i)
#pragma unroll
        for (int j = 0; j < 4; ++j) acc[i][j] = (f32x4){0.f, 0.f, 0.f, 0.f};

#pragma unroll
    for (int ks = 0; ks < 2; ++ks) {
        unsigned int p[8];
#pragma unroll
        for (int i = 0; i < 8; ++i) {
            int t0 = ks*32 + bq + 2*i;
            float lo = (t0     < NT) ? bio[(size_t)t0 * NH + n0 + bn]       : 0.f;
            float hi = (t0 + 1 < NT) ? bio[(size_t)(t0+1) * NH + n0 + bn]   : 0.f;
            p[i] = pk2(lo, hi);
        }
        __syncthreads();
        *(int4*)(Bsl + SW64(bn*64 + bq*2))      = make_int4(p[0], p[1], p[2], p[3]);
        *(int4*)(Bsl + SW64(bn*64 + bq*2 + 16)) = make_int4(p[4], p[5], p[6], p[7]);
        __syncthreads();

        bf16x8 af[4];
#pragma unroll
        for (int mf = 0; mf < 4; ++mf)
            af[mf] = *(const bf16x8*)(attn + (size_t)(m0 + wm + mf*16 + lr) * 64 + ks*32 + lk*8);
#pragma unroll
        for (int nf = 0; nf < 4; ++nf) {
            bf16x8 bb = *(const bf16x8*)(Bsl + SW64((wn + nf*16 + lr)*64 + lk*16));
#pragma unroll
            for (int mf = 0; mf < 4; ++mf)
                acc[mf][nf] = __builtin_amdgcn_mfma_f32_16x16x32_bf16(af[mf], bb, acc[mf][nf], 0, 0, 0);
        }
    }

#pragma unroll
    for (int mf = 0; mf < 4; ++mf)
#pragma unroll
        for (int nf = 0; nf < 4; ++nf)
#pragma unroll
            for (int r = 0; r < 4; ++r) {
                size_t row = (size_t)(m0 + wm + mf*16 + lk*4 + r);
                aware[row * NH + n0 + wn + nf*16 + lr] = f2bf(acc[mf][nf][r]);
            }
}

// ---------------------------------------------------------------------------
// Kernel B: x2 = gelu([h, aware, h*aware] @ W_cat + b_cat), bf16 MFMA GEMM
// 128x128 tile, BK=32, XCD-sliced 1D grid, stage-ahead prefetch: iteration
// k+1's global loads are issued before iteration k's MFMA so HBM/L2 latency
// overlaps compute instead of sitting between barriers.
// ---------------------------------------------------------------------------
__global__ __launch_bounds__(256) void kB(const float* __restrict__ h,
                                          const unsigned short* __restrict__ aware,
                                          const float* __restrict__ Wcat,
                                          const float* __restrict__ bcat,
                                          unsigned short* __restrict__ x2) {
    __shared__ __align__(16) char lds[16384];
    char* Asl = lds;
    char* Bsl = lds + 8192;

    const int tid  = threadIdx.x;
    const int lane = tid & 63;
    const int wid  = tid >> 6;
    const int wm   = (wid >> 1) * 64;
    const int wn   = (wid & 1) * 64;
    const int lr   = lane & 15;
    const int lk   = lane >> 4;

    const int id   = blockIdx.x;
    const int xcd  = id & 7;
    const int slot = id >> 3;                  // 0..127
    const int m0   = (xcd * 16 + (slot >> 3)) * 128;
    const int n0   = (slot & 7) * 128;

    const int am = tid >> 1;
    const int ak = (tid & 1) * 16;
    const int bn = tid & 127;
    const int bk = (tid >> 7) * 16;

    f32x4 acc[4][4];
#pragma unroll
    for (int i = 0; i < 4; ++i)
#pragma unroll
        for (int j = 0; j < 4; ++j) acc[i][j] = (f32x4){0.f, 0.f, 0.f, 0.f};

    const float*          hrow = h     + (size_t)(m0 + am) * NH + ak;
    const unsigned short* arow = aware + (size_t)(m0 + am) * NH + ak;
    const float*          wcol = Wcat  + (size_t)bk * NH + n0 + bn;

    float hv[16];
    unsigned int aw[8];
    float wv[16];

    auto stage = [&](int kt) {
        const int region = kt >> 10;
        const int kb = kt & 1023;
        if (region != 1) {
            const float4* hp = (const float4*)(hrow + kb);
            float4 a = hp[0], b = hp[1], c = hp[2], d = hp[3];
            hv[0]=a.x; hv[1]=a.y; hv[2]=a.z; hv[3]=a.w;
            hv[4]=b.x; hv[5]=b.y; hv[6]=b.z; hv[7]=b.w;
            hv[8]=c.x; hv[9]=c.y; hv[10]=c.z; hv[11]=c.w;
            hv[12]=d.x; hv[13]=d.y; hv[14]=d.z; hv[15]=d.w;
        }
        if (region >= 1) {
            const uint4* ap = (const uint4*)(arow + kb);
            uint4 a0 = ap[0], a1 = ap[1];
            aw[0]=a0.x; aw[1]=a0.y; aw[2]=a0.z; aw[3]=a0.w;
            aw[4]=a1.x; aw[5]=a1.y; aw[6]=a1.z; aw[7]=a1.w;
        }
        {
            const float* wp = wcol + (size_t)kt * NH;
#pragma unroll
            for (int j = 0; j < 16; ++j) wv[j] = wp[(size_t)j * NH];
        }
    };

    auto writeStage = [&](int kt) {
        const int region = kt >> 10;
        unsigned int p[8];
        if (region == 0) {
#pragma unroll
            for (int i = 0; i < 8; ++i) p[i] = pk2(hv[2*i], hv[2*i+1]);
        } else if (region == 1) {
#pragma unroll
            for (int i = 0; i < 8; ++i) p[i] = aw[i];
        } else {
#pragma unroll
            for (int i = 0; i < 8; ++i) {
                float lo = hv[2*i]   * bf2f(aw[i] & 0xffffu);
                float hi = hv[2*i+1] * bf2f(aw[i] >> 16);
                p[i] = pk2(lo, hi);
            }
        }
        *(int4*)(Asl + SW64(am*64 + ak*2))      = make_int4(p[0], p[1], p[2], p[3]);
        *(int4*)(Asl + SW64(am*64 + ak*2 + 16)) = make_int4(p[4], p[5], p[6], p[7]);
        unsigned int q[8];
#pragma unroll
        for (int i = 0; i < 8; ++i) q[i] = pk2(wv[2*i], wv[2*i+1]);
        *(int4*)(Bsl + SW64(bn*64 + bk*2))      = make_int4(q[0], q[1], q[2], q[3]);
        *(int4*)(Bsl + SW64(bn*64 + bk*2 + 16)) = make_int4(q[4], q[5], q[6], q[7]);
    };

    stage(0);
    for (int kt = 0; kt < 3072; kt += 32) {
        __syncthreads();
        writeStage(kt);
        __syncthreads();
        if (kt + 32 < 3072) stage(kt + 32);   // prefetch next tile's regs early

        bf16x8 af[4], bfr[4];
#pragma unroll
        for (int mf = 0; mf < 4; ++mf)
            af[mf] = *(const bf16x8*)(Asl + SW64((wm + mf*16 + lr)*64 + lk*16));
#pragma unroll
        for (int nf = 0; nf < 4; ++nf)
            bfr[nf] = *(const bf16x8*)(Bsl + SW64((wn + nf*16 + lr)*64 + lk*16));
#pragma unroll
        for (int mf = 0; mf < 4; ++mf)
#pragma unroll
            for (int nf = 0; nf < 4; ++nf)
                acc[mf][nf] = __builtin_amdgcn_mfma_f32_16x16x32_bf16(af[mf], bfr[nf], acc[mf][nf], 0, 0, 0);
    }

#pragma unroll
    for (int nf = 0; nf < 4; ++nf) {
        const int col = n0 + wn + nf*16 + lr;
        const float bc = bcat[col];
#pragma unroll
        for (int mf = 0; mf < 4; ++mf)
#pragma unroll
            for (int r = 0; r < 4; ++r) {
                size_t row = (size_t)(m0 + wm + mf*16 + lk*4 + r);
                float x = acc[mf][nf][r] + bc;
                float g = 0.5f * x * (1.0f + erff(x * 0.70710678118654752f));
                x2[row * NH + col] = f2bf(g);
            }
    }
}

// ---------------------------------------------------------------------------
// Kernel C: ner_scores = [x2 @ W_crf + b_crf, -10000, -10000]  (MFMA, N=48)
// ---------------------------------------------------------------------------
__global__ __launch_bounds__(256) void kC(const unsigned short* __restrict__ x2,
                                          const float* __restrict__ Wcrf,
                                          const float* __restrict__ bcrf,
                                          float* __restrict__ out) {
    __shared__ __align__(16) char Asl[8192];   // [128][32] bf16 SW64
    __shared__ __align__(16) char Bsl[3072];   // [48][32] bf16 SW64

    const int tid  = threadIdx.x;
    const int lane = tid & 63;
    const int wid  = tid >> 6;
    const int lr   = lane & 15;
    const int lk   = lane >> 4;
    const int m0   = blockIdx.x * 128;
    const int am   = tid >> 1;
    const int ak   = (tid & 1) * 16;

    for (int i = tid; i < 192; i += 256) *(int4*)(Bsl + i*16) = make_int4(0, 0, 0, 0);

    f32x4 acc[2][3];
#pragma unroll
    for (int i = 0; i < 2; ++i)
#pragma unroll
        for (int j = 0; j < 3; ++j) acc[i][j] = (f32x4){0.f, 0.f, 0.f, 0.f};

    const unsigned short* xrow = x2 + (size_t)(m0 + am) * NH + ak;

    for (int kt = 0; kt < NH; kt += 32) {
        const uint4* xp = (const uint4*)(xrow + kt);
        uint4 x0 = xp[0], x1 = xp[1];
        float wv[5];
#pragma unroll
        for (int p = 0; p < 5; ++p) {
            int i = tid + p * 256;
            wv[p] = (i < 32*NT) ? Wcrf[(size_t)kt * NT + i] : 0.f;
        }
        __syncthreads();
        *(uint4*)(Asl + SW64(am*64 + ak*2))      = x0;
        *(uint4*)(Asl + SW64(am*64 + ak*2 + 16)) = x1;
#pragma unroll
        for (int p = 0; p < 5; ++p) {
            int i = tid + p * 256;
            if (i < 32*NT) {
                int kk = i / NT;
                int t  = i - kk * NT;
                *(unsigned short*)(Bsl + SW64(t*64 + kk*2)) = f2bf(wv[p]);
            }
        }
        __syncthreads();
        bf16x8 af[2], bfr[3];
#pragma unroll
        for (int mf = 0; mf < 2; ++mf)
            af[mf] = *(const bf16x8*)(Asl + SW64((wid*32 + mf*16 + lr)*64 + lk*16));
#pragma unroll
        for (int nf = 0; nf < 3; ++nf)
            bfr[nf] = *(const bf16x8*)(Bsl + SW64((nf*16 + lr)*64 + lk*16));
#pragma unroll
        for (int mf = 0; mf < 2; ++mf)
#pragma unroll
            for (int nf = 0; nf < 3; ++nf)
                acc[mf][nf] = __builtin_amdgcn_mfma_f32_16x16x32_bf16(af[mf], bfr[nf], acc[mf][nf], 0, 0, 0);
    }

#pragma unroll
    for (int nf = 0; nf < 3; ++nf) {
        const int t = nf*16 + lr;
        const float bc = (t < NT) ? bcrf[t] : 0.f;
#pragma unroll
        for (int mf = 0; mf < 2; ++mf)
#pragma unroll
            for (int r = 0; r < 4; ++r) {
                size_t row = (size_t)(m0 + wid*32 + mf*16 + lk*4 + r);
                if (t < NT)       out[row * NLP + t] = acc[mf][nf][r] + bc;
                else if (t < NLP) out[row * NLP + t] = -10000.0f;
            }
    }
}

// ---------------------------------------------------------------------------
// Kernel D: CRF log-likelihood, exp-domain scan. One wave per batch.
// alpha kept as a = exp(alpha - C) per lane (lane = state). Per step:
//   a'[to] = exp(logit[to]) * sum_frm exp(trans[to][frm]) * a[frm]
// (39 readlane+fma), rescale by wave-max every 4 steps, C += log(s).
// No logsumexp tree, no per-state exp in the serial chain.
// ---------------------------------------------------------------------------
__global__ __launch_bounds__(64) void kD(const float* __restrict__ scores,
                                         const int* __restrict__ labels,
                                         const int* __restrict__ lens,
                                         const float* __restrict__ trans,
                                         float* __restrict__ loss) {
    __shared__ float trL[39 * 41];

    const int b = blockIdx.x;
    const int lane = threadIdx.x;

    for (int idx = lane; idx < 39 * 39; idx += 64) {
        int to = idx / 39, f = idx - to * 39;
        trL[to * 41 + f] = trans[idx];
    }
    __syncthreads();

    const int len = lens[b];

    // gold path score (unchanged)
    float g = 0.0f;
    for (int t = lane; t < len; t += 64) {
        int lab = labels[b * NS + t];
        g += scores[((size_t)(b * NS + t)) * NLP + lab];
    }
    for (int i = lane; i <= len; i += 64) {
        int frm = (i == 0) ? 37 : labels[b * NS + i - 1];
        int to  = (i == len) ? 38 : labels[b * NS + i];
        g += trL[to * 41 + frm];
    }
#pragma unroll
    for (int off = 32; off > 0; off >>= 1) g += __shfl_xor(g, off, 64);

    // per-lane row of exp(trans): trow[f] = exp(trans[lane][f])
    const int myrow = (lane < 39) ? lane : 0;
    float trow[39];
#pragma unroll
    for (int f = 0; f < 39; ++f) trow[f] = __expf(trL[myrow * 41 + f]);
    const float trEnd = (lane < 39) ? trL[38 * 41 + lane] : 0.f;

    float a = (lane == 37) ? 1.0f : 0.0f;   // exp(alpha0 - 0); exp(-100) ~ 0
    float C = 0.0f;                          // accumulated log-scale

    float logit_next = (lane < 39 && len > 0)
        ? scores[((size_t)(b * NS)) * NLP + lane] : 0.f;

    for (int t = 0; t < len; ++t) {
        float el = __expf(logit_next);       // exp(logit_t[lane]); pads -> 0
        if (t + 1 < len && lane < 39)
            logit_next = scores[((size_t)(b * NS + t + 1)) * NLP + lane];

        float acc0 = 0.f, acc1 = 0.f, acc2 = 0.f, acc3 = 0.f;
#pragma unroll
        for (int f = 0; f < 36; f += 4) {
            acc0 = fmaf(rl(a, f),     trow[f],     acc0);
            acc1 = fmaf(rl(a, f + 1), trow[f + 1], acc1);
            acc2 = fmaf(rl(a, f + 2), trow[f + 2], acc2);
            acc3 = fmaf(rl(a, f + 3), trow[f + 3], acc3);
        }
        acc0 = fmaf(rl(a, 36), trow[36], acc0);
        acc1 = fmaf(rl(a, 37), trow[37], acc1);
        acc2 = fmaf(rl(a, 38), trow[38], acc2);
        float acc = (acc0 + acc1) + (acc2 + acc3);

        a = (lane < 39) ? el * acc : 0.f;

        if ((t & 3) == 3) {                  // rescale every 4 steps
            float s = a;
#pragma unroll
            for (int off = 32; off > 0; off >>= 1) s = fmaxf(s, __shfl_xor(s, off, 64));
            float inv = 1.0f / s;
            a *= inv;
            C += __logf(s);
        }
    }

    float aend = (lane < 39 && a > 0.f) ? C + __logf(a) + trEnd : -1e30f;
    float mx = aend;
#pragma unroll
    for (int off = 32; off > 0; off >>= 1) mx = fmaxf(mx, __shfl_xor(mx, off, 64));
    float es = (lane < 39) ? __expf(aend - mx) : 0.0f;
#pragma unroll
    for (int off = 32; off > 0; off >>= 1) es += __shfl_xor(es, off, 64);
    float norm = mx + __logf(es);

    if (lane == 0) loss[b] = g - norm;
}

// ---------------------------------------------------------------------------
extern "C" void kernel_launch(void* const* d_in, const int* in_sizes, int n_in,
                              void* d_out, int out_size, void* d_ws, size_t ws_size,
                              hipStream_t stream) {
    const float* h        = (const float*)d_in[0];
    const int* token_nums = (const int*)d_in[2];
    const int* labels     = (const int*)d_in[3];
    const float* bio      = (const float*)d_in[4];
    const float* Wcat     = (const float*)d_in[5];
    const float* bcat     = (const float*)d_in[6];
    const float* Wcrf     = (const float*)d_in[7];
    const float* bcrf     = (const float*)d_in[8];
    const float* trans    = (const float*)d_in[9];

    float* out = (float*)d_out;

    unsigned short* aware = (unsigned short*)d_ws;       // 16384x1024 bf16 (32 MB)
    unsigned short* x2    = aware + (size_t)NM * NH;     // 16384x1024 bf16 (32 MB)
    // attn scratch lives in d_out (2 MB), fully overwritten by kC afterwards
    unsigned short* attn  = (unsigned short*)d_out;

    hipLaunchKernelGGL(kA1, dim3(NM / 64), dim3(256), 0, stream, h, bio, attn);
    hipLaunchKernelGGL(kA2, dim3(NH / 128, NM / 128), dim3(256), 0, stream, attn, bio, aware);
    hipLaunchKernelGGL(kB, dim3((NH / 128) * (NM / 128)), dim3(256), 0, stream, h, aware, Wcat, bcat, x2);
    hipLaunchKernelGGL(kC, dim3(NM / 128), dim3(256), 0, stream, x2, Wcrf, bcrf, out);
    hipLaunchKernelGGL(kD, dim3(NB), dim3(64), 0, stream, out, labels, token_nums, trans,
                       out + (size_t)NM * NLP);
}

// Round 5
// 365.713 us; speedup vs baseline: 10.3187x; 1.2855x over previous
//
#include <hip/hip_runtime.h>
#include <hip/hip_bf16.h>
#include <math.h>

#define NB 32
#define NS 512
#define NH 1024
#define NT 37
#define NLP 39
#define NM (NB*NS)   // 16384

typedef __attribute__((ext_vector_type(8))) short bf16x8;
typedef __attribute__((ext_vector_type(4))) float f32x4;

__device__ __forceinline__ float bf2f(unsigned int u) {
    unsigned int x = u << 16;
    float f;
    __builtin_memcpy(&f, &x, 4);
    return f;
}
__device__ __forceinline__ unsigned short f2bf(float f) {
    __hip_bfloat16 hb = __float2bfloat16(f);
    unsigned short u;
    __builtin_memcpy(&u, &hb, 2);
    return u;
}
__device__ __forceinline__ unsigned int pk2(float lo, float hi) {
    return ((unsigned int)f2bf(hi) << 16) | (unsigned int)f2bf(lo);
}
// bijective XOR swizzle for [row][64B] bf16 LDS tiles
__device__ __forceinline__ int SW64(int b)  { return b ^ ((b >> 2) & 0x70); }
// tile swizzle for [128 row][64 k] bf16 tiles (row stride 128B): XOR bits4-6 with row&7
__device__ __forceinline__ int TSW(int row, int kcolByte) {
    return (row * 128 + kcolByte) ^ ((row & 7) << 4);
}
__device__ __forceinline__ float rl(float x, int l) {
    return __int_as_float(__builtin_amdgcn_readlane(__float_as_int(x), l));
}
__device__ __forceinline__ void gld16(const void* g, void* l) {
    __builtin_amdgcn_global_load_lds((const __attribute__((address_space(1))) void*)g,
                                     (__attribute__((address_space(3))) void*)l, 16, 0, 0);
}

// ---------------------------------------------------------------------------
// Kernel A1: scores = h@bio^T /32 -> softmax -> attn (bf16, [NM][64], zero-pad)
// ---------------------------------------------------------------------------
__global__ __launch_bounds__(256) void kA1(const float* __restrict__ h,
                                           const float* __restrict__ bio,
                                           unsigned short* __restrict__ attn) {
    __shared__ __align__(16) char Asl[64 * 64];
    __shared__ __align__(16) char Bsl[48 * 64];

    const int tid  = threadIdx.x;
    const int lane = tid & 63;
    const int wid  = tid >> 6;
    const int lr   = lane & 15;
    const int lk   = lane >> 4;
    const int m0   = blockIdx.x * 64;

    const int arow = tid >> 2;
    const int aq   = (tid & 3) * 8;
    const int brow = tid >> 1;
    const int bkh  = (tid & 1) * 16;

    f32x4 sacc[3];
#pragma unroll
    for (int j = 0; j < 3; ++j) sacc[j] = (f32x4){0.f, 0.f, 0.f, 0.f};

    const float* hrow = h + (size_t)(m0 + arow) * NH + aq;

    for (int kt = 0; kt < NH; kt += 32) {
        float hv[8];
        {
            const float4* hp = (const float4*)(hrow + kt);
            float4 a = hp[0], b = hp[1];
            hv[0]=a.x; hv[1]=a.y; hv[2]=a.z; hv[3]=a.w;
            hv[4]=b.x; hv[5]=b.y; hv[6]=b.z; hv[7]=b.w;
        }
        float bv[16];
        if (tid < 96) {
            if (brow < NT) {
                const float4* bp = (const float4*)(bio + (size_t)brow * NH + kt + bkh);
                float4 a = bp[0], b = bp[1], c = bp[2], d = bp[3];
                bv[0]=a.x; bv[1]=a.y; bv[2]=a.z; bv[3]=a.w;
                bv[4]=b.x; bv[5]=b.y; bv[6]=b.z; bv[7]=b.w;
                bv[8]=c.x; bv[9]=c.y; bv[10]=c.z; bv[11]=c.w;
                bv[12]=d.x; bv[13]=d.y; bv[14]=d.z; bv[15]=d.w;
            } else {
#pragma unroll
                for (int i = 0; i < 16; ++i) bv[i] = 0.f;
            }
        }
        __syncthreads();
        {
            unsigned int p[4];
#pragma unroll
            for (int i = 0; i < 4; ++i) p[i] = pk2(hv[2*i], hv[2*i+1]);
            *(int4*)(Asl + SW64(arow*64 + aq*2)) = make_int4(p[0], p[1], p[2], p[3]);
        }
        if (tid < 96) {
            unsigned int p[8];
#pragma unroll
            for (int i = 0; i < 8; ++i) p[i] = pk2(bv[2*i], bv[2*i+1]);
            *(int4*)(Bsl + SW64(brow*64 + bkh*2))      = make_int4(p[0], p[1], p[2], p[3]);
            *(int4*)(Bsl + SW64(brow*64 + bkh*2 + 16)) = make_int4(p[4], p[5], p[6], p[7]);
        }
        __syncthreads();
        bf16x8 af = *(const bf16x8*)(Asl + SW64((wid*16 + lr)*64 + lk*16));
#pragma unroll
        for (int nf = 0; nf < 3; ++nf) {
            bf16x8 bfr = *(const bf16x8*)(Bsl + SW64((nf*16 + lr)*64 + lk*16));
            sacc[nf] = __builtin_amdgcn_mfma_f32_16x16x32_bf16(af, bfr, sacc[nf], 0, 0, 0);
        }
    }

#pragma unroll
    for (int r = 0; r < 4; ++r) {
        const int row = wid*16 + lk*4 + r;
        float s0 = sacc[0][r] * 0.03125f;
        float s1 = sacc[1][r] * 0.03125f;
        float s2 = sacc[2][r] * 0.03125f;
        const bool v2 = (lr < 5);
        float mx = fmaxf(fmaxf(s0, s1), v2 ? s2 : -1e30f);
#pragma unroll
        for (int d = 1; d < 16; d <<= 1) mx = fmaxf(mx, __shfl_xor(mx, d, 64));
        float e0 = __expf(s0 - mx), e1 = __expf(s1 - mx);
        float e2 = v2 ? __expf(s2 - mx) : 0.f;
        float sm = e0 + e1 + e2;
#pragma unroll
        for (int d = 1; d < 16; d <<= 1) sm += __shfl_xor(sm, d, 64);
        float inv = 1.f / sm;
        size_t g = (size_t)(m0 + row) * 64;
        attn[g + lr]      = f2bf(e0 * inv);
        attn[g + 16 + lr] = f2bf(e1 * inv);
        attn[g + 32 + lr] = f2bf(e2 * inv);
        attn[g + 48 + lr] = 0;
    }
}

// ---------------------------------------------------------------------------
// Kernel A2 (fallback): aware = attn @ bio, plain bf16 row-major out.
// ---------------------------------------------------------------------------
__global__ __launch_bounds__(256) void kA2(const unsigned short* __restrict__ attn,
                                           const float* __restrict__ bio,
                                           unsigned short* __restrict__ aware) {
    __shared__ __align__(16) char Bsl[128 * 64];

    const int tid  = threadIdx.x;
    const int lane = tid & 63;
    const int wid  = tid >> 6;
    const int wm   = (wid >> 1) * 64;
    const int wn   = (wid & 1) * 64;
    const int lr   = lane & 15;
    const int lk   = lane >> 4;
    const int n0   = blockIdx.x * 128;
    const int m0   = blockIdx.y * 128;

    const int bn = tid & 127;
    const int bq = (tid >> 7) * 16;

    f32x4 acc[4][4];
#pragma unroll
    for (int i = 0; i < 4; ++i)
#pragma unroll
        for (int j = 0; j < 4; ++j) acc[i][j] = (f32x4){0.f, 0.f, 0.f, 0.f};

#pragma unroll
    for (int ks = 0; ks < 2; ++ks) {
        unsigned int p[8];
#pragma unroll
        for (int i = 0; i < 8; ++i) {
            int t0 = ks*32 + bq + 2*i;
            float lo = (t0     < NT) ? bio[(size_t)t0 * NH + n0 + bn]       : 0.f;
            float hi = (t0 + 1 < NT) ? bio[(size_t)(t0+1) * NH + n0 + bn]   : 0.f;
            p[i] = pk2(lo, hi);
        }
        __syncthreads();
        *(int4*)(Bsl + SW64(bn*64 + bq*2))      = make_int4(p[0], p[1], p[2], p[3]);
        *(int4*)(Bsl + SW64(bn*64 + bq*2 + 16)) = make_int4(p[4], p[5], p[6], p[7]);
        __syncthreads();

        bf16x8 af[4];
#pragma unroll
        for (int mf = 0; mf < 4; ++mf)
            af[mf] = *(const bf16x8*)(attn + (size_t)(m0 + wm + mf*16 + lr) * 64 + ks*32 + lk*8);
#pragma unroll
        for (int nf = 0; nf < 4; ++nf) {
            bf16x8 bb = *(const bf16x8*)(Bsl + SW64((wn + nf*16 + lr)*64 + lk*16));
#pragma unroll
            for (int mf = 0; mf < 4; ++mf)
                acc[mf][nf] = __builtin_amdgcn_mfma_f32_16x16x32_bf16(af[mf], bb, acc[mf][nf], 0, 0, 0);
        }
    }

#pragma unroll
    for (int mf = 0; mf < 4; ++mf)
#pragma unroll
        for (int nf = 0; nf < 4; ++nf)
#pragma unroll
            for (int r = 0; r < 4; ++r) {
                size_t row = (size_t)(m0 + wm + mf*16 + lk*4 + r);
                aware[row * NH + n0 + wn + nf*16 + lr] = f2bf(acc[mf][nf][r]);
            }
}

// ---------------------------------------------------------------------------
// Kernel A2f (fast): computes aware chunk AND writes the full concat-A
// [h | aware | h*aware] in bf16, tile-major (128x64 tiles) with TSW swizzle
// baked in (so kBf's linear global_load_lds lands pre-swizzled in LDS).
// ---------------------------------------------------------------------------
__global__ __launch_bounds__(256) void kA2f(const unsigned short* __restrict__ attn,
                                            const float* __restrict__ bio,
                                            const float* __restrict__ h,
                                            char* __restrict__ Asw) {
    __shared__ __align__(16) char Bsl[128 * 64];
    __shared__ __align__(16) unsigned short awL[128 * 128];  // 32KB aware chunk

    const int tid  = threadIdx.x;
    const int lane = tid & 63;
    const int wid  = tid >> 6;
    const int wm   = (wid >> 1) * 64;
    const int wn   = (wid & 1) * 64;
    const int lr   = lane & 15;
    const int lk   = lane >> 4;
    const int n0   = blockIdx.x * 128;   // aware col chunk (= A k-offset in region)
    const int m0   = blockIdx.y * 128;
    const int tm   = blockIdx.y;         // m-tile index

    const int bn = tid & 127;
    const int bq = (tid >> 7) * 16;

    f32x4 acc[4][4];
#pragma unroll
    for (int i = 0; i < 4; ++i)
#pragma unroll
        for (int j = 0; j < 4; ++j) acc[i][j] = (f32x4){0.f, 0.f, 0.f, 0.f};

#pragma unroll
    for (int ks = 0; ks < 2; ++ks) {
        unsigned int p[8];
#pragma unroll
        for (int i = 0; i < 8; ++i) {
            int t0 = ks*32 + bq + 2*i;
            float lo = (t0     < NT) ? bio[(size_t)t0 * NH + n0 + bn]       : 0.f;
            float hi = (t0 + 1 < NT) ? bio[(size_t)(t0+1) * NH + n0 + bn]   : 0.f;
            p[i] = pk2(lo, hi);
        }
        __syncthreads();
        *(int4*)(Bsl + SW64(bn*64 + bq*2))      = make_int4(p[0], p[1], p[2], p[3]);
        *(int4*)(Bsl + SW64(bn*64 + bq*2 + 16)) = make_int4(p[4], p[5], p[6], p[7]);
        __syncthreads();

        bf16x8 af[4];
#pragma unroll
        for (int mf = 0; mf < 4; ++mf)
            af[mf] = *(const bf16x8*)(attn + (size_t)(m0 + wm + mf*16 + lr) * 64 + ks*32 + lk*8);
#pragma unroll
        for (int nf = 0; nf < 4; ++nf) {
            bf16x8 bb = *(const bf16x8*)(Bsl + SW64((wn + nf*16 + lr)*64 + lk*16));
#pragma unroll
            for (int mf = 0; mf < 4; ++mf)
                acc[mf][nf] = __builtin_amdgcn_mfma_f32_16x16x32_bf16(af[mf], bb, acc[mf][nf], 0, 0, 0);
        }
    }

    // stash aware chunk in LDS
#pragma unroll
    for (int mf = 0; mf < 4; ++mf)
#pragma unroll
        for (int nf = 0; nf < 4; ++nf)
#pragma unroll
            for (int r = 0; r < 4; ++r)
                awL[(wm + mf*16 + lk*4 + r) * 128 + wn + nf*16 + lr] = f2bf(acc[mf][nf][r]);
    __syncthreads();

    // region 1 (aware): 2048 16B chunks
#pragma unroll
    for (int i = 0; i < 8; ++i) {
        int lin = tid + i * 256;
        int row = lin >> 4, kg = lin & 15;
        uint4 v = *(const uint4*)&awL[row * 128 + kg * 8];
        int kglob = 1024 + n0 + kg * 8;
        size_t tbase = ((size_t)tm * 48 + (kglob >> 6)) * 16384;
        *(uint4*)(Asw + tbase + TSW(row, (kglob & 63) * 2)) = v;
    }
    // regions 0 (h) and 2 (h*aware)
#pragma unroll
    for (int i = 0; i < 8; ++i) {
        int lin = tid + i * 256;
        int row = lin >> 4, kg = lin & 15;
        const float4* hp = (const float4*)&h[(size_t)(m0 + row) * NH + n0 + kg * 8];
        float4 ha = hp[0], hb = hp[1];
        float hv[8] = {ha.x, ha.y, ha.z, ha.w, hb.x, hb.y, hb.z, hb.w};
        uint4 awv = *(const uint4*)&awL[row * 128 + kg * 8];
        unsigned int awu[4] = {awv.x, awv.y, awv.z, awv.w};
        unsigned int p0[4], p2[4];
#pragma unroll
        for (int j = 0; j < 4; ++j) {
            p0[j] = pk2(hv[2*j], hv[2*j+1]);
            float lo = hv[2*j]   * bf2f(awu[j] & 0xffffu);
            float hi = hv[2*j+1] * bf2f(awu[j] >> 16);
            p2[j] = pk2(lo, hi);
        }
        int k0g = n0 + kg * 8;
        size_t tb0 = ((size_t)tm * 48 + (k0g >> 6)) * 16384;
        *(uint4*)(Asw + tb0 + TSW(row, (k0g & 63) * 2)) = make_uint4(p0[0], p0[1], p0[2], p0[3]);
        int k2g = 2048 + n0 + kg * 8;
        size_t tb2 = ((size_t)tm * 48 + (k2g >> 6)) * 16384;
        *(uint4*)(Asw + tb2 + TSW(row, (k2g & 63) * 2)) = make_uint4(p2[0], p2[1], p2[2], p2[3]);
    }
}

// ---------------------------------------------------------------------------
// Kernel W: WbT swizzled tiles: W^T[n][k] bf16, tile (tn,tk) = [128 n][64 k].
// ---------------------------------------------------------------------------
__global__ __launch_bounds__(256) void kW(const float* __restrict__ Wcat,
                                          char* __restrict__ Wsw) {
    __shared__ unsigned short wt[64 * 128];  // [kk][nn] bf16, 16KB

    const int tid  = threadIdx.x;
    const int tile = blockIdx.x;         // tn*48 + tk
    const int tn   = tile / 48;
    const int tk   = tile - tn * 48;
    const int n00  = tn * 128;
    const int k0   = tk * 64;

#pragma unroll
    for (int i = 0; i < 8; ++i) {
        int lin = tid + i * 256;         // 2048 float4 groups
        int kk = lin >> 5, ng = lin & 31;
        float4 v = *(const float4*)&Wcat[(size_t)(k0 + kk) * NH + n00 + ng * 4];
        unsigned int lo = pk2(v.x, v.y), hi = pk2(v.z, v.w);
        *(uint2*)&wt[kk * 128 + ng * 4] = make_uint2(lo, hi);
    }
    __syncthreads();
#pragma unroll
    for (int i = 0; i < 4; ++i) {
        int lin = tid + i * 256;         // 1024 16B chunks
        int rn = lin >> 3, kg = lin & 7;
        unsigned short t8[8];
#pragma unroll
        for (int j = 0; j < 8; ++j) t8[j] = wt[(kg * 8 + j) * 128 + rn];
        uint4 v = *(const uint4*)t8;
        *(uint4*)(Wsw + (size_t)tile * 16384 + TSW(rn, kg * 16)) = v;
    }
}

// ---------------------------------------------------------------------------
// Kernel Bf (fast): pure bf16 GEMM, 128x128 tile, BK=64, global_load_lds
// staging from pre-swizzled tiles, 2-barrier m97 structure.
// ---------------------------------------------------------------------------
__global__ __launch_bounds__(256) void kBf(const char* __restrict__ Asw,
                                           const char* __restrict__ Wsw,
                                           const float* __restrict__ bcat,
                                           unsigned short* __restrict__ x2) {
    __shared__ __align__(16) char Asl[16384];
    __shared__ __align__(16) char Bsl[16384];

    const int tid  = threadIdx.x;
    const int lane = tid & 63;
    const int wid  = tid >> 6;
    const int wm   = (wid >> 1) * 64;
    const int wn   = (wid & 1) * 64;
    const int lr   = lane & 15;
    const int lk   = lane >> 4;

    const int id   = blockIdx.x;
    const int xcd  = id & 7;
    const int slot = id >> 3;
    const int m0   = (xcd * 16 + (slot >> 3)) * 128;
    const int n0   = (slot & 7) * 128;
    const int tm   = m0 >> 7;
    const int tn   = n0 >> 7;

    f32x4 acc[4][4];
#pragma unroll
    for (int i = 0; i < 4; ++i)
#pragma unroll
        for (int j = 0; j < 4; ++j) acc[i][j] = (f32x4){0.f, 0.f, 0.f, 0.f};

    const int laneOff = wid * 4096 + lane * 16;

    for (int tk = 0; tk < 48; ++tk) {
        const char* tA = Asw + ((size_t)tm * 48 + tk) * 16384;
        const char* tB = Wsw + ((size_t)tn * 48 + tk) * 16384;
#pragma unroll
        for (int j = 0; j < 4; ++j)
            gld16(tA + laneOff + j * 1024, Asl + wid * 4096 + j * 1024);
#pragma unroll
        for (int j = 0; j < 4; ++j)
            gld16(tB + laneOff + j * 1024, Bsl + wid * 4096 + j * 1024);
        __syncthreads();

#pragma unroll
        for (int ks = 0; ks < 2; ++ks) {
            bf16x8 af[4], bfr[4];
#pragma unroll
            for (int mf = 0; mf < 4; ++mf) {
                int row = wm + mf * 16 + lr;
                af[mf] = *(const bf16x8*)(Asl + TSW(row, ks * 64 + lk * 16));
            }
#pragma unroll
            for (int nf = 0; nf < 4; ++nf) {
                int rown = wn + nf * 16 + lr;
                bfr[nf] = *(const bf16x8*)(Bsl + TSW(rown, ks * 64 + lk * 16));
            }
#pragma unroll
            for (int mf = 0; mf < 4; ++mf)
#pragma unroll
                for (int nf = 0; nf < 4; ++nf)
                    acc[mf][nf] = __builtin_amdgcn_mfma_f32_16x16x32_bf16(af[mf], bfr[nf], acc[mf][nf], 0, 0, 0);
        }
        __syncthreads();
    }

#pragma unroll
    for (int nf = 0; nf < 4; ++nf) {
        const int col = n0 + wn + nf*16 + lr;
        const float bc = bcat[col];
#pragma unroll
        for (int mf = 0; mf < 4; ++mf)
#pragma unroll
            for (int r = 0; r < 4; ++r) {
                size_t row = (size_t)(m0 + wm + mf*16 + lk*4 + r);
                float x = acc[mf][nf][r] + bc;
                float g = 0.5f * x * (1.0f + erff(x * 0.70710678118654752f));
                x2[row * NH + col] = f2bf(g);
            }
    }
}

// ---------------------------------------------------------------------------
// Kernel B (fallback): reg-staged mixed GEMM (round-4 version).
// ---------------------------------------------------------------------------
__global__ __launch_bounds__(256) void kB(const float* __restrict__ h,
                                          const unsigned short* __restrict__ aware,
                                          const float* __restrict__ Wcat,
                                          const float* __restrict__ bcat,
                                          unsigned short* __restrict__ x2) {
    __shared__ __align__(16) char lds[16384];
    char* Asl = lds;
    char* Bsl = lds + 8192;

    const int tid  = threadIdx.x;
    const int lane = tid & 63;
    const int wid  = tid >> 6;
    const int wm   = (wid >> 1) * 64;
    const int wn   = (wid & 1) * 64;
    const int lr   = lane & 15;
    const int lk   = lane >> 4;

    const int id   = blockIdx.x;
    const int xcd  = id & 7;
    const int slot = id >> 3;
    const int m0   = (xcd * 16 + (slot >> 3)) * 128;
    const int n0   = (slot & 7) * 128;

    const int am = tid >> 1;
    const int ak = (tid & 1) * 16;
    const int bn = tid & 127;
    const int bk = (tid >> 7) * 16;

    f32x4 acc[4][4];
#pragma unroll
    for (int i = 0; i < 4; ++i)
#pragma unroll
        for (int j = 0; j < 4; ++j) acc[i][j] = (f32x4){0.f, 0.f, 0.f, 0.f};

    const float*          hrow = h     + (size_t)(m0 + am) * NH + ak;
    const unsigned short* arow = aware + (size_t)(m0 + am) * NH + ak;
    const float*          wcol = Wcat  + (size_t)bk * NH + n0 + bn;

    float hv[16];
    unsigned int aw[8];
    float wv[16];

    auto stage = [&](int kt) {
        const int region = kt >> 10;
        const int kb = kt & 1023;
        if (region != 1) {
            const float4* hp = (const float4*)(hrow + kb);
            float4 a = hp[0], b = hp[1], c = hp[2], d = hp[3];
            hv[0]=a.x; hv[1]=a.y; hv[2]=a.z; hv[3]=a.w;
            hv[4]=b.x; hv[5]=b.y; hv[6]=b.z; hv[7]=b.w;
            hv[8]=c.x; hv[9]=c.y; hv[10]=c.z; hv[11]=c.w;
            hv[12]=d.x; hv[13]=d.y; hv[14]=d.z; hv[15]=d.w;
        }
        if (region >= 1) {
            const uint4* ap = (const uint4*)(arow + kb);
            uint4 a0 = ap[0], a1 = ap[1];
            aw[0]=a0.x; aw[1]=a0.y; aw[2]=a0.z; aw[3]=a0.w;
            aw[4]=a1.x; aw[5]=a1.y; aw[6]=a1.z; aw[7]=a1.w;
        }
        {
            const float* wp = wcol + (size_t)kt * NH;
#pragma unroll
            for (int j = 0; j < 16; ++j) wv[j] = wp[(size_t)j * NH];
        }
    };

    auto writeStage = [&](int kt) {
        const int region = kt >> 10;
        unsigned int p[8];
        if (region == 0) {
#pragma unroll
            for (int i = 0; i < 8; ++i) p[i] = pk2(hv[2*i], hv[2*i+1]);
        } else if (region == 1) {
#pragma unroll
            for (int i = 0; i < 8; ++i) p[i] = aw[i];
        } else {
#pragma unroll
            for (int i = 0; i < 8; ++i) {
                float lo = hv[2*i]   * bf2f(aw[i] & 0xffffu);
                float hi = hv[2*i+1] * bf2f(aw[i] >> 16);
                p[i] = pk2(lo, hi);
            }
        }
        *(int4*)(Asl + SW64(am*64 + ak*2))      = make_int4(p[0], p[1], p[2], p[3]);
        *(int4*)(Asl + SW64(am*64 + ak*2 + 16)) = make_int4(p[4], p[5], p[6], p[7]);
        unsigned int q[8];
#pragma unroll
        for (int i = 0; i < 8; ++i) q[i] = pk2(wv[2*i], wv[2*i+1]);
        *(int4*)(Bsl + SW64(bn*64 + bk*2))      = make_int4(q[0], q[1], q[2], q[3]);
        *(int4*)(Bsl + SW64(bn*64 + bk*2 + 16)) = make_int4(q[4], q[5], q[6], q[7]);
    };

    stage(0);
    for (int kt = 0; kt < 3072; kt += 32) {
        __syncthreads();
        writeStage(kt);
        __syncthreads();
        if (kt + 32 < 3072) stage(kt + 32);

        bf16x8 af[4], bfr[4];
#pragma unroll
        for (int mf = 0; mf < 4; ++mf)
            af[mf] = *(const bf16x8*)(Asl + SW64((wm + mf*16 + lr)*64 + lk*16));
#pragma unroll
        for (int nf = 0; nf < 4; ++nf)
            bfr[nf] = *(const bf16x8*)(Bsl + SW64((wn + nf*16 + lr)*64 + lk*16));
#pragma unroll
        for (int mf = 0; mf < 4; ++mf)
#pragma unroll
            for (int nf = 0; nf < 4; ++nf)
                acc[mf][nf] = __builtin_amdgcn_mfma_f32_16x16x32_bf16(af[mf], bfr[nf], acc[mf][nf], 0, 0, 0);
    }

#pragma unroll
    for (int nf = 0; nf < 4; ++nf) {
        const int col = n0 + wn + nf*16 + lr;
        const float bc = bcat[col];
#pragma unroll
        for (int mf = 0; mf < 4; ++mf)
#pragma unroll
            for (int r = 0; r < 4; ++r) {
                size_t row = (size_t)(m0 + wm + mf*16 + lk*4 + r);
                float x = acc[mf][nf][r] + bc;
                float g = 0.5f * x * (1.0f + erff(x * 0.70710678118654752f));
                x2[row * NH + col] = f2bf(g);
            }
    }
}

// ---------------------------------------------------------------------------
// Kernel C: ner_scores = [x2 @ W_crf + b_crf, -10000, -10000]  (MFMA, N=48)
// ---------------------------------------------------------------------------
__global__ __launch_bounds__(256) void kC(const unsigned short* __restrict__ x2,
                                          const float* __restrict__ Wcrf,
                                          const float* __restrict__ bcrf,
                                          float* __restrict__ out) {
    __shared__ __align__(16) char Asl[8192];
    __shared__ __align__(16) char Bsl[3072];

    const int tid  = threadIdx.x;
    const int lane = tid & 63;
    const int wid  = tid >> 6;
    const int lr   = lane & 15;
    const int lk   = lane >> 4;
    const int m0   = blockIdx.x * 128;
    const int am   = tid >> 1;
    const int ak   = (tid & 1) * 16;

    for (int i = tid; i < 192; i += 256) *(int4*)(Bsl + i*16) = make_int4(0, 0, 0, 0);

    f32x4 acc[2][3];
#pragma unroll
    for (int i = 0; i < 2; ++i)
#pragma unroll
        for (int j = 0; j < 3; ++j) acc[i][j] = (f32x4){0.f, 0.f, 0.f, 0.f};

    const unsigned short* xrow = x2 + (size_t)(m0 + am) * NH + ak;

    for (int kt = 0; kt < NH; kt += 32) {
        const uint4* xp = (const uint4*)(xrow + kt);
        uint4 x0 = xp[0], x1 = xp[1];
        float wv[5];
#pragma unroll
        for (int p = 0; p < 5; ++p) {
            int i = tid + p * 256;
            wv[p] = (i < 32*NT) ? Wcrf[(size_t)kt * NT + i] : 0.f;
        }
        __syncthreads();
        *(uint4*)(Asl + SW64(am*64 + ak*2))      = x0;
        *(uint4*)(Asl + SW64(am*64 + ak*2 + 16)) = x1;
#pragma unroll
        for (int p = 0; p < 5; ++p) {
            int i = tid + p * 256;
            if (i < 32*NT) {
                int kk = i / NT;
                int t  = i - kk * NT;
                *(unsigned short*)(Bsl + SW64(t*64 + kk*2)) = f2bf(wv[p]);
            }
        }
        __syncthreads();
        bf16x8 af[2], bfr[3];
#pragma unroll
        for (int mf = 0; mf < 2; ++mf)
            af[mf] = *(const bf16x8*)(Asl + SW64((wid*32 + mf*16 + lr)*64 + lk*16));
#pragma unroll
        for (int nf = 0; nf < 3; ++nf)
            bfr[nf] = *(const bf16x8*)(Bsl + SW64((nf*16 + lr)*64 + lk*16));
#pragma unroll
        for (int mf = 0; mf < 2; ++mf)
#pragma unroll
            for (int nf = 0; nf < 3; ++nf)
                acc[mf][nf] = __builtin_amdgcn_mfma_f32_16x16x32_bf16(af[mf], bfr[nf], acc[mf][nf], 0, 0, 0);
    }

#pragma unroll
    for (int nf = 0; nf < 3; ++nf) {
        const int t = nf*16 + lr;
        const float bc = (t < NT) ? bcrf[t] : 0.f;
#pragma unroll
        for (int mf = 0; mf < 2; ++mf)
#pragma unroll
            for (int r = 0; r < 4; ++r) {
                size_t row = (size_t)(m0 + wid*32 + mf*16 + lk*4 + r);
                if (t < NT)       out[row * NLP + t] = acc[mf][nf][r] + bc;
                else if (t < NLP) out[row * NLP + t] = -10000.0f;
            }
    }
}

// ---------------------------------------------------------------------------
// Kernel D: CRF log-likelihood, exp-domain scan. One wave per batch.
// ---------------------------------------------------------------------------
__global__ __launch_bounds__(64) void kD(const float* __restrict__ scores,
                                         const int* __restrict__ labels,
                                         const int* __restrict__ lens,
                                         const float* __restrict__ trans,
                                         float* __restrict__ loss) {
    __shared__ float trL[39 * 41];

    const int b = blockIdx.x;
    const int lane = threadIdx.x;

    for (int idx = lane; idx < 39 * 39; idx += 64) {
        int to = idx / 39, f = idx - to * 39;
        trL[to * 41 + f] = trans[idx];
    }
    __syncthreads();

    const int len = lens[b];

    float g = 0.0f;
    for (int t = lane; t < len; t += 64) {
        int lab = labels[b * NS + t];
        g += scores[((size_t)(b * NS + t)) * NLP + lab];
    }
    for (int i = lane; i <= len; i += 64) {
        int frm = (i == 0) ? 37 : labels[b * NS + i - 1];
        int to  = (i == len) ? 38 : labels[b * NS + i];
        g += trL[to * 41 + frm];
    }
#pragma unroll
    for (int off = 32; off > 0; off >>= 1) g += __shfl_xor(g, off, 64);

    const int myrow = (lane < 39) ? lane : 0;
    float trow[39];
#pragma unroll
    for (int f = 0; f < 39; ++f) trow[f] = __expf(trL[myrow * 41 + f]);
    const float trEnd = (lane < 39) ? trL[38 * 41 + lane] : 0.f;

    float a = (lane == 37) ? 1.0f : 0.0f;
    float C = 0.0f;

    float logit_next = (lane < 39 && len > 0)
        ? scores[((size_t)(b * NS)) * NLP + lane] : 0.f;

    for (int t = 0; t < len; ++t) {
        float el = __expf(logit_next);
        if (t + 1 < len && lane < 39)
            logit_next = scores[((size_t)(b * NS + t + 1)) * NLP + lane];

        float acc0 = 0.f, acc1 = 0.f, acc2 = 0.f, acc3 = 0.f;
#pragma unroll
        for (int f = 0; f < 36; f += 4) {
            acc0 = fmaf(rl(a, f),     trow[f],     acc0);
            acc1 = fmaf(rl(a, f + 1), trow[f + 1], acc1);
            acc2 = fmaf(rl(a, f + 2), trow[f + 2], acc2);
            acc3 = fmaf(rl(a, f + 3), trow[f + 3], acc3);
        }
        acc0 = fmaf(rl(a, 36), trow[36], acc0);
        acc1 = fmaf(rl(a, 37), trow[37], acc1);
        acc2 = fmaf(rl(a, 38), trow[38], acc2);
        float acc = (acc0 + acc1) + (acc2 + acc3);

        a = (lane < 39) ? el * acc : 0.f;

        if ((t & 3) == 3) {
            float s = a;
#pragma unroll
            for (int off = 32; off > 0; off >>= 1) s = fmaxf(s, __shfl_xor(s, off, 64));
            float inv = 1.0f / s;
            a *= inv;
            C += __logf(s);
        }
    }

    float aend = (lane < 39 && a > 0.f) ? C + __logf(a) + trEnd : -1e30f;
    float mx = aend;
#pragma unroll
    for (int off = 32; off > 0; off >>= 1) mx = fmaxf(mx, __shfl_xor(mx, off, 64));
    float es = (lane < 39) ? __expf(aend - mx) : 0.0f;
#pragma unroll
    for (int off = 32; off > 0; off >>= 1) es += __shfl_xor(es, off, 64);
    float norm = mx + __logf(es);

    if (lane == 0) loss[b] = g - norm;
}

// ---------------------------------------------------------------------------
extern "C" void kernel_launch(void* const* d_in, const int* in_sizes, int n_in,
                              void* d_out, int out_size, void* d_ws, size_t ws_size,
                              hipStream_t stream) {
    const float* h        = (const float*)d_in[0];
    const int* token_nums = (const int*)d_in[2];
    const int* labels     = (const int*)d_in[3];
    const float* bio      = (const float*)d_in[4];
    const float* Wcat     = (const float*)d_in[5];
    const float* bcat     = (const float*)d_in[6];
    const float* Wcrf     = (const float*)d_in[7];
    const float* bcrf     = (const float*)d_in[8];
    const float* trans    = (const float*)d_in[9];

    float* out = (float*)d_out;
    unsigned short* attn  = (unsigned short*)d_out;  // 2MB scratch, overwritten by kC

    const size_t ASW_BYTES = (size_t)128 * 48 * 16384;        // 96 MB
    const size_t X2_BYTES  = (size_t)NM * NH * 2;             // 32 MB
    const size_t WSW_BYTES = (size_t)8 * 48 * 16384;          // 6 MB
    const bool fast = ws_size >= ASW_BYTES + X2_BYTES + WSW_BYTES;

    hipLaunchKernelGGL(kA1, dim3(NM / 64), dim3(256), 0, stream, h, bio, attn);

    if (fast) {
        char* Asw           = (char*)d_ws;
        unsigned short* x2  = (unsigned short*)((char*)d_ws + ASW_BYTES);
        char* Wsw           = (char*)d_ws + ASW_BYTES + X2_BYTES;

        hipLaunchKernelGGL(kW, dim3(8 * 48), dim3(256), 0, stream, Wcat, Wsw);
        hipLaunchKernelGGL(kA2f, dim3(NH / 128, NM / 128), dim3(256), 0, stream,
                           attn, bio, h, Asw);
        hipLaunchKernelGGL(kBf, dim3((NH / 128) * (NM / 128)), dim3(256), 0, stream,
                           Asw, Wsw, bcat, x2);
        hipLaunchKernelGGL(kC, dim3(NM / 128), dim3(256), 0, stream, x2, Wcrf, bcrf, out);
    } else {
        unsigned short* aware = (unsigned short*)d_ws;
        unsigned short* x2    = aware + (size_t)NM * NH;

        hipLaunchKernelGGL(kA2, dim3(NH / 128, NM / 128), dim3(256), 0, stream, attn, bio, aware);
        hipLaunchKernelGGL(kB, dim3((NH / 128) * (NM / 128)), dim3(256), 0, stream,
                           h, aware, Wcat, bcat, x2);
        hipLaunchKernelGGL(kC, dim3(NM / 128), dim3(256), 0, stream, x2, Wcrf, bcrf, out);
    }

    hipLaunchKernelGGL(kD, dim3(NB), dim3(64), 0, stream, out, labels, token_nums, trans,
                       out + (size_t)NM * NLP);
}

// Round 6
// 349.605 us; speedup vs baseline: 10.7941x; 1.0461x over previous
//
#include <hip/hip_runtime.h>
#include <hip/hip_bf16.h>
#include <math.h>

#define NB 32
#define NS 512
#define NH 1024
#define NT 37
#define NLP 39
#define NM (NB*NS)   // 16384

typedef __attribute__((ext_vector_type(8))) short bf16x8;
typedef __attribute__((ext_vector_type(4))) float f32x4;

__device__ __forceinline__ float bf2f(unsigned int u) {
    unsigned int x = u << 16;
    float f;
    __builtin_memcpy(&f, &x, 4);
    return f;
}
__device__ __forceinline__ unsigned short f2bf(float f) {
    __hip_bfloat16 hb = __float2bfloat16(f);
    unsigned short u;
    __builtin_memcpy(&u, &hb, 2);
    return u;
}
__device__ __forceinline__ unsigned int pk2(float lo, float hi) {
    return ((unsigned int)f2bf(hi) << 16) | (unsigned int)f2bf(lo);
}
// bijective XOR swizzle for [row][64B] bf16 LDS tiles
__device__ __forceinline__ int SW64(int b)  { return b ^ ((b >> 2) & 0x70); }
// tile swizzle for [128 row][64 k] bf16 tiles (row stride 128B): XOR bits4-6 with row&7
__device__ __forceinline__ int TSW(int row, int kcolByte) {
    return (row * 128 + kcolByte) ^ ((row & 7) << 4);
}
__device__ __forceinline__ float rl(float x, int l) {
    return __int_as_float(__builtin_amdgcn_readlane(__float_as_int(x), l));
}
__device__ __forceinline__ void gld16(const void* g, void* l) {
    __builtin_amdgcn_global_load_lds((const __attribute__((address_space(1))) void*)g,
                                     (__attribute__((address_space(3))) void*)l, 16, 0, 0);
}

// ---------------------------------------------------------------------------
// Kernel A1: scores = h@bio^T /32 -> softmax -> attn (bf16, [NM][64], zero-pad)
// ---------------------------------------------------------------------------
__global__ __launch_bounds__(256) void kA1(const float* __restrict__ h,
                                           const float* __restrict__ bio,
                                           unsigned short* __restrict__ attn) {
    __shared__ __align__(16) char Asl[64 * 64];
    __shared__ __align__(16) char Bsl[48 * 64];

    const int tid  = threadIdx.x;
    const int lane = tid & 63;
    const int wid  = tid >> 6;
    const int lr   = lane & 15;
    const int lk   = lane >> 4;
    const int m0   = blockIdx.x * 64;

    const int arow = tid >> 2;
    const int aq   = (tid & 3) * 8;
    const int brow = tid >> 1;
    const int bkh  = (tid & 1) * 16;

    f32x4 sacc[3];
#pragma unroll
    for (int j = 0; j < 3; ++j) sacc[j] = (f32x4){0.f, 0.f, 0.f, 0.f};

    const float* hrow = h + (size_t)(m0 + arow) * NH + aq;

    for (int kt = 0; kt < NH; kt += 32) {
        float hv[8];
        {
            const float4* hp = (const float4*)(hrow + kt);
            float4 a = hp[0], b = hp[1];
            hv[0]=a.x; hv[1]=a.y; hv[2]=a.z; hv[3]=a.w;
            hv[4]=b.x; hv[5]=b.y; hv[6]=b.z; hv[7]=b.w;
        }
        float bv[16];
        if (tid < 96) {
            if (brow < NT) {
                const float4* bp = (const float4*)(bio + (size_t)brow * NH + kt + bkh);
                float4 a = bp[0], b = bp[1], c = bp[2], d = bp[3];
                bv[0]=a.x; bv[1]=a.y; bv[2]=a.z; bv[3]=a.w;
                bv[4]=b.x; bv[5]=b.y; bv[6]=b.z; bv[7]=b.w;
                bv[8]=c.x; bv[9]=c.y; bv[10]=c.z; bv[11]=c.w;
                bv[12]=d.x; bv[13]=d.y; bv[14]=d.z; bv[15]=d.w;
            } else {
#pragma unroll
                for (int i = 0; i < 16; ++i) bv[i] = 0.f;
            }
        }
        __syncthreads();
        {
            unsigned int p[4];
#pragma unroll
            for (int i = 0; i < 4; ++i) p[i] = pk2(hv[2*i], hv[2*i+1]);
            *(int4*)(Asl + SW64(arow*64 + aq*2)) = make_int4(p[0], p[1], p[2], p[3]);
        }
        if (tid < 96) {
            unsigned int p[8];
#pragma unroll
            for (int i = 0; i < 8; ++i) p[i] = pk2(bv[2*i], bv[2*i+1]);
            *(int4*)(Bsl + SW64(brow*64 + bkh*2))      = make_int4(p[0], p[1], p[2], p[3]);
            *(int4*)(Bsl + SW64(brow*64 + bkh*2 + 16)) = make_int4(p[4], p[5], p[6], p[7]);
        }
        __syncthreads();
        bf16x8 af = *(const bf16x8*)(Asl + SW64((wid*16 + lr)*64 + lk*16));
#pragma unroll
        for (int nf = 0; nf < 3; ++nf) {
            bf16x8 bfr = *(const bf16x8*)(Bsl + SW64((nf*16 + lr)*64 + lk*16));
            sacc[nf] = __builtin_amdgcn_mfma_f32_16x16x32_bf16(af, bfr, sacc[nf], 0, 0, 0);
        }
    }

#pragma unroll
    for (int r = 0; r < 4; ++r) {
        const int row = wid*16 + lk*4 + r;
        float s0 = sacc[0][r] * 0.03125f;
        float s1 = sacc[1][r] * 0.03125f;
        float s2 = sacc[2][r] * 0.03125f;
        const bool v2 = (lr < 5);
        float mx = fmaxf(fmaxf(s0, s1), v2 ? s2 : -1e30f);
#pragma unroll
        for (int d = 1; d < 16; d <<= 1) mx = fmaxf(mx, __shfl_xor(mx, d, 64));
        float e0 = __expf(s0 - mx), e1 = __expf(s1 - mx);
        float e2 = v2 ? __expf(s2 - mx) : 0.f;
        float sm = e0 + e1 + e2;
#pragma unroll
        for (int d = 1; d < 16; d <<= 1) sm += __shfl_xor(sm, d, 64);
        float inv = 1.f / sm;
        size_t g = (size_t)(m0 + row) * 64;
        attn[g + lr]      = f2bf(e0 * inv);
        attn[g + 16 + lr] = f2bf(e1 * inv);
        attn[g + 32 + lr] = f2bf(e2 * inv);
        attn[g + 48 + lr] = 0;
    }
}

// ---------------------------------------------------------------------------
// Kernel A2 (fallback): aware = attn @ bio, plain bf16 row-major out.
// ---------------------------------------------------------------------------
__global__ __launch_bounds__(256) void kA2(const unsigned short* __restrict__ attn,
                                           const float* __restrict__ bio,
                                           unsigned short* __restrict__ aware) {
    __shared__ __align__(16) char Bsl[128 * 64];

    const int tid  = threadIdx.x;
    const int lane = tid & 63;
    const int wid  = tid >> 6;
    const int wm   = (wid >> 1) * 64;
    const int wn   = (wid & 1) * 64;
    const int lr   = lane & 15;
    const int lk   = lane >> 4;
    const int n0   = blockIdx.x * 128;
    const int m0   = blockIdx.y * 128;

    const int bn = tid & 127;
    const int bq = (tid >> 7) * 16;

    f32x4 acc[4][4];
#pragma unroll
    for (int i = 0; i < 4; ++i)
#pragma unroll
        for (int j = 0; j < 4; ++j) acc[i][j] = (f32x4){0.f, 0.f, 0.f, 0.f};

#pragma unroll
    for (int ks = 0; ks < 2; ++ks) {
        unsigned int p[8];
#pragma unroll
        for (int i = 0; i < 8; ++i) {
            int t0 = ks*32 + bq + 2*i;
            float lo = (t0     < NT) ? bio[(size_t)t0 * NH + n0 + bn]       : 0.f;
            float hi = (t0 + 1 < NT) ? bio[(size_t)(t0+1) * NH + n0 + bn]   : 0.f;
            p[i] = pk2(lo, hi);
        }
        __syncthreads();
        *(int4*)(Bsl + SW64(bn*64 + bq*2))      = make_int4(p[0], p[1], p[2], p[3]);
        *(int4*)(Bsl + SW64(bn*64 + bq*2 + 16)) = make_int4(p[4], p[5], p[6], p[7]);
        __syncthreads();

        bf16x8 af[4];
#pragma unroll
        for (int mf = 0; mf < 4; ++mf)
            af[mf] = *(const bf16x8*)(attn + (size_t)(m0 + wm + mf*16 + lr) * 64 + ks*32 + lk*8);
#pragma unroll
        for (int nf = 0; nf < 4; ++nf) {
            bf16x8 bb = *(const bf16x8*)(Bsl + SW64((wn + nf*16 + lr)*64 + lk*16));
#pragma unroll
            for (int mf = 0; mf < 4; ++mf)
                acc[mf][nf] = __builtin_amdgcn_mfma_f32_16x16x32_bf16(af[mf], bb, acc[mf][nf], 0, 0, 0);
        }
    }

#pragma unroll
    for (int mf = 0; mf < 4; ++mf)
#pragma unroll
        for (int nf = 0; nf < 4; ++nf)
#pragma unroll
            for (int r = 0; r < 4; ++r) {
                size_t row = (size_t)(m0 + wm + mf*16 + lk*4 + r);
                aware[row * NH + n0 + wn + nf*16 + lr] = f2bf(acc[mf][nf][r]);
            }
}

// ---------------------------------------------------------------------------
// Kernel A2f (fast): computes aware chunk AND writes the full concat-A
// [h | aware | h*aware] in bf16, tile-major (128x64 tiles) with TSW swizzle.
// ---------------------------------------------------------------------------
__global__ __launch_bounds__(256) void kA2f(const unsigned short* __restrict__ attn,
                                            const float* __restrict__ bio,
                                            const float* __restrict__ h,
                                            char* __restrict__ Asw) {
    __shared__ __align__(16) char Bsl[128 * 64];
    __shared__ __align__(16) unsigned short awL[128 * 128];  // 32KB aware chunk

    const int tid  = threadIdx.x;
    const int lane = tid & 63;
    const int wid  = tid >> 6;
    const int wm   = (wid >> 1) * 64;
    const int wn   = (wid & 1) * 64;
    const int lr   = lane & 15;
    const int lk   = lane >> 4;
    const int n0   = blockIdx.x * 128;
    const int m0   = blockIdx.y * 128;
    const int tm   = blockIdx.y;

    const int bn = tid & 127;
    const int bq = (tid >> 7) * 16;

    f32x4 acc[4][4];
#pragma unroll
    for (int i = 0; i < 4; ++i)
#pragma unroll
        for (int j = 0; j < 4; ++j) acc[i][j] = (f32x4){0.f, 0.f, 0.f, 0.f};

#pragma unroll
    for (int ks = 0; ks < 2; ++ks) {
        unsigned int p[8];
#pragma unroll
        for (int i = 0; i < 8; ++i) {
            int t0 = ks*32 + bq + 2*i;
            float lo = (t0     < NT) ? bio[(size_t)t0 * NH + n0 + bn]       : 0.f;
            float hi = (t0 + 1 < NT) ? bio[(size_t)(t0+1) * NH + n0 + bn]   : 0.f;
            p[i] = pk2(lo, hi);
        }
        __syncthreads();
        *(int4*)(Bsl + SW64(bn*64 + bq*2))      = make_int4(p[0], p[1], p[2], p[3]);
        *(int4*)(Bsl + SW64(bn*64 + bq*2 + 16)) = make_int4(p[4], p[5], p[6], p[7]);
        __syncthreads();

        bf16x8 af[4];
#pragma unroll
        for (int mf = 0; mf < 4; ++mf)
            af[mf] = *(const bf16x8*)(attn + (size_t)(m0 + wm + mf*16 + lr) * 64 + ks*32 + lk*8);
#pragma unroll
        for (int nf = 0; nf < 4; ++nf) {
            bf16x8 bb = *(const bf16x8*)(Bsl + SW64((wn + nf*16 + lr)*64 + lk*16));
#pragma unroll
            for (int mf = 0; mf < 4; ++mf)
                acc[mf][nf] = __builtin_amdgcn_mfma_f32_16x16x32_bf16(af[mf], bb, acc[mf][nf], 0, 0, 0);
        }
    }

#pragma unroll
    for (int mf = 0; mf < 4; ++mf)
#pragma unroll
        for (int nf = 0; nf < 4; ++nf)
#pragma unroll
            for (int r = 0; r < 4; ++r)
                awL[(wm + mf*16 + lk*4 + r) * 128 + wn + nf*16 + lr] = f2bf(acc[mf][nf][r]);
    __syncthreads();

    // region 1 (aware)
#pragma unroll
    for (int i = 0; i < 8; ++i) {
        int lin = tid + i * 256;
        int row = lin >> 4, kg = lin & 15;
        uint4 v = *(const uint4*)&awL[row * 128 + kg * 8];
        int kglob = 1024 + n0 + kg * 8;
        size_t tbase = ((size_t)tm * 48 + (kglob >> 6)) * 16384;
        *(uint4*)(Asw + tbase + TSW(row, (kglob & 63) * 2)) = v;
    }
    // regions 0 (h) and 2 (h*aware)
#pragma unroll
    for (int i = 0; i < 8; ++i) {
        int lin = tid + i * 256;
        int row = lin >> 4, kg = lin & 15;
        const float4* hp = (const float4*)&h[(size_t)(m0 + row) * NH + n0 + kg * 8];
        float4 ha = hp[0], hb = hp[1];
        float hv[8] = {ha.x, ha.y, ha.z, ha.w, hb.x, hb.y, hb.z, hb.w};
        uint4 awv = *(const uint4*)&awL[row * 128 + kg * 8];
        unsigned int awu[4] = {awv.x, awv.y, awv.z, awv.w};
        unsigned int p0[4], p2[4];
#pragma unroll
        for (int j = 0; j < 4; ++j) {
            p0[j] = pk2(hv[2*j], hv[2*j+1]);
            float lo = hv[2*j]   * bf2f(awu[j] & 0xffffu);
            float hi = hv[2*j+1] * bf2f(awu[j] >> 16);
            p2[j] = pk2(lo, hi);
        }
        int k0g = n0 + kg * 8;
        size_t tb0 = ((size_t)tm * 48 + (k0g >> 6)) * 16384;
        *(uint4*)(Asw + tb0 + TSW(row, (k0g & 63) * 2)) = make_uint4(p0[0], p0[1], p0[2], p0[3]);
        int k2g = 2048 + n0 + kg * 8;
        size_t tb2 = ((size_t)tm * 48 + (k2g >> 6)) * 16384;
        *(uint4*)(Asw + tb2 + TSW(row, (k2g & 63) * 2)) = make_uint4(p2[0], p2[1], p2[2], p2[3]);
    }
}

// ---------------------------------------------------------------------------
// Kernel W: WbT swizzled tiles: W^T[n][k] bf16, tile (tn,tk) = [128 n][64 k].
// ---------------------------------------------------------------------------
__global__ __launch_bounds__(256) void kW(const float* __restrict__ Wcat,
                                          char* __restrict__ Wsw) {
    __shared__ unsigned short wt[64 * 128];

    const int tid  = threadIdx.x;
    const int tile = blockIdx.x;
    const int tn   = tile / 48;
    const int tk   = tile - tn * 48;
    const int n00  = tn * 128;
    const int k0   = tk * 64;

#pragma unroll
    for (int i = 0; i < 8; ++i) {
        int lin = tid + i * 256;
        int kk = lin >> 5, ng = lin & 31;
        float4 v = *(const float4*)&Wcat[(size_t)(k0 + kk) * NH + n00 + ng * 4];
        unsigned int lo = pk2(v.x, v.y), hi = pk2(v.z, v.w);
        *(uint2*)&wt[kk * 128 + ng * 4] = make_uint2(lo, hi);
    }
    __syncthreads();
#pragma unroll
    for (int i = 0; i < 4; ++i) {
        int lin = tid + i * 256;
        int rn = lin >> 3, kg = lin & 7;
        unsigned short t8[8];
#pragma unroll
        for (int j = 0; j < 8; ++j) t8[j] = wt[(kg * 8 + j) * 128 + rn];
        uint4 v = *(const uint4*)t8;
        *(uint4*)(Wsw + (size_t)tile * 16384 + TSW(rn, kg * 16)) = v;
    }
}

// ---------------------------------------------------------------------------
// Kernel Bf (fast): pure bf16 GEMM, 128x128 tile, BK=64, global_load_lds
// staging from pre-swizzled tiles, 2-barrier m97 structure.
// ---------------------------------------------------------------------------
__global__ __launch_bounds__(256) void kBf(const char* __restrict__ Asw,
                                           const char* __restrict__ Wsw,
                                           const float* __restrict__ bcat,
                                           unsigned short* __restrict__ x2) {
    __shared__ __align__(16) char Asl[16384];
    __shared__ __align__(16) char Bsl[16384];

    const int tid  = threadIdx.x;
    const int lane = tid & 63;
    const int wid  = tid >> 6;
    const int wm   = (wid >> 1) * 64;
    const int wn   = (wid & 1) * 64;
    const int lr   = lane & 15;
    const int lk   = lane >> 4;

    const int id   = blockIdx.x;
    const int xcd  = id & 7;
    const int slot = id >> 3;
    const int m0   = (xcd * 16 + (slot >> 3)) * 128;
    const int n0   = (slot & 7) * 128;
    const int tm   = m0 >> 7;
    const int tn   = n0 >> 7;

    f32x4 acc[4][4];
#pragma unroll
    for (int i = 0; i < 4; ++i)
#pragma unroll
        for (int j = 0; j < 4; ++j) acc[i][j] = (f32x4){0.f, 0.f, 0.f, 0.f};

    const int laneOff = wid * 4096 + lane * 16;

    for (int tk = 0; tk < 48; ++tk) {
        const char* tA = Asw + ((size_t)tm * 48 + tk) * 16384;
        const char* tB = Wsw + ((size_t)tn * 48 + tk) * 16384;
#pragma unroll
        for (int j = 0; j < 4; ++j)
            gld16(tA + laneOff + j * 1024, Asl + wid * 4096 + j * 1024);
#pragma unroll
        for (int j = 0; j < 4; ++j)
            gld16(tB + laneOff + j * 1024, Bsl + wid * 4096 + j * 1024);
        __syncthreads();

#pragma unroll
        for (int ks = 0; ks < 2; ++ks) {
            bf16x8 af[4], bfr[4];
#pragma unroll
            for (int mf = 0; mf < 4; ++mf) {
                int row = wm + mf * 16 + lr;
                af[mf] = *(const bf16x8*)(Asl + TSW(row, ks * 64 + lk * 16));
            }
#pragma unroll
            for (int nf = 0; nf < 4; ++nf) {
                int rown = wn + nf * 16 + lr;
                bfr[nf] = *(const bf16x8*)(Bsl + TSW(rown, ks * 64 + lk * 16));
            }
#pragma unroll
            for (int mf = 0; mf < 4; ++mf)
#pragma unroll
                for (int nf = 0; nf < 4; ++nf)
                    acc[mf][nf] = __builtin_amdgcn_mfma_f32_16x16x32_bf16(af[mf], bfr[nf], acc[mf][nf], 0, 0, 0);
        }
        __syncthreads();
    }

#pragma unroll
    for (int nf = 0; nf < 4; ++nf) {
        const int col = n0 + wn + nf*16 + lr;
        const float bc = bcat[col];
#pragma unroll
        for (int mf = 0; mf < 4; ++mf)
#pragma unroll
            for (int r = 0; r < 4; ++r) {
                size_t row = (size_t)(m0 + wm + mf*16 + lk*4 + r);
                float x = acc[mf][nf][r] + bc;
                float g = 0.5f * x * (1.0f + erff(x * 0.70710678118654752f));
                x2[row * NH + col] = f2bf(g);
            }
    }
}

// ---------------------------------------------------------------------------
// Kernel B (fallback): reg-staged mixed GEMM (round-4 version).
// ---------------------------------------------------------------------------
__global__ __launch_bounds__(256) void kB(const float* __restrict__ h,
                                          const unsigned short* __restrict__ aware,
                                          const float* __restrict__ Wcat,
                                          const float* __restrict__ bcat,
                                          unsigned short* __restrict__ x2) {
    __shared__ __align__(16) char lds[16384];
    char* Asl = lds;
    char* Bsl = lds + 8192;

    const int tid  = threadIdx.x;
    const int lane = tid & 63;
    const int wid  = tid >> 6;
    const int wm   = (wid >> 1) * 64;
    const int wn   = (wid & 1) * 64;
    const int lr   = lane & 15;
    const int lk   = lane >> 4;

    const int id   = blockIdx.x;
    const int xcd  = id & 7;
    const int slot = id >> 3;
    const int m0   = (xcd * 16 + (slot >> 3)) * 128;
    const int n0   = (slot & 7) * 128;

    const int am = tid >> 1;
    const int ak = (tid & 1) * 16;
    const int bn = tid & 127;
    const int bk = (tid >> 7) * 16;

    f32x4 acc[4][4];
#pragma unroll
    for (int i = 0; i < 4; ++i)
#pragma unroll
        for (int j = 0; j < 4; ++j) acc[i][j] = (f32x4){0.f, 0.f, 0.f, 0.f};

    const float*          hrow = h     + (size_t)(m0 + am) * NH + ak;
    const unsigned short* arow = aware + (size_t)(m0 + am) * NH + ak;
    const float*          wcol = Wcat  + (size_t)bk * NH + n0 + bn;

    float hv[16];
    unsigned int aw[8];
    float wv[16];

    auto stage = [&](int kt) {
        const int region = kt >> 10;
        const int kb = kt & 1023;
        if (region != 1) {
            const float4* hp = (const float4*)(hrow + kb);
            float4 a = hp[0], b = hp[1], c = hp[2], d = hp[3];
            hv[0]=a.x; hv[1]=a.y; hv[2]=a.z; hv[3]=a.w;
            hv[4]=b.x; hv[5]=b.y; hv[6]=b.z; hv[7]=b.w;
            hv[8]=c.x; hv[9]=c.y; hv[10]=c.z; hv[11]=c.w;
            hv[12]=d.x; hv[13]=d.y; hv[14]=d.z; hv[15]=d.w;
        }
        if (region >= 1) {
            const uint4* ap = (const uint4*)(arow + kb);
            uint4 a0 = ap[0], a1 = ap[1];
            aw[0]=a0.x; aw[1]=a0.y; aw[2]=a0.z; aw[3]=a0.w;
            aw[4]=a1.x; aw[5]=a1.y; aw[6]=a1.z; aw[7]=a1.w;
        }
        {
            const float* wp = wcol + (size_t)kt * NH;
#pragma unroll
            for (int j = 0; j < 16; ++j) wv[j] = wp[(size_t)j * NH];
        }
    };

    auto writeStage = [&](int kt) {
        const int region = kt >> 10;
        unsigned int p[8];
        if (region == 0) {
#pragma unroll
            for (int i = 0; i < 8; ++i) p[i] = pk2(hv[2*i], hv[2*i+1]);
        } else if (region == 1) {
#pragma unroll
            for (int i = 0; i < 8; ++i) p[i] = aw[i];
        } else {
#pragma unroll
            for (int i = 0; i < 8; ++i) {
                float lo = hv[2*i]   * bf2f(aw[i] & 0xffffu);
                float hi = hv[2*i+1] * bf2f(aw[i] >> 16);
                p[i] = pk2(lo, hi);
            }
        }
        *(int4*)(Asl + SW64(am*64 + ak*2))      = make_int4(p[0], p[1], p[2], p[3]);
        *(int4*)(Asl + SW64(am*64 + ak*2 + 16)) = make_int4(p[4], p[5], p[6], p[7]);
        unsigned int q[8];
#pragma unroll
        for (int i = 0; i < 8; ++i) q[i] = pk2(wv[2*i], wv[2*i+1]);
        *(int4*)(Bsl + SW64(bn*64 + bk*2))      = make_int4(q[0], q[1], q[2], q[3]);
        *(int4*)(Bsl + SW64(bn*64 + bk*2 + 16)) = make_int4(q[4], q[5], q[6], q[7]);
    };

    stage(0);
    for (int kt = 0; kt < 3072; kt += 32) {
        __syncthreads();
        writeStage(kt);
        __syncthreads();
        if (kt + 32 < 3072) stage(kt + 32);

        bf16x8 af[4], bfr[4];
#pragma unroll
        for (int mf = 0; mf < 4; ++mf)
            af[mf] = *(const bf16x8*)(Asl + SW64((wm + mf*16 + lr)*64 + lk*16));
#pragma unroll
        for (int nf = 0; nf < 4; ++nf)
            bfr[nf] = *(const bf16x8*)(Bsl + SW64((wn + nf*16 + lr)*64 + lk*16));
#pragma unroll
        for (int mf = 0; mf < 4; ++mf)
#pragma unroll
            for (int nf = 0; nf < 4; ++nf)
                acc[mf][nf] = __builtin_amdgcn_mfma_f32_16x16x32_bf16(af[mf], bfr[nf], acc[mf][nf], 0, 0, 0);
    }

#pragma unroll
    for (int nf = 0; nf < 4; ++nf) {
        const int col = n0 + wn + nf*16 + lr;
        const float bc = bcat[col];
#pragma unroll
        for (int mf = 0; mf < 4; ++mf)
#pragma unroll
            for (int r = 0; r < 4; ++r) {
                size_t row = (size_t)(m0 + wm + mf*16 + lk*4 + r);
                float x = acc[mf][nf][r] + bc;
                float g = 0.5f * x * (1.0f + erff(x * 0.70710678118654752f));
                x2[row * NH + col] = f2bf(g);
            }
    }
}

// ---------------------------------------------------------------------------
// Kernel C: ner_scores = [x2 @ W_crf + b_crf, -10000, -10000]  (MFMA, N=48)
// ---------------------------------------------------------------------------
__global__ __launch_bounds__(256) void kC(const unsigned short* __restrict__ x2,
                                          const float* __restrict__ Wcrf,
                                          const float* __restrict__ bcrf,
                                          float* __restrict__ out) {
    __shared__ __align__(16) char Asl[8192];
    __shared__ __align__(16) char Bsl[3072];

    const int tid  = threadIdx.x;
    const int lane = tid & 63;
    const int wid  = tid >> 6;
    const int lr   = lane & 15;
    const int lk   = lane >> 4;
    const int m0   = blockIdx.x * 128;
    const int am   = tid >> 1;
    const int ak   = (tid & 1) * 16;

    for (int i = tid; i < 192; i += 256) *(int4*)(Bsl + i*16) = make_int4(0, 0, 0, 0);

    f32x4 acc[2][3];
#pragma unroll
    for (int i = 0; i < 2; ++i)
#pragma unroll
        for (int j = 0; j < 3; ++j) acc[i][j] = (f32x4){0.f, 0.f, 0.f, 0.f};

    const unsigned short* xrow = x2 + (size_t)(m0 + am) * NH + ak;

    for (int kt = 0; kt < NH; kt += 32) {
        const uint4* xp = (const uint4*)(xrow + kt);
        uint4 x0 = xp[0], x1 = xp[1];
        float wv[5];
#pragma unroll
        for (int p = 0; p < 5; ++p) {
            int i = tid + p * 256;
            wv[p] = (i < 32*NT) ? Wcrf[(size_t)kt * NT + i] : 0.f;
        }
        __syncthreads();
        *(uint4*)(Asl + SW64(am*64 + ak*2))      = x0;
        *(uint4*)(Asl + SW64(am*64 + ak*2 + 16)) = x1;
#pragma unroll
        for (int p = 0; p < 5; ++p) {
            int i = tid + p * 256;
            if (i < 32*NT) {
                int kk = i / NT;
                int t  = i - kk * NT;
                *(unsigned short*)(Bsl + SW64(t*64 + kk*2)) = f2bf(wv[p]);
            }
        }
        __syncthreads();
        bf16x8 af[2], bfr[3];
#pragma unroll
        for (int mf = 0; mf < 2; ++mf)
            af[mf] = *(const bf16x8*)(Asl + SW64((wid*32 + mf*16 + lr)*64 + lk*16));
#pragma unroll
        for (int nf = 0; nf < 3; ++nf)
            bfr[nf] = *(const bf16x8*)(Bsl + SW64((nf*16 + lr)*64 + lk*16));
#pragma unroll
        for (int mf = 0; mf < 2; ++mf)
#pragma unroll
            for (int nf = 0; nf < 3; ++nf)
                acc[mf][nf] = __builtin_amdgcn_mfma_f32_16x16x32_bf16(af[mf], bfr[nf], acc[mf][nf], 0, 0, 0);
    }

#pragma unroll
    for (int nf = 0; nf < 3; ++nf) {
        const int t = nf*16 + lr;
        const float bc = (t < NT) ? bcrf[t] : 0.f;
#pragma unroll
        for (int mf = 0; mf < 2; ++mf)
#pragma unroll
            for (int r = 0; r < 4; ++r) {
                size_t row = (size_t)(m0 + wid*32 + mf*16 + lk*4 + r);
                if (t < NT)       out[row * NLP + t] = acc[mf][nf][r] + bc;
                else if (t < NLP) out[row * NLP + t] = -10000.0f;
            }
    }
}

// ---------------------------------------------------------------------------
// Kernel D: CRF log-likelihood, exp-domain scan. One wave per batch.
// Critical-path trims vs round 5:
//  - t=0 closed form (only f=START contributes): a[to] = exp(logit0[to])*e^trans[to][37]
//  - a[37]=a[38]==0 for t>=1 (pad logits -10000 -> el=0), so inner loop is f=0..36
//  - rescale by readlane(a,0) (no ds_bpermute max-butterfly on the serial chain);
//    any positive scale is valid since C compensates: a*=r, C-=log(r)
//  - logit prefetch 2 steps ahead (step time ~ L2 latency)
// ---------------------------------------------------------------------------
__global__ __launch_bounds__(64) void kD(const float* __restrict__ scores,
                                         const int* __restrict__ labels,
                                         const int* __restrict__ lens,
                                         const float* __restrict__ trans,
                                         float* __restrict__ loss) {
    __shared__ float trL[39 * 41];

    const int b = blockIdx.x;
    const int lane = threadIdx.x;

    for (int idx = lane; idx < 39 * 39; idx += 64) {
        int to = idx / 39, f = idx - to * 39;
        trL[to * 41 + f] = trans[idx];
    }
    __syncthreads();

    const int len = lens[b];
    const float* sb = scores + (size_t)b * NS * NLP;

    // gold path score
    float g = 0.0f;
    for (int t = lane; t < len; t += 64) {
        int lab = labels[b * NS + t];
        g += sb[(size_t)t * NLP + lab];
    }
    for (int i = lane; i <= len; i += 64) {
        int frm = (i == 0) ? 37 : labels[b * NS + i - 1];
        int to  = (i == len) ? 38 : labels[b * NS + i];
        g += trL[to * 41 + frm];
    }
#pragma unroll
    for (int off = 32; off > 0; off >>= 1) g += __shfl_xor(g, off, 64);

    const int myrow = (lane < 39) ? lane : 0;
    float trow[39];
#pragma unroll
    for (int f = 0; f < 39; ++f) trow[f] = __expf(trL[myrow * 41 + f]);
    const float trEnd = (lane < 39) ? trL[38 * 41 + lane] : 0.f;

    // t = 0 closed form: alpha0 = e at START only -> a[to] = el0[to]*exp(tr[to][37])
    float l0 = (lane < 39) ? sb[lane] : -10000.f;
    float a = (lane < 39) ? __expf(l0) * trow[37] : 0.f;
    float C = 0.0f;

    // prefetch logits for t=1 and t=2
    float lg1 = (lane < 39 && len > 1) ? sb[NLP + lane] : 0.f;
    float lg2 = (lane < 39 && len > 2) ? sb[2 * NLP + lane] : 0.f;

    for (int t = 1; t < len; ++t) {
        float el = __expf(lg1);
        lg1 = lg2;
        int tp = (t + 2 < len) ? (t + 2) : (len - 1);
        if (lane < 39) lg2 = sb[(size_t)tp * NLP + lane];

        float acc0 = 0.f, acc1 = 0.f, acc2 = 0.f, acc3 = 0.f;
#pragma unroll
        for (int f = 0; f < 36; f += 4) {
            acc0 = fmaf(rl(a, f),     trow[f],     acc0);
            acc1 = fmaf(rl(a, f + 1), trow[f + 1], acc1);
            acc2 = fmaf(rl(a, f + 2), trow[f + 2], acc2);
            acc3 = fmaf(rl(a, f + 3), trow[f + 3], acc3);
        }
        acc0 = fmaf(rl(a, 36), trow[36], acc0);
        float acc = (acc0 + acc1) + (acc2 + acc3);

        a = (lane < 39) ? el * acc : 0.f;

        if ((t & 3) == 3) {
            float s = rl(a, 0);                         // a[0] > 0 always
            float r = __builtin_amdgcn_rcpf(s);
            a *= r;
            C -= __logf(r);
        }
    }

    float aend = (lane < 39 && a > 0.f) ? C + __logf(a) + trEnd : -1e30f;
    float mx = aend;
#pragma unroll
    for (int off = 32; off > 0; off >>= 1) mx = fmaxf(mx, __shfl_xor(mx, off, 64));
    float es = (lane < 39) ? __expf(aend - mx) : 0.0f;
#pragma unroll
    for (int off = 32; off > 0; off >>= 1) es += __shfl_xor(es, off, 64);
    float norm = mx + __logf(es);

    if (lane == 0) loss[b] = g - norm;
}

// ---------------------------------------------------------------------------
extern "C" void kernel_launch(void* const* d_in, const int* in_sizes, int n_in,
                              void* d_out, int out_size, void* d_ws, size_t ws_size,
                              hipStream_t stream) {
    const float* h        = (const float*)d_in[0];
    const int* token_nums = (const int*)d_in[2];
    const int* labels     = (const int*)d_in[3];
    const float* bio      = (const float*)d_in[4];
    const float* Wcat     = (const float*)d_in[5];
    const float* bcat     = (const float*)d_in[6];
    const float* Wcrf     = (const float*)d_in[7];
    const float* bcrf     = (const float*)d_in[8];
    const float* trans    = (const float*)d_in[9];

    float* out = (float*)d_out;
    unsigned short* attn  = (unsigned short*)d_out;  // 2MB scratch, overwritten by kC

    const size_t ASW_BYTES = (size_t)128 * 48 * 16384;        // 96 MB
    const size_t X2_BYTES  = (size_t)NM * NH * 2;             // 32 MB
    const size_t WSW_BYTES = (size_t)8 * 48 * 16384;          // 6 MB
    const bool fast = ws_size >= ASW_BYTES + X2_BYTES + WSW_BYTES;

    hipLaunchKernelGGL(kA1, dim3(NM / 64), dim3(256), 0, stream, h, bio, attn);

    if (fast) {
        char* Asw           = (char*)d_ws;
        unsigned short* x2  = (unsigned short*)((char*)d_ws + ASW_BYTES);
        char* Wsw           = (char*)d_ws + ASW_BYTES + X2_BYTES;

        hipLaunchKernelGGL(kW, dim3(8 * 48), dim3(256), 0, stream, Wcat, Wsw);
        hipLaunchKernelGGL(kA2f, dim3(NH / 128, NM / 128), dim3(256), 0, stream,
                           attn, bio, h, Asw);
        hipLaunchKernelGGL(kBf, dim3((NH / 128) * (NM / 128)), dim3(256), 0, stream,
                           Asw, Wsw, bcat, x2);
        hipLaunchKernelGGL(kC, dim3(NM / 128), dim3(256), 0, stream, x2, Wcrf, bcrf, out);
    } else {
        unsigned short* aware = (unsigned short*)d_ws;
        unsigned short* x2    = aware + (size_t)NM * NH;

        hipLaunchKernelGGL(kA2, dim3(NH / 128, NM / 128), dim3(256), 0, stream, attn, bio, aware);
        hipLaunchKernelGGL(kB, dim3((NH / 128) * (NM / 128)), dim3(256), 0, stream,
                           h, aware, Wcat, bcat, x2);
        hipLaunchKernelGGL(kC, dim3(NM / 128), dim3(256), 0, stream, x2, Wcrf, bcrf, out);
    }

    hipLaunchKernelGGL(kD, dim3(NB), dim3(64), 0, stream, out, labels, token_nums, trans,
                       out + (size_t)NM * NLP);
}

// Round 7
// 347.724 us; speedup vs baseline: 10.8525x; 1.0054x over previous
//
#include <hip/hip_runtime.h>
#include <hip/hip_bf16.h>
#include <math.h>

#define NB 32
#define NS 512
#define NH 1024
#define NT 37
#define NLP 39
#define NM (NB*NS)   // 16384

typedef __attribute__((ext_vector_type(8))) short bf16x8;
typedef __attribute__((ext_vector_type(4))) float f32x4;

__device__ __forceinline__ float bf2f(unsigned int u) {
    unsigned int x = u << 16;
    float f;
    __builtin_memcpy(&f, &x, 4);
    return f;
}
__device__ __forceinline__ unsigned short f2bf(float f) {
    __hip_bfloat16 hb = __float2bfloat16(f);
    unsigned short u;
    __builtin_memcpy(&u, &hb, 2);
    return u;
}
__device__ __forceinline__ unsigned int pk2(float lo, float hi) {
    return ((unsigned int)f2bf(hi) << 16) | (unsigned int)f2bf(lo);
}
// bijective XOR swizzle for [row][64B] bf16 LDS tiles
__device__ __forceinline__ int SW64(int b)  { return b ^ ((b >> 2) & 0x70); }
// tile swizzle for [128 row][64 k] bf16 tiles (row stride 128B)
__device__ __forceinline__ int TSW(int row, int kcolByte) {
    return (row * 128 + kcolByte) ^ ((row & 7) << 4);
}
__device__ __forceinline__ float rl(float x, int l) {
    return __int_as_float(__builtin_amdgcn_readlane(__float_as_int(x), l));
}
__device__ __forceinline__ void gld16(const void* g, void* l) {
    __builtin_amdgcn_global_load_lds((const __attribute__((address_space(1))) void*)g,
                                     (__attribute__((address_space(3))) void*)l, 16, 0, 0);
}

// ---------------------------------------------------------------------------
// Kernel A1: scores = h@bio^T /32 -> softmax -> attn (bf16, [NM][64], zero-pad)
// ---------------------------------------------------------------------------
__global__ __launch_bounds__(256) void kA1(const float* __restrict__ h,
                                           const float* __restrict__ bio,
                                           unsigned short* __restrict__ attn) {
    __shared__ __align__(16) char Asl[64 * 64];
    __shared__ __align__(16) char Bsl[48 * 64];

    const int tid  = threadIdx.x;
    const int lane = tid & 63;
    const int wid  = tid >> 6;
    const int lr   = lane & 15;
    const int lk   = lane >> 4;
    const int m0   = blockIdx.x * 64;

    const int arow = tid >> 2;
    const int aq   = (tid & 3) * 8;
    const int brow = tid >> 1;
    const int bkh  = (tid & 1) * 16;

    f32x4 sacc[3];
#pragma unroll
    for (int j = 0; j < 3; ++j) sacc[j] = (f32x4){0.f, 0.f, 0.f, 0.f};

    const float* hrow = h + (size_t)(m0 + arow) * NH + aq;

    for (int kt = 0; kt < NH; kt += 32) {
        float hv[8];
        {
            const float4* hp = (const float4*)(hrow + kt);
            float4 a = hp[0], b = hp[1];
            hv[0]=a.x; hv[1]=a.y; hv[2]=a.z; hv[3]=a.w;
            hv[4]=b.x; hv[5]=b.y; hv[6]=b.z; hv[7]=b.w;
        }
        float bv[16];
        if (tid < 96) {
            if (brow < NT) {
                const float4* bp = (const float4*)(bio + (size_t)brow * NH + kt + bkh);
                float4 a = bp[0], b = bp[1], c = bp[2], d = bp[3];
                bv[0]=a.x; bv[1]=a.y; bv[2]=a.z; bv[3]=a.w;
                bv[4]=b.x; bv[5]=b.y; bv[6]=b.z; bv[7]=b.w;
                bv[8]=c.x; bv[9]=c.y; bv[10]=c.z; bv[11]=c.w;
                bv[12]=d.x; bv[13]=d.y; bv[14]=d.z; bv[15]=d.w;
            } else {
#pragma unroll
                for (int i = 0; i < 16; ++i) bv[i] = 0.f;
            }
        }
        __syncthreads();
        {
            unsigned int p[4];
#pragma unroll
            for (int i = 0; i < 4; ++i) p[i] = pk2(hv[2*i], hv[2*i+1]);
            *(int4*)(Asl + SW64(arow*64 + aq*2)) = make_int4(p[0], p[1], p[2], p[3]);
        }
        if (tid < 96) {
            unsigned int p[8];
#pragma unroll
            for (int i = 0; i < 8; ++i) p[i] = pk2(bv[2*i], bv[2*i+1]);
            *(int4*)(Bsl + SW64(brow*64 + bkh*2))      = make_int4(p[0], p[1], p[2], p[3]);
            *(int4*)(Bsl + SW64(brow*64 + bkh*2 + 16)) = make_int4(p[4], p[5], p[6], p[7]);
        }
        __syncthreads();
        bf16x8 af = *(const bf16x8*)(Asl + SW64((wid*16 + lr)*64 + lk*16));
#pragma unroll
        for (int nf = 0; nf < 3; ++nf) {
            bf16x8 bfr = *(const bf16x8*)(Bsl + SW64((nf*16 + lr)*64 + lk*16));
            sacc[nf] = __builtin_amdgcn_mfma_f32_16x16x32_bf16(af, bfr, sacc[nf], 0, 0, 0);
        }
    }

#pragma unroll
    for (int r = 0; r < 4; ++r) {
        const int row = wid*16 + lk*4 + r;
        float s0 = sacc[0][r] * 0.03125f;
        float s1 = sacc[1][r] * 0.03125f;
        float s2 = sacc[2][r] * 0.03125f;
        const bool v2 = (lr < 5);
        float mx = fmaxf(fmaxf(s0, s1), v2 ? s2 : -1e30f);
#pragma unroll
        for (int d = 1; d < 16; d <<= 1) mx = fmaxf(mx, __shfl_xor(mx, d, 64));
        float e0 = __expf(s0 - mx), e1 = __expf(s1 - mx);
        float e2 = v2 ? __expf(s2 - mx) : 0.f;
        float sm = e0 + e1 + e2;
#pragma unroll
        for (int d = 1; d < 16; d <<= 1) sm += __shfl_xor(sm, d, 64);
        float inv = 1.f / sm;
        size_t g = (size_t)(m0 + row) * 64;
        attn[g + lr]      = f2bf(e0 * inv);
        attn[g + 16 + lr] = f2bf(e1 * inv);
        attn[g + 32 + lr] = f2bf(e2 * inv);
        attn[g + 48 + lr] = 0;
    }
}

// ---------------------------------------------------------------------------
// Kernel A2 (fallback): aware = attn @ bio, plain bf16 row-major out.
// ---------------------------------------------------------------------------
__global__ __launch_bounds__(256) void kA2(const unsigned short* __restrict__ attn,
                                           const float* __restrict__ bio,
                                           unsigned short* __restrict__ aware) {
    __shared__ __align__(16) char Bsl[128 * 64];

    const int tid  = threadIdx.x;
    const int lane = tid & 63;
    const int wid  = tid >> 6;
    const int wm   = (wid >> 1) * 64;
    const int wn   = (wid & 1) * 64;
    const int lr   = lane & 15;
    const int lk   = lane >> 4;
    const int n0   = blockIdx.x * 128;
    const int m0   = blockIdx.y * 128;

    const int bn = tid & 127;
    const int bq = (tid >> 7) * 16;

    f32x4 acc[4][4];
#pragma unroll
    for (int i = 0; i < 4; ++i)
#pragma unroll
        for (int j = 0; j < 4; ++j) acc[i][j] = (f32x4){0.f, 0.f, 0.f, 0.f};

#pragma unroll
    for (int ks = 0; ks < 2; ++ks) {
        unsigned int p[8];
#pragma unroll
        for (int i = 0; i < 8; ++i) {
            int t0 = ks*32 + bq + 2*i;
            float lo = (t0     < NT) ? bio[(size_t)t0 * NH + n0 + bn]       : 0.f;
            float hi = (t0 + 1 < NT) ? bio[(size_t)(t0+1) * NH + n0 + bn]   : 0.f;
            p[i] = pk2(lo, hi);
        }
        __syncthreads();
        *(int4*)(Bsl + SW64(bn*64 + bq*2))      = make_int4(p[0], p[1], p[2], p[3]);
        *(int4*)(Bsl + SW64(bn*64 + bq*2 + 16)) = make_int4(p[4], p[5], p[6], p[7]);
        __syncthreads();

        bf16x8 af[4];
#pragma unroll
        for (int mf = 0; mf < 4; ++mf)
            af[mf] = *(const bf16x8*)(attn + (size_t)(m0 + wm + mf*16 + lr) * 64 + ks*32 + lk*8);
#pragma unroll
        for (int nf = 0; nf < 4; ++nf) {
            bf16x8 bb = *(const bf16x8*)(Bsl + SW64((wn + nf*16 + lr)*64 + lk*16));
#pragma unroll
            for (int mf = 0; mf < 4; ++mf)
                acc[mf][nf] = __builtin_amdgcn_mfma_f32_16x16x32_bf16(af[mf], bb, acc[mf][nf], 0, 0, 0);
        }
    }

#pragma unroll
    for (int mf = 0; mf < 4; ++mf)
#pragma unroll
        for (int nf = 0; nf < 4; ++nf)
#pragma unroll
            for (int r = 0; r < 4; ++r) {
                size_t row = (size_t)(m0 + wm + mf*16 + lk*4 + r);
                aware[row * NH + n0 + wn + nf*16 + lr] = f2bf(acc[mf][nf][r]);
            }
}

// ---------------------------------------------------------------------------
// Kernel A2f (fast): computes aware chunk AND writes the full concat-A
// [h | aware | h*aware] in bf16, tile-major (128x64 tiles) with TSW swizzle.
// ---------------------------------------------------------------------------
__global__ __launch_bounds__(256) void kA2f(const unsigned short* __restrict__ attn,
                                            const float* __restrict__ bio,
                                            const float* __restrict__ h,
                                            char* __restrict__ Asw) {
    __shared__ __align__(16) char Bsl[128 * 64];
    __shared__ __align__(16) unsigned short awL[128 * 128];  // 32KB aware chunk

    const int tid  = threadIdx.x;
    const int lane = tid & 63;
    const int wid  = tid >> 6;
    const int wm   = (wid >> 1) * 64;
    const int wn   = (wid & 1) * 64;
    const int lr   = lane & 15;
    const int lk   = lane >> 4;
    const int n0   = blockIdx.x * 128;
    const int m0   = blockIdx.y * 128;
    const int tm   = blockIdx.y;

    const int bn = tid & 127;
    const int bq = (tid >> 7) * 16;

    f32x4 acc[4][4];
#pragma unroll
    for (int i = 0; i < 4; ++i)
#pragma unroll
        for (int j = 0; j < 4; ++j) acc[i][j] = (f32x4){0.f, 0.f, 0.f, 0.f};

#pragma unroll
    for (int ks = 0; ks < 2; ++ks) {
        unsigned int p[8];
#pragma unroll
        for (int i = 0; i < 8; ++i) {
            int t0 = ks*32 + bq + 2*i;
            float lo = (t0     < NT) ? bio[(size_t)t0 * NH + n0 + bn]       : 0.f;
            float hi = (t0 + 1 < NT) ? bio[(size_t)(t0+1) * NH + n0 + bn]   : 0.f;
            p[i] = pk2(lo, hi);
        }
        __syncthreads();
        *(int4*)(Bsl + SW64(bn*64 + bq*2))      = make_int4(p[0], p[1], p[2], p[3]);
        *(int4*)(Bsl + SW64(bn*64 + bq*2 + 16)) = make_int4(p[4], p[5], p[6], p[7]);
        __syncthreads();

        bf16x8 af[4];
#pragma unroll
        for (int mf = 0; mf < 4; ++mf)
            af[mf] = *(const bf16x8*)(attn + (size_t)(m0 + wm + mf*16 + lr) * 64 + ks*32 + lk*8);
#pragma unroll
        for (int nf = 0; nf < 4; ++nf) {
            bf16x8 bb = *(const bf16x8*)(Bsl + SW64((wn + nf*16 + lr)*64 + lk*16));
#pragma unroll
            for (int mf = 0; mf < 4; ++mf)
                acc[mf][nf] = __builtin_amdgcn_mfma_f32_16x16x32_bf16(af[mf], bb, acc[mf][nf], 0, 0, 0);
        }
    }

#pragma unroll
    for (int mf = 0; mf < 4; ++mf)
#pragma unroll
        for (int nf = 0; nf < 4; ++nf)
#pragma unroll
            for (int r = 0; r < 4; ++r)
                awL[(wm + mf*16 + lk*4 + r) * 128 + wn + nf*16 + lr] = f2bf(acc[mf][nf][r]);
    __syncthreads();

    // region 1 (aware)
#pragma unroll
    for (int i = 0; i < 8; ++i) {
        int lin = tid + i * 256;
        int row = lin >> 4, kg = lin & 15;
        uint4 v = *(const uint4*)&awL[row * 128 + kg * 8];
        int kglob = 1024 + n0 + kg * 8;
        size_t tbase = ((size_t)tm * 48 + (kglob >> 6)) * 16384;
        *(uint4*)(Asw + tbase + TSW(row, (kglob & 63) * 2)) = v;
    }
    // regions 0 (h) and 2 (h*aware)
#pragma unroll
    for (int i = 0; i < 8; ++i) {
        int lin = tid + i * 256;
        int row = lin >> 4, kg = lin & 15;
        const float4* hp = (const float4*)&h[(size_t)(m0 + row) * NH + n0 + kg * 8];
        float4 ha = hp[0], hb = hp[1];
        float hv[8] = {ha.x, ha.y, ha.z, ha.w, hb.x, hb.y, hb.z, hb.w};
        uint4 awv = *(const uint4*)&awL[row * 128 + kg * 8];
        unsigned int awu[4] = {awv.x, awv.y, awv.z, awv.w};
        unsigned int p0[4], p2[4];
#pragma unroll
        for (int j = 0; j < 4; ++j) {
            p0[j] = pk2(hv[2*j], hv[2*j+1]);
            float lo = hv[2*j]   * bf2f(awu[j] & 0xffffu);
            float hi = hv[2*j+1] * bf2f(awu[j] >> 16);
            p2[j] = pk2(lo, hi);
        }
        int k0g = n0 + kg * 8;
        size_t tb0 = ((size_t)tm * 48 + (k0g >> 6)) * 16384;
        *(uint4*)(Asw + tb0 + TSW(row, (k0g & 63) * 2)) = make_uint4(p0[0], p0[1], p0[2], p0[3]);
        int k2g = 2048 + n0 + kg * 8;
        size_t tb2 = ((size_t)tm * 48 + (k2g >> 6)) * 16384;
        *(uint4*)(Asw + tb2 + TSW(row, (k2g & 63) * 2)) = make_uint4(p2[0], p2[1], p2[2], p2[3]);
    }
}

// ---------------------------------------------------------------------------
// Kernel W: WbT swizzled tiles: W^T[n][k] bf16, tile (tn,tk) = [128 n][64 k].
// ---------------------------------------------------------------------------
__global__ __launch_bounds__(256) void kW(const float* __restrict__ Wcat,
                                          char* __restrict__ Wsw) {
    __shared__ unsigned short wt[64 * 128];

    const int tid  = threadIdx.x;
    const int tile = blockIdx.x;
    const int tn   = tile / 48;
    const int tk   = tile - tn * 48;
    const int n00  = tn * 128;
    const int k0   = tk * 64;

#pragma unroll
    for (int i = 0; i < 8; ++i) {
        int lin = tid + i * 256;
        int kk = lin >> 5, ng = lin & 31;
        float4 v = *(const float4*)&Wcat[(size_t)(k0 + kk) * NH + n00 + ng * 4];
        unsigned int lo = pk2(v.x, v.y), hi = pk2(v.z, v.w);
        *(uint2*)&wt[kk * 128 + ng * 4] = make_uint2(lo, hi);
    }
    __syncthreads();
#pragma unroll
    for (int i = 0; i < 4; ++i) {
        int lin = tid + i * 256;
        int rn = lin >> 3, kg = lin & 7;
        unsigned short t8[8];
#pragma unroll
        for (int j = 0; j < 8; ++j) t8[j] = wt[(kg * 8 + j) * 128 + rn];
        uint4 v = *(const uint4*)t8;
        *(uint4*)(Wsw + (size_t)tile * 16384 + TSW(rn, kg * 16)) = v;
    }
}

// ---------------------------------------------------------------------------
// Kernel Bf (fast): 256x256 tile bf16 GEMM, BK=64, 8 waves, double-buffered
// 128KB LDS, global_load_lds staging with COUNTED vmcnt(8) (never 0 in the
// main loop) + raw s_barriers (no drain). Each wave owns one A-half and one
// B-half, so one wait + two barriers per K-tile suffice.
// ---------------------------------------------------------------------------
__global__ __launch_bounds__(512, 2) void kBf(const char* __restrict__ Asw,
                                              const char* __restrict__ Wsw,
                                              const float* __restrict__ bcat,
                                              unsigned short* __restrict__ x2) {
    __shared__ __align__(16) char lds[131072];  // A: [buf][half][16KB]; B at +65536

    const int tid  = threadIdx.x;
    const int lane = tid & 63;
    const int wid  = tid >> 6;
    const int widm = wid >> 2;       // 0..1
    const int widn = wid & 3;        // 0..3
    const int wm   = widm * 128;
    const int wn   = widn * 64;
    const int lr   = lane & 15;
    const int lk   = lane >> 4;

    const int id   = blockIdx.x;     // 256 blocks
    const int xcd  = id & 7;
    const int slot = id >> 3;        // 0..31
    const int m0   = (xcd * 8 + (slot >> 2)) * 256;
    const int n0   = (slot & 3) * 256;

    const char* Abase = Asw + (size_t)(m0 >> 7) * 48 * 16384;
    const char* Bbase = Wsw + (size_t)(n0 >> 7) * 48 * 16384;
    const int soff = wid * 1024 + lane * 16;

    f32x4 acc[8][4];
#pragma unroll
    for (int i = 0; i < 8; ++i)
#pragma unroll
        for (int j = 0; j < 4; ++j) acc[i][j] = (f32x4){0.f, 0.f, 0.f, 0.f};

    auto stageTile = [&](int q, int tk) {
#pragma unroll
        for (int hh = 0; hh < 2; ++hh) {
            const char* sA = Abase + ((size_t)hh * 48 + tk) * 16384;
            const char* sB = Bbase + ((size_t)hh * 48 + tk) * 16384;
            char* dA = lds + q * 32768 + hh * 16384 + wid * 1024;
            char* dB = lds + 65536 + q * 32768 + hh * 16384 + wid * 1024;
            gld16(sA + soff,        dA);
            gld16(sA + soff + 8192, dA + 8192);
            gld16(sB + soff,        dB);
            gld16(sB + soff + 8192, dB + 8192);
        }
    };

    stageTile(0, 0);   // prologue: 8 loads in flight

    for (int t = 0; t < 48; ++t) {
        const int q = t & 1;
        if (t + 1 < 48) {
            stageTile(q ^ 1, t + 1);                       // 8 more loads (next tile)
            asm volatile("s_waitcnt vmcnt(8)" ::: "memory"); // tile t's 8 loads landed
        } else {
            asm volatile("s_waitcnt vmcnt(0)" ::: "memory"); // last tile: drain
        }
        __builtin_amdgcn_sched_barrier(0);
        __builtin_amdgcn_s_barrier();                      // buf q ready for all waves
        __builtin_amdgcn_sched_barrier(0);

        const char* Ah = lds + q * 32768 + widm * 16384;
        const char* Bh = lds + 65536 + q * 32768 + (widn >> 1) * 16384;

        bf16x8 bfr[2][2];
#pragma unroll
        for (int nh = 0; nh < 2; ++nh) {
#pragma unroll
            for (int j = 0; j < 2; ++j) {
                int c = (wn & 127) + (nh * 2 + j) * 16 + lr;
#pragma unroll
                for (int kk = 0; kk < 2; ++kk)
                    bfr[j][kk] = *(const bf16x8*)(Bh + TSW(c, kk * 64 + lk * 16));
            }
#pragma unroll
            for (int mh = 0; mh < 2; ++mh) {
                bf16x8 af[4][2];
#pragma unroll
                for (int i = 0; i < 4; ++i) {
                    int r = (mh * 4 + i) * 16 + lr;        // row within wave's half
#pragma unroll
                    for (int kk = 0; kk < 2; ++kk)
                        af[i][kk] = *(const bf16x8*)(Ah + TSW(r, kk * 64 + lk * 16));
                }
                __builtin_amdgcn_s_setprio(1);
#pragma unroll
                for (int kk = 0; kk < 2; ++kk)
#pragma unroll
                    for (int i = 0; i < 4; ++i)
#pragma unroll
                        for (int j = 0; j < 2; ++j)
                            acc[mh*4+i][nh*2+j] = __builtin_amdgcn_mfma_f32_16x16x32_bf16(
                                af[i][kk], bfr[j][kk], acc[mh*4+i][nh*2+j], 0, 0, 0);
                __builtin_amdgcn_s_setprio(0);
            }
        }
        __builtin_amdgcn_sched_barrier(0);
        __builtin_amdgcn_s_barrier();   // all reads of buf q done -> next stage may overwrite
        __builtin_amdgcn_sched_barrier(0);
    }

#pragma unroll
    for (int nf = 0; nf < 4; ++nf) {
        const int col = n0 + wn + nf*16 + lr;
        const float bc = bcat[col];
#pragma unroll
        for (int mf = 0; mf < 8; ++mf)
#pragma unroll
            for (int r = 0; r < 4; ++r) {
                size_t row = (size_t)(m0 + wm + mf*16 + lk*4 + r);
                float x = acc[mf][nf][r] + bc;
                float g = 0.5f * x * (1.0f + erff(x * 0.70710678118654752f));
                x2[row * NH + col] = f2bf(g);
            }
    }
}

// ---------------------------------------------------------------------------
// Kernel B (fallback): reg-staged mixed GEMM (round-4 version).
// ---------------------------------------------------------------------------
__global__ __launch_bounds__(256) void kB(const float* __restrict__ h,
                                          const unsigned short* __restrict__ aware,
                                          const float* __restrict__ Wcat,
                                          const float* __restrict__ bcat,
                                          unsigned short* __restrict__ x2) {
    __shared__ __align__(16) char lds[16384];
    char* Asl = lds;
    char* Bsl = lds + 8192;

    const int tid  = threadIdx.x;
    const int lane = tid & 63;
    const int wid  = tid >> 6;
    const int wm   = (wid >> 1) * 64;
    const int wn   = (wid & 1) * 64;
    const int lr   = lane & 15;
    const int lk   = lane >> 4;

    const int id   = blockIdx.x;
    const int xcd  = id & 7;
    const int slot = id >> 3;
    const int m0   = (xcd * 16 + (slot >> 3)) * 128;
    const int n0   = (slot & 7) * 128;

    const int am = tid >> 1;
    const int ak = (tid & 1) * 16;
    const int bn = tid & 127;
    const int bk = (tid >> 7) * 16;

    f32x4 acc[4][4];
#pragma unroll
    for (int i = 0; i < 4; ++i)
#pragma unroll
        for (int j = 0; j < 4; ++j) acc[i][j] = (f32x4){0.f, 0.f, 0.f, 0.f};

    const float*          hrow = h     + (size_t)(m0 + am) * NH + ak;
    const unsigned short* arow = aware + (size_t)(m0 + am) * NH + ak;
    const float*          wcol = Wcat  + (size_t)bk * NH + n0 + bn;

    float hv[16];
    unsigned int aw[8];
    float wv[16];

    auto stage = [&](int kt) {
        const int region = kt >> 10;
        const int kb = kt & 1023;
        if (region != 1) {
            const float4* hp = (const float4*)(hrow + kb);
            float4 a = hp[0], b = hp[1], c = hp[2], d = hp[3];
            hv[0]=a.x; hv[1]=a.y; hv[2]=a.z; hv[3]=a.w;
            hv[4]=b.x; hv[5]=b.y; hv[6]=b.z; hv[7]=b.w;
            hv[8]=c.x; hv[9]=c.y; hv[10]=c.z; hv[11]=c.w;
            hv[12]=d.x; hv[13]=d.y; hv[14]=d.z; hv[15]=d.w;
        }
        if (region >= 1) {
            const uint4* ap = (const uint4*)(arow + kb);
            uint4 a0 = ap[0], a1 = ap[1];
            aw[0]=a0.x; aw[1]=a0.y; aw[2]=a0.z; aw[3]=a0.w;
            aw[4]=a1.x; aw[5]=a1.y; aw[6]=a1.z; aw[7]=a1.w;
        }
        {
            const float* wp = wcol + (size_t)kt * NH;
#pragma unroll
            for (int j = 0; j < 16; ++j) wv[j] = wp[(size_t)j * NH];
        }
    };

    auto writeStage = [&](int kt) {
        const int region = kt >> 10;
        unsigned int p[8];
        if (region == 0) {
#pragma unroll
            for (int i = 0; i < 8; ++i) p[i] = pk2(hv[2*i], hv[2*i+1]);
        } else if (region == 1) {
#pragma unroll
            for (int i = 0; i < 8; ++i) p[i] = aw[i];
        } else {
#pragma unroll
            for (int i = 0; i < 8; ++i) {
                float lo = hv[2*i]   * bf2f(aw[i] & 0xffffu);
                float hi = hv[2*i+1] * bf2f(aw[i] >> 16);
                p[i] = pk2(lo, hi);
            }
        }
        *(int4*)(Asl + SW64(am*64 + ak*2))      = make_int4(p[0], p[1], p[2], p[3]);
        *(int4*)(Asl + SW64(am*64 + ak*2 + 16)) = make_int4(p[4], p[5], p[6], p[7]);
        unsigned int q[8];
#pragma unroll
        for (int i = 0; i < 8; ++i) q[i] = pk2(wv[2*i], wv[2*i+1]);
        *(int4*)(Bsl + SW64(bn*64 + bk*2))      = make_int4(q[0], q[1], q[2], q[3]);
        *(int4*)(Bsl + SW64(bn*64 + bk*2 + 16)) = make_int4(q[4], q[5], q[6], q[7]);
    };

    stage(0);
    for (int kt = 0; kt < 3072; kt += 32) {
        __syncthreads();
        writeStage(kt);
        __syncthreads();
        if (kt + 32 < 3072) stage(kt + 32);

        bf16x8 af[4], bfr[4];
#pragma unroll
        for (int mf = 0; mf < 4; ++mf)
            af[mf] = *(const bf16x8*)(Asl + SW64((wm + mf*16 + lr)*64 + lk*16));
#pragma unroll
        for (int nf = 0; nf < 4; ++nf)
            bfr[nf] = *(const bf16x8*)(Bsl + SW64((wn + nf*16 + lr)*64 + lk*16));
#pragma unroll
        for (int mf = 0; mf < 4; ++mf)
#pragma unroll
            for (int nf = 0; nf < 4; ++nf)
                acc[mf][nf] = __builtin_amdgcn_mfma_f32_16x16x32_bf16(af[mf], bfr[nf], acc[mf][nf], 0, 0, 0);
    }

#pragma unroll
    for (int nf = 0; nf < 4; ++nf) {
        const int col = n0 + wn + nf*16 + lr;
        const float bc = bcat[col];
#pragma unroll
        for (int mf = 0; mf < 4; ++mf)
#pragma unroll
            for (int r = 0; r < 4; ++r) {
                size_t row = (size_t)(m0 + wm + mf*16 + lk*4 + r);
                float x = acc[mf][nf][r] + bc;
                float g = 0.5f * x * (1.0f + erff(x * 0.70710678118654752f));
                x2[row * NH + col] = f2bf(g);
            }
    }
}

// ---------------------------------------------------------------------------
// Kernel C: ner_scores = [x2 @ W_crf + b_crf, -10000, -10000]  (MFMA, N=48)
// ---------------------------------------------------------------------------
__global__ __launch_bounds__(256) void kC(const unsigned short* __restrict__ x2,
                                          const float* __restrict__ Wcrf,
                                          const float* __restrict__ bcrf,
                                          float* __restrict__ out) {
    __shared__ __align__(16) char Asl[8192];
    __shared__ __align__(16) char Bsl[3072];

    const int tid  = threadIdx.x;
    const int lane = tid & 63;
    const int wid  = tid >> 6;
    const int lr   = lane & 15;
    const int lk   = lane >> 4;
    const int m0   = blockIdx.x * 128;
    const int am   = tid >> 1;
    const int ak   = (tid & 1) * 16;

    for (int i = tid; i < 192; i += 256) *(int4*)(Bsl + i*16) = make_int4(0, 0, 0, 0);

    f32x4 acc[2][3];
#pragma unroll
    for (int i = 0; i < 2; ++i)
#pragma unroll
        for (int j = 0; j < 3; ++j) acc[i][j] = (f32x4){0.f, 0.f, 0.f, 0.f};

    const unsigned short* xrow = x2 + (size_t)(m0 + am) * NH + ak;

    for (int kt = 0; kt < NH; kt += 32) {
        const uint4* xp = (const uint4*)(xrow + kt);
        uint4 x0 = xp[0], x1 = xp[1];
        float wv[5];
#pragma unroll
        for (int p = 0; p < 5; ++p) {
            int i = tid + p * 256;
            wv[p] = (i < 32*NT) ? Wcrf[(size_t)kt * NT + i] : 0.f;
        }
        __syncthreads();
        *(uint4*)(Asl + SW64(am*64 + ak*2))      = x0;
        *(uint4*)(Asl + SW64(am*64 + ak*2 + 16)) = x1;
#pragma unroll
        for (int p = 0; p < 5; ++p) {
            int i = tid + p * 256;
            if (i < 32*NT) {
                int kk = i / NT;
                int t  = i - kk * NT;
                *(unsigned short*)(Bsl + SW64(t*64 + kk*2)) = f2bf(wv[p]);
            }
        }
        __syncthreads();
        bf16x8 af[2], bfr[3];
#pragma unroll
        for (int mf = 0; mf < 2; ++mf)
            af[mf] = *(const bf16x8*)(Asl + SW64((wid*32 + mf*16 + lr)*64 + lk*16));
#pragma unroll
        for (int nf = 0; nf < 3; ++nf)
            bfr[nf] = *(const bf16x8*)(Bsl + SW64((nf*16 + lr)*64 + lk*16));
#pragma unroll
        for (int mf = 0; mf < 2; ++mf)
#pragma unroll
            for (int nf = 0; nf < 3; ++nf)
                acc[mf][nf] = __builtin_amdgcn_mfma_f32_16x16x32_bf16(af[mf], bfr[nf], acc[mf][nf], 0, 0, 0);
    }

#pragma unroll
    for (int nf = 0; nf < 3; ++nf) {
        const int t = nf*16 + lr;
        const float bc = (t < NT) ? bcrf[t] : 0.f;
#pragma unroll
        for (int mf = 0; mf < 2; ++mf)
#pragma unroll
            for (int r = 0; r < 4; ++r) {
                size_t row = (size_t)(m0 + wid*32 + mf*16 + lk*4 + r);
                if (t < NT)       out[row * NLP + t] = acc[mf][nf][r] + bc;
                else if (t < NLP) out[row * NLP + t] = -10000.0f;
            }
    }
}

// ---------------------------------------------------------------------------
// Kernel D: CRF log-likelihood, exp-domain scan, unroll x4 with distance-4
// logit prefetch (named registers), exp hoisted off the serial chain,
// rescale by readlane(a,0)+rcp once per 4 steps.
// ---------------------------------------------------------------------------
#define CRFSTEP(EL) do {                                   \
    float c0 = 0.f, c1 = 0.f, c2 = 0.f, c3 = 0.f;          \
    _Pragma("unroll")                                      \
    for (int f_ = 0; f_ < 36; f_ += 4) {                   \
        c0 = fmaf(rl(a, f_    ), trow[f_    ], c0);        \
        c1 = fmaf(rl(a, f_ + 1), trow[f_ + 1], c1);        \
        c2 = fmaf(rl(a, f_ + 2), trow[f_ + 2], c2);        \
        c3 = fmaf(rl(a, f_ + 3), trow[f_ + 3], c3);        \
    }                                                      \
    c0 = fmaf(rl(a, 36), trow[36], c0);                    \
    a = (EL) * ((c0 + c1) + (c2 + c3));                    \
} while (0)

__global__ __launch_bounds__(64) void kD(const float* __restrict__ scores,
                                         const int* __restrict__ labels,
                                         const int* __restrict__ lens,
                                         const float* __restrict__ trans,
                                         float* __restrict__ loss) {
    __shared__ float trL[39 * 41];

    const int b = blockIdx.x;
    const int lane = threadIdx.x;

    for (int idx = lane; idx < 39 * 39; idx += 64) {
        int to = idx / 39, f = idx - to * 39;
        trL[to * 41 + f] = trans[idx];
    }
    __syncthreads();

    const int len = lens[b];
    const float* sb = scores + (size_t)b * NS * NLP;

    // gold path score
    float g = 0.0f;
    for (int t = lane; t < len; t += 64) g += sb[(size_t)t * NLP + labels[b * NS + t]];
    for (int i = lane; i <= len; i += 64) {
        int frm = (i == 0) ? 37 : labels[b * NS + i - 1];
        int to  = (i == len) ? 38 : labels[b * NS + i];
        g += trL[to * 41 + frm];
    }
#pragma unroll
    for (int off = 32; off > 0; off >>= 1) g += __shfl_xor(g, off, 64);

    const int myrow = (lane < 39) ? lane : 0;
    float trow[39];
#pragma unroll
    for (int f = 0; f < 39; ++f) trow[f] = __expf(trL[myrow * 41 + f]);
    const float trEnd = (lane < 39) ? trL[38 * 41 + lane] : 0.f;
    const bool act = (lane < 39);
    const float* sbl = sb + lane;

    // t = 0 closed form: a[to] = exp(logit0[to]) * exp(trans[to][START])
    float l0 = act ? sbl[0] : -10000.f;
    float a = act ? __expf(l0) * trow[37] : 0.f;
    float C = 0.0f;

    auto ldrow = [&](int r) {
        r = (r < len) ? r : (len - 1);
        return act ? sbl[(size_t)r * NLP] : 0.f;
    };
    float lg0 = ldrow(1), lg1 = ldrow(2), lg2 = ldrow(3), lg3 = ldrow(4);

    int t = 1;
    for (; t + 3 < len; t += 4) {
        float e0 = __expf(lg0), e1 = __expf(lg1), e2 = __expf(lg2), e3 = __expf(lg3);
        lg0 = ldrow(t + 4); lg1 = ldrow(t + 5); lg2 = ldrow(t + 6); lg3 = ldrow(t + 7);
        CRFSTEP(e0); CRFSTEP(e1); CRFSTEP(e2); CRFSTEP(e3);
        float s = rl(a, 0);                       // a[0] > 0 always
        float rr = __builtin_amdgcn_rcpf(s);
        a *= rr; C -= __logf(rr);
    }
    for (; t < len; ++t) {
        float el = __expf(ldrow(t));
        CRFSTEP(el);
    }

    float aend = (lane < 39 && a > 0.f) ? C + __logf(a) + trEnd : -1e30f;
    float mx = aend;
#pragma unroll
    for (int off = 32; off > 0; off >>= 1) mx = fmaxf(mx, __shfl_xor(mx, off, 64));
    float es = (lane < 39) ? __expf(aend - mx) : 0.0f;
#pragma unroll
    for (int off = 32; off > 0; off >>= 1) es += __shfl_xor(es, off, 64);
    float norm = mx + __logf(es);

    if (lane == 0) loss[b] = g - norm;
}

// ---------------------------------------------------------------------------
extern "C" void kernel_launch(void* const* d_in, const int* in_sizes, int n_in,
                              void* d_out, int out_size, void* d_ws, size_t ws_size,
                              hipStream_t stream) {
    const float* h        = (const float*)d_in[0];
    const int* token_nums = (const int*)d_in[2];
    const int* labels     = (const int*)d_in[3];
    const float* bio      = (const float*)d_in[4];
    const float* Wcat     = (const float*)d_in[5];
    const float* bcat     = (const float*)d_in[6];
    const float* Wcrf     = (const float*)d_in[7];
    const float* bcrf     = (const float*)d_in[8];
    const float* trans    = (const float*)d_in[9];

    float* out = (float*)d_out;
    unsigned short* attn  = (unsigned short*)d_out;  // 2MB scratch, overwritten by kC

    const size_t ASW_BYTES = (size_t)128 * 48 * 16384;        // 96 MB
    const size_t X2_BYTES  = (size_t)NM * NH * 2;             // 32 MB
    const size_t WSW_BYTES = (size_t)8 * 48 * 16384;          // 6 MB
    const bool fast = ws_size >= ASW_BYTES + X2_BYTES + WSW_BYTES;

    hipLaunchKernelGGL(kA1, dim3(NM / 64), dim3(256), 0, stream, h, bio, attn);

    if (fast) {
        char* Asw           = (char*)d_ws;
        unsigned short* x2  = (unsigned short*)((char*)d_ws + ASW_BYTES);
        char* Wsw           = (char*)d_ws + ASW_BYTES + X2_BYTES;

        hipLaunchKernelGGL(kW, dim3(8 * 48), dim3(256), 0, stream, Wcat, Wsw);
        hipLaunchKernelGGL(kA2f, dim3(NH / 128, NM / 128), dim3(256), 0, stream,
                           attn, bio, h, Asw);
        hipLaunchKernelGGL(kBf, dim3(256), dim3(512), 0, stream, Asw, Wsw, bcat, x2);
        hipLaunchKernelGGL(kC, dim3(NM / 128), dim3(256), 0, stream, x2, Wcrf, bcrf, out);
    } else {
        unsigned short* aware = (unsigned short*)d_ws;
        unsigned short* x2    = aware + (size_t)NM * NH;

        hipLaunchKernelGGL(kA2, dim3(NH / 128, NM / 128), dim3(256), 0, stream, attn, bio, aware);
        hipLaunchKernelGGL(kB, dim3((NH / 128) * (NM / 128)), dim3(256), 0, stream,
                           h, aware, Wcat, bcat, x2);
        hipLaunchKernelGGL(kC, dim3(NM / 128), dim3(256), 0, stream, x2, Wcrf, bcrf, out);
    }

    hipLaunchKernelGGL(kD, dim3(NB), dim3(64), 0, stream, out, labels, token_nums, trans,
                       out + (size_t)NM * NLP);
}

// Round 8
// 319.401 us; speedup vs baseline: 11.8149x; 1.0887x over previous
//
#include <hip/hip_runtime.h>
#include <hip/hip_bf16.h>
#include <math.h>

#define NB 32
#define NS 512
#define NH 1024
#define NT 37
#define NLP 39
#define NM (NB*NS)   // 16384

typedef __attribute__((ext_vector_type(8))) short bf16x8;
typedef __attribute__((ext_vector_type(4))) float f32x4;

__device__ __forceinline__ float bf2f(unsigned int u) {
    unsigned int x = u << 16;
    float f;
    __builtin_memcpy(&f, &x, 4);
    return f;
}
__device__ __forceinline__ unsigned short f2bf(float f) {
    __hip_bfloat16 hb = __float2bfloat16(f);
    unsigned short u;
    __builtin_memcpy(&u, &hb, 2);
    return u;
}
__device__ __forceinline__ unsigned int pk2(float lo, float hi) {
    return ((unsigned int)f2bf(hi) << 16) | (unsigned int)f2bf(lo);
}
// bijective XOR swizzle for [row][64B] bf16 LDS tiles
__device__ __forceinline__ int SW64(int b)  { return b ^ ((b >> 2) & 0x70); }
// tile swizzle for [128 row][64 k] bf16 tiles (row stride 128B)
__device__ __forceinline__ int TSW(int row, int kcolByte) {
    return (row * 128 + kcolByte) ^ ((row & 7) << 4);
}
__device__ __forceinline__ float rl(float x, int l) {
    return __int_as_float(__builtin_amdgcn_readlane(__float_as_int(x), l));
}
__device__ __forceinline__ void gld16(const void* g, void* l) {
    __builtin_amdgcn_global_load_lds((const __attribute__((address_space(1))) void*)g,
                                     (__attribute__((address_space(3))) void*)l, 16, 0, 0);
}

// ---------------------------------------------------------------------------
// Kernel A1: scores = h@bio^T /32 -> softmax -> attn (bf16, [NM][64], zero-pad)
// ---------------------------------------------------------------------------
__global__ __launch_bounds__(256) void kA1(const float* __restrict__ h,
                                           const float* __restrict__ bio,
                                           unsigned short* __restrict__ attn) {
    __shared__ __align__(16) char Asl[64 * 64];
    __shared__ __align__(16) char Bsl[48 * 64];

    const int tid  = threadIdx.x;
    const int lane = tid & 63;
    const int wid  = tid >> 6;
    const int lr   = lane & 15;
    const int lk   = lane >> 4;
    const int m0   = blockIdx.x * 64;

    const int arow = tid >> 2;
    const int aq   = (tid & 3) * 8;
    const int brow = tid >> 1;
    const int bkh  = (tid & 1) * 16;

    f32x4 sacc[3];
#pragma unroll
    for (int j = 0; j < 3; ++j) sacc[j] = (f32x4){0.f, 0.f, 0.f, 0.f};

    const float* hrow = h + (size_t)(m0 + arow) * NH + aq;

    for (int kt = 0; kt < NH; kt += 32) {
        float hv[8];
        {
            const float4* hp = (const float4*)(hrow + kt);
            float4 a = hp[0], b = hp[1];
            hv[0]=a.x; hv[1]=a.y; hv[2]=a.z; hv[3]=a.w;
            hv[4]=b.x; hv[5]=b.y; hv[6]=b.z; hv[7]=b.w;
        }
        float bv[16];
        if (tid < 96) {
            if (brow < NT) {
                const float4* bp = (const float4*)(bio + (size_t)brow * NH + kt + bkh);
                float4 a = bp[0], b = bp[1], c = bp[2], d = bp[3];
                bv[0]=a.x; bv[1]=a.y; bv[2]=a.z; bv[3]=a.w;
                bv[4]=b.x; bv[5]=b.y; bv[6]=b.z; bv[7]=b.w;
                bv[8]=c.x; bv[9]=c.y; bv[10]=c.z; bv[11]=c.w;
                bv[12]=d.x; bv[13]=d.y; bv[14]=d.z; bv[15]=d.w;
            } else {
#pragma unroll
                for (int i = 0; i < 16; ++i) bv[i] = 0.f;
            }
        }
        __syncthreads();
        {
            unsigned int p[4];
#pragma unroll
            for (int i = 0; i < 4; ++i) p[i] = pk2(hv[2*i], hv[2*i+1]);
            *(int4*)(Asl + SW64(arow*64 + aq*2)) = make_int4(p[0], p[1], p[2], p[3]);
        }
        if (tid < 96) {
            unsigned int p[8];
#pragma unroll
            for (int i = 0; i < 8; ++i) p[i] = pk2(bv[2*i], bv[2*i+1]);
            *(int4*)(Bsl + SW64(brow*64 + bkh*2))      = make_int4(p[0], p[1], p[2], p[3]);
            *(int4*)(Bsl + SW64(brow*64 + bkh*2 + 16)) = make_int4(p[4], p[5], p[6], p[7]);
        }
        __syncthreads();
        bf16x8 af = *(const bf16x8*)(Asl + SW64((wid*16 + lr)*64 + lk*16));
#pragma unroll
        for (int nf = 0; nf < 3; ++nf) {
            bf16x8 bfr = *(const bf16x8*)(Bsl + SW64((nf*16 + lr)*64 + lk*16));
            sacc[nf] = __builtin_amdgcn_mfma_f32_16x16x32_bf16(af, bfr, sacc[nf], 0, 0, 0);
        }
    }

#pragma unroll
    for (int r = 0; r < 4; ++r) {
        const int row = wid*16 + lk*4 + r;
        float s0 = sacc[0][r] * 0.03125f;
        float s1 = sacc[1][r] * 0.03125f;
        float s2 = sacc[2][r] * 0.03125f;
        const bool v2 = (lr < 5);
        float mx = fmaxf(fmaxf(s0, s1), v2 ? s2 : -1e30f);
#pragma unroll
        for (int d = 1; d < 16; d <<= 1) mx = fmaxf(mx, __shfl_xor(mx, d, 64));
        float e0 = __expf(s0 - mx), e1 = __expf(s1 - mx);
        float e2 = v2 ? __expf(s2 - mx) : 0.f;
        float sm = e0 + e1 + e2;
#pragma unroll
        for (int d = 1; d < 16; d <<= 1) sm += __shfl_xor(sm, d, 64);
        float inv = 1.f / sm;
        size_t g = (size_t)(m0 + row) * 64;
        attn[g + lr]      = f2bf(e0 * inv);
        attn[g + 16 + lr] = f2bf(e1 * inv);
        attn[g + 32 + lr] = f2bf(e2 * inv);
        attn[g + 48 + lr] = 0;
    }
}

// ---------------------------------------------------------------------------
// Kernel A2 (fallback): aware = attn @ bio, plain bf16 row-major out.
// ---------------------------------------------------------------------------
__global__ __launch_bounds__(256) void kA2(const unsigned short* __restrict__ attn,
                                           const float* __restrict__ bio,
                                           unsigned short* __restrict__ aware) {
    __shared__ __align__(16) char Bsl[128 * 64];

    const int tid  = threadIdx.x;
    const int lane = tid & 63;
    const int wid  = tid >> 6;
    const int wm   = (wid >> 1) * 64;
    const int wn   = (wid & 1) * 64;
    const int lr   = lane & 15;
    const int lk   = lane >> 4;
    const int n0   = blockIdx.x * 128;
    const int m0   = blockIdx.y * 128;

    const int bn = tid & 127;
    const int bq = (tid >> 7) * 16;

    f32x4 acc[4][4];
#pragma unroll
    for (int i = 0; i < 4; ++i)
#pragma unroll
        for (int j = 0; j < 4; ++j) acc[i][j] = (f32x4){0.f, 0.f, 0.f, 0.f};

#pragma unroll
    for (int ks = 0; ks < 2; ++ks) {
        unsigned int p[8];
#pragma unroll
        for (int i = 0; i < 8; ++i) {
            int t0 = ks*32 + bq + 2*i;
            float lo = (t0     < NT) ? bio[(size_t)t0 * NH + n0 + bn]       : 0.f;
            float hi = (t0 + 1 < NT) ? bio[(size_t)(t0+1) * NH + n0 + bn]   : 0.f;
            p[i] = pk2(lo, hi);
        }
        __syncthreads();
        *(int4*)(Bsl + SW64(bn*64 + bq*2))      = make_int4(p[0], p[1], p[2], p[3]);
        *(int4*)(Bsl + SW64(bn*64 + bq*2 + 16)) = make_int4(p[4], p[5], p[6], p[7]);
        __syncthreads();

        bf16x8 af[4];
#pragma unroll
        for (int mf = 0; mf < 4; ++mf)
            af[mf] = *(const bf16x8*)(attn + (size_t)(m0 + wm + mf*16 + lr) * 64 + ks*32 + lk*8);
#pragma unroll
        for (int nf = 0; nf < 4; ++nf) {
            bf16x8 bb = *(const bf16x8*)(Bsl + SW64((wn + nf*16 + lr)*64 + lk*16));
#pragma unroll
            for (int mf = 0; mf < 4; ++mf)
                acc[mf][nf] = __builtin_amdgcn_mfma_f32_16x16x32_bf16(af[mf], bb, acc[mf][nf], 0, 0, 0);
        }
    }

#pragma unroll
    for (int mf = 0; mf < 4; ++mf)
#pragma unroll
        for (int nf = 0; nf < 4; ++nf)
#pragma unroll
            for (int r = 0; r < 4; ++r) {
                size_t row = (size_t)(m0 + wm + mf*16 + lk*4 + r);
                aware[row * NH + n0 + wn + nf*16 + lr] = f2bf(acc[mf][nf][r]);
            }
}

// ---------------------------------------------------------------------------
// Kernel A2f (fast): computes aware chunk AND writes the full concat-A
// [h | aware | h*aware] in bf16, tile-major (128x64 tiles) with TSW swizzle.
// ---------------------------------------------------------------------------
__global__ __launch_bounds__(256) void kA2f(const unsigned short* __restrict__ attn,
                                            const float* __restrict__ bio,
                                            const float* __restrict__ h,
                                            char* __restrict__ Asw) {
    __shared__ __align__(16) char Bsl[128 * 64];
    __shared__ __align__(16) unsigned short awL[128 * 128];  // 32KB aware chunk

    const int tid  = threadIdx.x;
    const int lane = tid & 63;
    const int wid  = tid >> 6;
    const int wm   = (wid >> 1) * 64;
    const int wn   = (wid & 1) * 64;
    const int lr   = lane & 15;
    const int lk   = lane >> 4;
    const int n0   = blockIdx.x * 128;
    const int m0   = blockIdx.y * 128;
    const int tm   = blockIdx.y;

    const int bn = tid & 127;
    const int bq = (tid >> 7) * 16;

    f32x4 acc[4][4];
#pragma unroll
    for (int i = 0; i < 4; ++i)
#pragma unroll
        for (int j = 0; j < 4; ++j) acc[i][j] = (f32x4){0.f, 0.f, 0.f, 0.f};

#pragma unroll
    for (int ks = 0; ks < 2; ++ks) {
        unsigned int p[8];
#pragma unroll
        for (int i = 0; i < 8; ++i) {
            int t0 = ks*32 + bq + 2*i;
            float lo = (t0     < NT) ? bio[(size_t)t0 * NH + n0 + bn]       : 0.f;
            float hi = (t0 + 1 < NT) ? bio[(size_t)(t0+1) * NH + n0 + bn]   : 0.f;
            p[i] = pk2(lo, hi);
        }
        __syncthreads();
        *(int4*)(Bsl + SW64(bn*64 + bq*2))      = make_int4(p[0], p[1], p[2], p[3]);
        *(int4*)(Bsl + SW64(bn*64 + bq*2 + 16)) = make_int4(p[4], p[5], p[6], p[7]);
        __syncthreads();

        bf16x8 af[4];
#pragma unroll
        for (int mf = 0; mf < 4; ++mf)
            af[mf] = *(const bf16x8*)(attn + (size_t)(m0 + wm + mf*16 + lr) * 64 + ks*32 + lk*8);
#pragma unroll
        for (int nf = 0; nf < 4; ++nf) {
            bf16x8 bb = *(const bf16x8*)(Bsl + SW64((wn + nf*16 + lr)*64 + lk*16));
#pragma unroll
            for (int mf = 0; mf < 4; ++mf)
                acc[mf][nf] = __builtin_amdgcn_mfma_f32_16x16x32_bf16(af[mf], bb, acc[mf][nf], 0, 0, 0);
        }
    }

#pragma unroll
    for (int mf = 0; mf < 4; ++mf)
#pragma unroll
        for (int nf = 0; nf < 4; ++nf)
#pragma unroll
            for (int r = 0; r < 4; ++r)
                awL[(wm + mf*16 + lk*4 + r) * 128 + wn + nf*16 + lr] = f2bf(acc[mf][nf][r]);
    __syncthreads();

    // region 1 (aware)
#pragma unroll
    for (int i = 0; i < 8; ++i) {
        int lin = tid + i * 256;
        int row = lin >> 4, kg = lin & 15;
        uint4 v = *(const uint4*)&awL[row * 128 + kg * 8];
        int kglob = 1024 + n0 + kg * 8;
        size_t tbase = ((size_t)tm * 48 + (kglob >> 6)) * 16384;
        *(uint4*)(Asw + tbase + TSW(row, (kglob & 63) * 2)) = v;
    }
    // regions 0 (h) and 2 (h*aware)
#pragma unroll
    for (int i = 0; i < 8; ++i) {
        int lin = tid + i * 256;
        int row = lin >> 4, kg = lin & 15;
        const float4* hp = (const float4*)&h[(size_t)(m0 + row) * NH + n0 + kg * 8];
        float4 ha = hp[0], hb = hp[1];
        float hv[8] = {ha.x, ha.y, ha.z, ha.w, hb.x, hb.y, hb.z, hb.w};
        uint4 awv = *(const uint4*)&awL[row * 128 + kg * 8];
        unsigned int awu[4] = {awv.x, awv.y, awv.z, awv.w};
        unsigned int p0[4], p2[4];
#pragma unroll
        for (int j = 0; j < 4; ++j) {
            p0[j] = pk2(hv[2*j], hv[2*j+1]);
            float lo = hv[2*j]   * bf2f(awu[j] & 0xffffu);
            float hi = hv[2*j+1] * bf2f(awu[j] >> 16);
            p2[j] = pk2(lo, hi);
        }
        int k0g = n0 + kg * 8;
        size_t tb0 = ((size_t)tm * 48 + (k0g >> 6)) * 16384;
        *(uint4*)(Asw + tb0 + TSW(row, (k0g & 63) * 2)) = make_uint4(p0[0], p0[1], p0[2], p0[3]);
        int k2g = 2048 + n0 + kg * 8;
        size_t tb2 = ((size_t)tm * 48 + (k2g >> 6)) * 16384;
        *(uint4*)(Asw + tb2 + TSW(row, (k2g & 63) * 2)) = make_uint4(p2[0], p2[1], p2[2], p2[3]);
    }
}

// ---------------------------------------------------------------------------
// Kernel W: WbT swizzled tiles: W^T[n][k] bf16, tile (tn,tk) = [128 n][64 k].
// ---------------------------------------------------------------------------
__global__ __launch_bounds__(256) void kW(const float* __restrict__ Wcat,
                                          char* __restrict__ Wsw) {
    __shared__ unsigned short wt[64 * 128];

    const int tid  = threadIdx.x;
    const int tile = blockIdx.x;
    const int tn   = tile / 48;
    const int tk   = tile - tn * 48;
    const int n00  = tn * 128;
    const int k0   = tk * 64;

#pragma unroll
    for (int i = 0; i < 8; ++i) {
        int lin = tid + i * 256;
        int kk = lin >> 5, ng = lin & 31;
        float4 v = *(const float4*)&Wcat[(size_t)(k0 + kk) * NH + n00 + ng * 4];
        unsigned int lo = pk2(v.x, v.y), hi = pk2(v.z, v.w);
        *(uint2*)&wt[kk * 128 + ng * 4] = make_uint2(lo, hi);
    }
    __syncthreads();
#pragma unroll
    for (int i = 0; i < 4; ++i) {
        int lin = tid + i * 256;
        int rn = lin >> 3, kg = lin & 7;
        unsigned short t8[8];
#pragma unroll
        for (int j = 0; j < 8; ++j) t8[j] = wt[(kg * 8 + j) * 128 + rn];
        uint4 v = *(const uint4*)t8;
        *(uint4*)(Wsw + (size_t)tile * 16384 + TSW(rn, kg * 16)) = v;
    }
}

// ---------------------------------------------------------------------------
// Kernel Bf (fast): pure bf16 GEMM, 128x128 tile, BK=64, global_load_lds
// staging from pre-swizzled tiles, 2-barrier m97 structure (proven 126us).
// ---------------------------------------------------------------------------
__global__ __launch_bounds__(256) void kBf(const char* __restrict__ Asw,
                                           const char* __restrict__ Wsw,
                                           const float* __restrict__ bcat,
                                           unsigned short* __restrict__ x2) {
    __shared__ __align__(16) char Asl[16384];
    __shared__ __align__(16) char Bsl[16384];

    const int tid  = threadIdx.x;
    const int lane = tid & 63;
    const int wid  = tid >> 6;
    const int wm   = (wid >> 1) * 64;
    const int wn   = (wid & 1) * 64;
    const int lr   = lane & 15;
    const int lk   = lane >> 4;

    const int id   = blockIdx.x;
    const int xcd  = id & 7;
    const int slot = id >> 3;
    const int m0   = (xcd * 16 + (slot >> 3)) * 128;
    const int n0   = (slot & 7) * 128;
    const int tm   = m0 >> 7;
    const int tn   = n0 >> 7;

    f32x4 acc[4][4];
#pragma unroll
    for (int i = 0; i < 4; ++i)
#pragma unroll
        for (int j = 0; j < 4; ++j) acc[i][j] = (f32x4){0.f, 0.f, 0.f, 0.f};

    const int laneOff = wid * 4096 + lane * 16;

    for (int tk = 0; tk < 48; ++tk) {
        const char* tA = Asw + ((size_t)tm * 48 + tk) * 16384;
        const char* tB = Wsw + ((size_t)tn * 48 + tk) * 16384;
#pragma unroll
        for (int j = 0; j < 4; ++j)
            gld16(tA + laneOff + j * 1024, Asl + wid * 4096 + j * 1024);
#pragma unroll
        for (int j = 0; j < 4; ++j)
            gld16(tB + laneOff + j * 1024, Bsl + wid * 4096 + j * 1024);
        __syncthreads();

#pragma unroll
        for (int ks = 0; ks < 2; ++ks) {
            bf16x8 af[4], bfr[4];
#pragma unroll
            for (int mf = 0; mf < 4; ++mf) {
                int row = wm + mf * 16 + lr;
                af[mf] = *(const bf16x8*)(Asl + TSW(row, ks * 64 + lk * 16));
            }
#pragma unroll
            for (int nf = 0; nf < 4; ++nf) {
                int rown = wn + nf * 16 + lr;
                bfr[nf] = *(const bf16x8*)(Bsl + TSW(rown, ks * 64 + lk * 16));
            }
#pragma unroll
            for (int mf = 0; mf < 4; ++mf)
#pragma unroll
                for (int nf = 0; nf < 4; ++nf)
                    acc[mf][nf] = __builtin_amdgcn_mfma_f32_16x16x32_bf16(af[mf], bfr[nf], acc[mf][nf], 0, 0, 0);
        }
        __syncthreads();
    }

#pragma unroll
    for (int nf = 0; nf < 4; ++nf) {
        const int col = n0 + wn + nf*16 + lr;
        const float bc = bcat[col];
#pragma unroll
        for (int mf = 0; mf < 4; ++mf)
#pragma unroll
            for (int r = 0; r < 4; ++r) {
                size_t row = (size_t)(m0 + wm + mf*16 + lk*4 + r);
                float x = acc[mf][nf][r] + bc;
                float g = 0.5f * x * (1.0f + erff(x * 0.70710678118654752f));
                x2[row * NH + col] = f2bf(g);
            }
    }
}

// ---------------------------------------------------------------------------
// Kernel B (fallback): reg-staged mixed GEMM (round-4 version).
// ---------------------------------------------------------------------------
__global__ __launch_bounds__(256) void kB(const float* __restrict__ h,
                                          const unsigned short* __restrict__ aware,
                                          const float* __restrict__ Wcat,
                                          const float* __restrict__ bcat,
                                          unsigned short* __restrict__ x2) {
    __shared__ __align__(16) char lds[16384];
    char* Asl = lds;
    char* Bsl = lds + 8192;

    const int tid  = threadIdx.x;
    const int lane = tid & 63;
    const int wid  = tid >> 6;
    const int wm   = (wid >> 1) * 64;
    const int wn   = (wid & 1) * 64;
    const int lr   = lane & 15;
    const int lk   = lane >> 4;

    const int id   = blockIdx.x;
    const int xcd  = id & 7;
    const int slot = id >> 3;
    const int m0   = (xcd * 16 + (slot >> 3)) * 128;
    const int n0   = (slot & 7) * 128;

    const int am = tid >> 1;
    const int ak = (tid & 1) * 16;
    const int bn = tid & 127;
    const int bk = (tid >> 7) * 16;

    f32x4 acc[4][4];
#pragma unroll
    for (int i = 0; i < 4; ++i)
#pragma unroll
        for (int j = 0; j < 4; ++j) acc[i][j] = (f32x4){0.f, 0.f, 0.f, 0.f};

    const float*          hrow = h     + (size_t)(m0 + am) * NH + ak;
    const unsigned short* arow = aware + (size_t)(m0 + am) * NH + ak;
    const float*          wcol = Wcat  + (size_t)bk * NH + n0 + bn;

    float hv[16];
    unsigned int aw[8];
    float wv[16];

    auto stage = [&](int kt) {
        const int region = kt >> 10;
        const int kb = kt & 1023;
        if (region != 1) {
            const float4* hp = (const float4*)(hrow + kb);
            float4 a = hp[0], b = hp[1], c = hp[2], d = hp[3];
            hv[0]=a.x; hv[1]=a.y; hv[2]=a.z; hv[3]=a.w;
            hv[4]=b.x; hv[5]=b.y; hv[6]=b.z; hv[7]=b.w;
            hv[8]=c.x; hv[9]=c.y; hv[10]=c.z; hv[11]=c.w;
            hv[12]=d.x; hv[13]=d.y; hv[14]=d.z; hv[15]=d.w;
        }
        if (region >= 1) {
            const uint4* ap = (const uint4*)(arow + kb);
            uint4 a0 = ap[0], a1 = ap[1];
            aw[0]=a0.x; aw[1]=a0.y; aw[2]=a0.z; aw[3]=a0.w;
            aw[4]=a1.x; aw[5]=a1.y; aw[6]=a1.z; aw[7]=a1.w;
        }
        {
            const float* wp = wcol + (size_t)kt * NH;
#pragma unroll
            for (int j = 0; j < 16; ++j) wv[j] = wp[(size_t)j * NH];
        }
    };

    auto writeStage = [&](int kt) {
        const int region = kt >> 10;
        unsigned int p[8];
        if (region == 0) {
#pragma unroll
            for (int i = 0; i < 8; ++i) p[i] = pk2(hv[2*i], hv[2*i+1]);
        } else if (region == 1) {
#pragma unroll
            for (int i = 0; i < 8; ++i) p[i] = aw[i];
        } else {
#pragma unroll
            for (int i = 0; i < 8; ++i) {
                float lo = hv[2*i]   * bf2f(aw[i] & 0xffffu);
                float hi = hv[2*i+1] * bf2f(aw[i] >> 16);
                p[i] = pk2(lo, hi);
            }
        }
        *(int4*)(Asl + SW64(am*64 + ak*2))      = make_int4(p[0], p[1], p[2], p[3]);
        *(int4*)(Asl + SW64(am*64 + ak*2 + 16)) = make_int4(p[4], p[5], p[6], p[7]);
        unsigned int q[8];
#pragma unroll
        for (int i = 0; i < 8; ++i) q[i] = pk2(wv[2*i], wv[2*i+1]);
        *(int4*)(Bsl + SW64(bn*64 + bk*2))      = make_int4(q[0], q[1], q[2], q[3]);
        *(int4*)(Bsl + SW64(bn*64 + bk*2 + 16)) = make_int4(q[4], q[5], q[6], q[7]);
    };

    stage(0);
    for (int kt = 0; kt < 3072; kt += 32) {
        __syncthreads();
        writeStage(kt);
        __syncthreads();
        if (kt + 32 < 3072) stage(kt + 32);

        bf16x8 af[4], bfr[4];
#pragma unroll
        for (int mf = 0; mf < 4; ++mf)
            af[mf] = *(const bf16x8*)(Asl + SW64((wm + mf*16 + lr)*64 + lk*16));
#pragma unroll
        for (int nf = 0; nf < 4; ++nf)
            bfr[nf] = *(const bf16x8*)(Bsl + SW64((wn + nf*16 + lr)*64 + lk*16));
#pragma unroll
        for (int mf = 0; mf < 4; ++mf)
#pragma unroll
            for (int nf = 0; nf < 4; ++nf)
                acc[mf][nf] = __builtin_amdgcn_mfma_f32_16x16x32_bf16(af[mf], bfr[nf], acc[mf][nf], 0, 0, 0);
    }

#pragma unroll
    for (int nf = 0; nf < 4; ++nf) {
        const int col = n0 + wn + nf*16 + lr;
        const float bc = bcat[col];
#pragma unroll
        for (int mf = 0; mf < 4; ++mf)
#pragma unroll
            for (int r = 0; r < 4; ++r) {
                size_t row = (size_t)(m0 + wm + mf*16 + lk*4 + r);
                float x = acc[mf][nf][r] + bc;
                float g = 0.5f * x * (1.0f + erff(x * 0.70710678118654752f));
                x2[row * NH + col] = f2bf(g);
            }
    }
}

// ---------------------------------------------------------------------------
// Kernel C: ner_scores = [x2 @ W_crf + b_crf, -10000, -10000]  (MFMA, N=48)
// ---------------------------------------------------------------------------
__global__ __launch_bounds__(256) void kC(const unsigned short* __restrict__ x2,
                                          const float* __restrict__ Wcrf,
                                          const float* __restrict__ bcrf,
                                          float* __restrict__ out) {
    __shared__ __align__(16) char Asl[8192];
    __shared__ __align__(16) char Bsl[3072];

    const int tid  = threadIdx.x;
    const int lane = tid & 63;
    const int wid  = tid >> 6;
    const int lr   = lane & 15;
    const int lk   = lane >> 4;
    const int m0   = blockIdx.x * 128;
    const int am   = tid >> 1;
    const int ak   = (tid & 1) * 16;

    for (int i = tid; i < 192; i += 256) *(int4*)(Bsl + i*16) = make_int4(0, 0, 0, 0);

    f32x4 acc[2][3];
#pragma unroll
    for (int i = 0; i < 2; ++i)
#pragma unroll
        for (int j = 0; j < 3; ++j) acc[i][j] = (f32x4){0.f, 0.f, 0.f, 0.f};

    const unsigned short* xrow = x2 + (size_t)(m0 + am) * NH + ak;

    for (int kt = 0; kt < NH; kt += 32) {
        const uint4* xp = (const uint4*)(xrow + kt);
        uint4 x0 = xp[0], x1 = xp[1];
        float wv[5];
#pragma unroll
        for (int p = 0; p < 5; ++p) {
            int i = tid + p * 256;
            wv[p] = (i < 32*NT) ? Wcrf[(size_t)kt * NT + i] : 0.f;
        }
        __syncthreads();
        *(uint4*)(Asl + SW64(am*64 + ak*2))      = x0;
        *(uint4*)(Asl + SW64(am*64 + ak*2 + 16)) = x1;
#pragma unroll
        for (int p = 0; p < 5; ++p) {
            int i = tid + p * 256;
            if (i < 32*NT) {
                int kk = i / NT;
                int t  = i - kk * NT;
                *(unsigned short*)(Bsl + SW64(t*64 + kk*2)) = f2bf(wv[p]);
            }
        }
        __syncthreads();
        bf16x8 af[2], bfr[3];
#pragma unroll
        for (int mf = 0; mf < 2; ++mf)
            af[mf] = *(const bf16x8*)(Asl + SW64((wid*32 + mf*16 + lr)*64 + lk*16));
#pragma unroll
        for (int nf = 0; nf < 3; ++nf)
            bfr[nf] = *(const bf16x8*)(Bsl + SW64((nf*16 + lr)*64 + lk*16));
#pragma unroll
        for (int mf = 0; mf < 2; ++mf)
#pragma unroll
            for (int nf = 0; nf < 3; ++nf)
                acc[mf][nf] = __builtin_amdgcn_mfma_f32_16x16x32_bf16(af[mf], bfr[nf], acc[mf][nf], 0, 0, 0);
    }

#pragma unroll
    for (int nf = 0; nf < 3; ++nf) {
        const int t = nf*16 + lr;
        const float bc = (t < NT) ? bcrf[t] : 0.f;
#pragma unroll
        for (int mf = 0; mf < 2; ++mf)
#pragma unroll
            for (int r = 0; r < 4; ++r) {
                size_t row = (size_t)(m0 + wid*32 + mf*16 + lk*4 + r);
                if (t < NT)       out[row * NLP + t] = acc[mf][nf][r] + bc;
                else if (t < NLP) out[row * NLP + t] = -10000.0f;
            }
    }
}

// ---------------------------------------------------------------------------
// Kernel D: CRF log-likelihood, exp-domain scan, scores STAGED IN LDS.
// Block = 256 threads (4 waves) per batch: all waves memcpy scores/labels/
// trans into LDS + compute the gold path in parallel; wave 0 then runs the
// serial scan reading logits from LDS (no global latency on the chain).
// ---------------------------------------------------------------------------
#define CRFSTEP(EL) do {                                   \
    float c0 = 0.f, c1 = 0.f, c2 = 0.f, c3 = 0.f;          \
    _Pragma("unroll")                                      \
    for (int f_ = 0; f_ < 36; f_ += 4) {                   \
        c0 = fmaf(rl(a, f_    ), trow[f_    ], c0);        \
        c1 = fmaf(rl(a, f_ + 1), trow[f_ + 1], c1);        \
        c2 = fmaf(rl(a, f_ + 2), trow[f_ + 2], c2);        \
        c3 = fmaf(rl(a, f_ + 3), trow[f_ + 3], c3);        \
    }                                                      \
    c0 = fmaf(rl(a, 36), trow[36], c0);                    \
    a = (EL) * ((c0 + c1) + (c2 + c3));                    \
} while (0)

__global__ __launch_bounds__(256) void kD(const float* __restrict__ scores,
                                          const int* __restrict__ labels,
                                          const int* __restrict__ lens,
                                          const float* __restrict__ trans,
                                          float* __restrict__ loss) {
    __shared__ float S[NS * NLP];      // 79872 B, packed [t][39]
    __shared__ float trL[39 * 41];     // 6396 B
    __shared__ int   labL[NS];         // 2048 B
    __shared__ float gred[4];

    const int b    = blockIdx.x;
    const int tid  = threadIdx.x;
    const int lane = tid & 63;
    const int wid  = tid >> 6;
    const int len  = lens[b];
    const float* sb = scores + (size_t)b * NS * NLP;

    // cooperative stage: scores (coalesced float4), labels, trans
    {
        const float4* src = (const float4*)sb;
        float4* dst = (float4*)S;
        for (int i = tid; i < NS * NLP / 4; i += 256) dst[i] = src[i];
    }
    for (int i = tid; i < NS; i += 256) labL[i] = labels[b * NS + i];
    for (int idx = tid; idx < 39 * 39; idx += 256) {
        int to = idx / 39, f = idx - to * 39;
        trL[to * 41 + f] = trans[idx];
    }
    __syncthreads();

    // gold path: all 256 threads over t, 4 wave-partials, combine in wave 0
    float g = 0.0f;
    for (int t = tid; t < len; t += 256) g += S[t * NLP + labL[t]];
    for (int i = tid; i <= len; i += 256) {
        int frm = (i == 0) ? 37 : labL[i - 1];
        int to  = (i == len) ? 38 : labL[i];
        g += trL[to * 41 + frm];
    }
#pragma unroll
    for (int off = 32; off > 0; off >>= 1) g += __shfl_xor(g, off, 64);
    if (lane == 0) gred[wid] = g;
    __syncthreads();

    if (wid != 0) return;    // waves 1-3 done (no further barriers below)

    const float gold = (gred[0] + gred[1]) + (gred[2] + gred[3]);

    const int myrow = (lane < 39) ? lane : 0;
    float trow[39];
#pragma unroll
    for (int f = 0; f < 39; ++f) trow[f] = __expf(trL[myrow * 41 + f]);
    const float trEnd = (lane < 39) ? trL[38 * 41 + lane] : 0.f;
    const bool act = (lane < 39);

    // t = 0 closed form: a[to] = exp(logit0[to]) * exp(trans[to][START])
    float l0 = act ? S[lane] : -10000.f;
    float a = act ? __expf(l0) * trow[37] : 0.f;
    float C = 0.0f;

    auto ldrow = [&](int r) {
        r = (r < len) ? r : (len - 1);
        return S[act ? (r * NLP + lane) : 0];
    };
    float lg0 = ldrow(1), lg1 = ldrow(2), lg2 = ldrow(3), lg3 = ldrow(4);

    int t = 1;
    for (; t + 3 < len; t += 4) {
        float e0 = __expf(lg0), e1 = __expf(lg1), e2 = __expf(lg2), e3 = __expf(lg3);
        lg0 = ldrow(t + 4); lg1 = ldrow(t + 5); lg2 = ldrow(t + 6); lg3 = ldrow(t + 7);
        CRFSTEP(e0); CRFSTEP(e1); CRFSTEP(e2); CRFSTEP(e3);
        float s = rl(a, 0);                       // a[0] > 0 always
        float rr = __builtin_amdgcn_rcpf(s);
        a *= rr; C -= __logf(rr);
    }
    for (; t < len; ++t) {
        float el = __expf(ldrow(t));
        CRFSTEP(el);
    }

    float aend = (act && a > 0.f) ? C + __logf(a) + trEnd : -1e30f;
    float mx = aend;
#pragma unroll
    for (int off = 32; off > 0; off >>= 1) mx = fmaxf(mx, __shfl_xor(mx, off, 64));
    float es = act ? __expf(aend - mx) : 0.0f;
#pragma unroll
    for (int off = 32; off > 0; off >>= 1) es += __shfl_xor(es, off, 64);
    float norm = mx + __logf(es);

    if (lane == 0) loss[b] = gold - norm;
}

// ---------------------------------------------------------------------------
extern "C" void kernel_launch(void* const* d_in, const int* in_sizes, int n_in,
                              void* d_out, int out_size, void* d_ws, size_t ws_size,
                              hipStream_t stream) {
    const float* h        = (const float*)d_in[0];
    const int* token_nums = (const int*)d_in[2];
    const int* labels     = (const int*)d_in[3];
    const float* bio      = (const float*)d_in[4];
    const float* Wcat     = (const float*)d_in[5];
    const float* bcat     = (const float*)d_in[6];
    const float* Wcrf     = (const float*)d_in[7];
    const float* bcrf     = (const float*)d_in[8];
    const float* trans    = (const float*)d_in[9];

    float* out = (float*)d_out;
    unsigned short* attn  = (unsigned short*)d_out;  // 2MB scratch, overwritten by kC

    const size_t ASW_BYTES = (size_t)128 * 48 * 16384;        // 96 MB
    const size_t X2_BYTES  = (size_t)NM * NH * 2;             // 32 MB
    const size_t WSW_BYTES = (size_t)8 * 48 * 16384;          // 6 MB
    const bool fast = ws_size >= ASW_BYTES + X2_BYTES + WSW_BYTES;

    hipLaunchKernelGGL(kA1, dim3(NM / 64), dim3(256), 0, stream, h, bio, attn);

    if (fast) {
        char* Asw           = (char*)d_ws;
        unsigned short* x2  = (unsigned short*)((char*)d_ws + ASW_BYTES);
        char* Wsw           = (char*)d_ws + ASW_BYTES + X2_BYTES;

        hipLaunchKernelGGL(kW, dim3(8 * 48), dim3(256), 0, stream, Wcat, Wsw);
        hipLaunchKernelGGL(kA2f, dim3(NH / 128, NM / 128), dim3(256), 0, stream,
                           attn, bio, h, Asw);
        hipLaunchKernelGGL(kBf, dim3((NH / 128) * (NM / 128)), dim3(256), 0, stream,
                           Asw, Wsw, bcat, x2);
        hipLaunchKernelGGL(kC, dim3(NM / 128), dim3(256), 0, stream, x2, Wcrf, bcrf, out);
    } else {
        unsigned short* aware = (unsigned short*)d_ws;
        unsigned short* x2    = aware + (size_t)NM * NH;

        hipLaunchKernelGGL(kA2, dim3(NH / 128, NM / 128), dim3(256), 0, stream, attn, bio, aware);
        hipLaunchKernelGGL(kB, dim3((NH / 128) * (NM / 128)), dim3(256), 0, stream,
                           h, aware, Wcat, bcat, x2);
        hipLaunchKernelGGL(kC, dim3(NM / 128), dim3(256), 0, stream, x2, Wcrf, bcrf, out);
    }

    hipLaunchKernelGGL(kD, dim3(NB), dim3(256), 0, stream, out, labels, token_nums, trans,
                       out + (size_t)NM * NLP);
}

// Round 9
// 299.220 us; speedup vs baseline: 12.6117x; 1.0674x over previous
//
#include <hip/hip_runtime.h>
#include <hip/hip_bf16.h>
#include <math.h>

#define NB 32
#define NS 512
#define NH 1024
#define NT 37
#define NLP 39
#define NM (NB*NS)   // 16384

typedef __attribute__((ext_vector_type(8))) short bf16x8;
typedef __attribute__((ext_vector_type(4))) float f32x4;

__device__ __forceinline__ float bf2f(unsigned int u) {
    unsigned int x = u << 16;
    float f;
    __builtin_memcpy(&f, &x, 4);
    return f;
}
__device__ __forceinline__ unsigned short f2bf(float f) {
    __hip_bfloat16 hb = __float2bfloat16(f);
    unsigned short u;
    __builtin_memcpy(&u, &hb, 2);
    return u;
}
__device__ __forceinline__ unsigned int pk2(float lo, float hi) {
    return ((unsigned int)f2bf(hi) << 16) | (unsigned int)f2bf(lo);
}
// bijective XOR swizzle for [row][64B] bf16 LDS tiles
__device__ __forceinline__ int SW64(int b)  { return b ^ ((b >> 2) & 0x70); }
// tile swizzle for [128 row][64 k] bf16 tiles (row stride 128B)
__device__ __forceinline__ int TSW(int row, int kcolByte) {
    return (row * 128 + kcolByte) ^ ((row & 7) << 4);
}
__device__ __forceinline__ float rl(float x, int l) {
    return __int_as_float(__builtin_amdgcn_readlane(__float_as_int(x), l));
}
__device__ __forceinline__ void gld16(const void* g, void* l) {
    __builtin_amdgcn_global_load_lds((const __attribute__((address_space(1))) void*)g,
                                     (__attribute__((address_space(3))) void*)l, 16, 0, 0);
}
#define VMW(N) asm volatile("s_waitcnt vmcnt(" #N ")" ::: "memory")
#define BARR() do { __builtin_amdgcn_s_barrier(); __builtin_amdgcn_sched_barrier(0); } while (0)

// ---------------------------------------------------------------------------
// Kernel A1: scores = h@bio^T /32 -> softmax -> attn (bf16, [NM][64], zero-pad)
// ---------------------------------------------------------------------------
__global__ __launch_bounds__(256) void kA1(const float* __restrict__ h,
                                           const float* __restrict__ bio,
                                           unsigned short* __restrict__ attn) {
    __shared__ __align__(16) char Asl[64 * 64];
    __shared__ __align__(16) char Bsl[48 * 64];

    const int tid  = threadIdx.x;
    const int lane = tid & 63;
    const int wid  = tid >> 6;
    const int lr   = lane & 15;
    const int lk   = lane >> 4;
    const int m0   = blockIdx.x * 64;

    const int arow = tid >> 2;
    const int aq   = (tid & 3) * 8;
    const int brow = tid >> 1;
    const int bkh  = (tid & 1) * 16;

    f32x4 sacc[3];
#pragma unroll
    for (int j = 0; j < 3; ++j) sacc[j] = (f32x4){0.f, 0.f, 0.f, 0.f};

    const float* hrow = h + (size_t)(m0 + arow) * NH + aq;

    for (int kt = 0; kt < NH; kt += 32) {
        float hv[8];
        {
            const float4* hp = (const float4*)(hrow + kt);
            float4 a = hp[0], b = hp[1];
            hv[0]=a.x; hv[1]=a.y; hv[2]=a.z; hv[3]=a.w;
            hv[4]=b.x; hv[5]=b.y; hv[6]=b.z; hv[7]=b.w;
        }
        float bv[16];
        if (tid < 96) {
            if (brow < NT) {
                const float4* bp = (const float4*)(bio + (size_t)brow * NH + kt + bkh);
                float4 a = bp[0], b = bp[1], c = bp[2], d = bp[3];
                bv[0]=a.x; bv[1]=a.y; bv[2]=a.z; bv[3]=a.w;
                bv[4]=b.x; bv[5]=b.y; bv[6]=b.z; bv[7]=b.w;
                bv[8]=c.x; bv[9]=c.y; bv[10]=c.z; bv[11]=c.w;
                bv[12]=d.x; bv[13]=d.y; bv[14]=d.z; bv[15]=d.w;
            } else {
#pragma unroll
                for (int i = 0; i < 16; ++i) bv[i] = 0.f;
            }
        }
        __syncthreads();
        {
            unsigned int p[4];
#pragma unroll
            for (int i = 0; i < 4; ++i) p[i] = pk2(hv[2*i], hv[2*i+1]);
            *(int4*)(Asl + SW64(arow*64 + aq*2)) = make_int4(p[0], p[1], p[2], p[3]);
        }
        if (tid < 96) {
            unsigned int p[8];
#pragma unroll
            for (int i = 0; i < 8; ++i) p[i] = pk2(bv[2*i], bv[2*i+1]);
            *(int4*)(Bsl + SW64(brow*64 + bkh*2))      = make_int4(p[0], p[1], p[2], p[3]);
            *(int4*)(Bsl + SW64(brow*64 + bkh*2 + 16)) = make_int4(p[4], p[5], p[6], p[7]);
        }
        __syncthreads();
        bf16x8 af = *(const bf16x8*)(Asl + SW64((wid*16 + lr)*64 + lk*16));
#pragma unroll
        for (int nf = 0; nf < 3; ++nf) {
            bf16x8 bfr = *(const bf16x8*)(Bsl + SW64((nf*16 + lr)*64 + lk*16));
            sacc[nf] = __builtin_amdgcn_mfma_f32_16x16x32_bf16(af, bfr, sacc[nf], 0, 0, 0);
        }
    }

#pragma unroll
    for (int r = 0; r < 4; ++r) {
        const int row = wid*16 + lk*4 + r;
        float s0 = sacc[0][r] * 0.03125f;
        float s1 = sacc[1][r] * 0.03125f;
        float s2 = sacc[2][r] * 0.03125f;
        const bool v2 = (lr < 5);
        float mx = fmaxf(fmaxf(s0, s1), v2 ? s2 : -1e30f);
#pragma unroll
        for (int d = 1; d < 16; d <<= 1) mx = fmaxf(mx, __shfl_xor(mx, d, 64));
        float e0 = __expf(s0 - mx), e1 = __expf(s1 - mx);
        float e2 = v2 ? __expf(s2 - mx) : 0.f;
        float sm = e0 + e1 + e2;
#pragma unroll
        for (int d = 1; d < 16; d <<= 1) sm += __shfl_xor(sm, d, 64);
        float inv = 1.f / sm;
        size_t g = (size_t)(m0 + row) * 64;
        attn[g + lr]      = f2bf(e0 * inv);
        attn[g + 16 + lr] = f2bf(e1 * inv);
        attn[g + 32 + lr] = f2bf(e2 * inv);
        attn[g + 48 + lr] = 0;
    }
}

// ---------------------------------------------------------------------------
// Kernel A2 (fallback): aware = attn @ bio, plain bf16 row-major out.
// ---------------------------------------------------------------------------
__global__ __launch_bounds__(256) void kA2(const unsigned short* __restrict__ attn,
                                           const float* __restrict__ bio,
                                           unsigned short* __restrict__ aware) {
    __shared__ __align__(16) char Bsl[128 * 64];

    const int tid  = threadIdx.x;
    const int lane = tid & 63;
    const int wid  = tid >> 6;
    const int wm   = (wid >> 1) * 64;
    const int wn   = (wid & 1) * 64;
    const int lr   = lane & 15;
    const int lk   = lane >> 4;
    const int n0   = blockIdx.x * 128;
    const int m0   = blockIdx.y * 128;

    const int bn = tid & 127;
    const int bq = (tid >> 7) * 16;

    f32x4 acc[4][4];
#pragma unroll
    for (int i = 0; i < 4; ++i)
#pragma unroll
        for (int j = 0; j < 4; ++j) acc[i][j] = (f32x4){0.f, 0.f, 0.f, 0.f};

#pragma unroll
    for (int ks = 0; ks < 2; ++ks) {
        unsigned int p[8];
#pragma unroll
        for (int i = 0; i < 8; ++i) {
            int t0 = ks*32 + bq + 2*i;
            float lo = (t0     < NT) ? bio[(size_t)t0 * NH + n0 + bn]       : 0.f;
            float hi = (t0 + 1 < NT) ? bio[(size_t)(t0+1) * NH + n0 + bn]   : 0.f;
            p[i] = pk2(lo, hi);
        }
        __syncthreads();
        *(int4*)(Bsl + SW64(bn*64 + bq*2))      = make_int4(p[0], p[1], p[2], p[3]);
        *(int4*)(Bsl + SW64(bn*64 + bq*2 + 16)) = make_int4(p[4], p[5], p[6], p[7]);
        __syncthreads();

        bf16x8 af[4];
#pragma unroll
        for (int mf = 0; mf < 4; ++mf)
            af[mf] = *(const bf16x8*)(attn + (size_t)(m0 + wm + mf*16 + lr) * 64 + ks*32 + lk*8);
#pragma unroll
        for (int nf = 0; nf < 4; ++nf) {
            bf16x8 bb = *(const bf16x8*)(Bsl + SW64((wn + nf*16 + lr)*64 + lk*16));
#pragma unroll
            for (int mf = 0; mf < 4; ++mf)
                acc[mf][nf] = __builtin_amdgcn_mfma_f32_16x16x32_bf16(af[mf], bb, acc[mf][nf], 0, 0, 0);
        }
    }

#pragma unroll
    for (int mf = 0; mf < 4; ++mf)
#pragma unroll
        for (int nf = 0; nf < 4; ++nf)
#pragma unroll
            for (int r = 0; r < 4; ++r) {
                size_t row = (size_t)(m0 + wm + mf*16 + lk*4 + r);
                aware[row * NH + n0 + wn + nf*16 + lr] = f2bf(acc[mf][nf][r]);
            }
}

// ---------------------------------------------------------------------------
// Kernel A2f (fast): computes aware chunk AND writes the full concat-A
// [h | aware | h*aware] in bf16, tile-major (128x64 tiles) with TSW swizzle.
// ---------------------------------------------------------------------------
__global__ __launch_bounds__(256) void kA2f(const unsigned short* __restrict__ attn,
                                            const float* __restrict__ bio,
                                            const float* __restrict__ h,
                                            char* __restrict__ Asw) {
    __shared__ __align__(16) char Bsl[128 * 64];
    __shared__ __align__(16) unsigned short awL[128 * 128];  // 32KB aware chunk

    const int tid  = threadIdx.x;
    const int lane = tid & 63;
    const int wid  = tid >> 6;
    const int wm   = (wid >> 1) * 64;
    const int wn   = (wid & 1) * 64;
    const int lr   = lane & 15;
    const int lk   = lane >> 4;
    const int n0   = blockIdx.x * 128;
    const int m0   = blockIdx.y * 128;
    const int tm   = blockIdx.y;

    const int bn = tid & 127;
    const int bq = (tid >> 7) * 16;

    f32x4 acc[4][4];
#pragma unroll
    for (int i = 0; i < 4; ++i)
#pragma unroll
        for (int j = 0; j < 4; ++j) acc[i][j] = (f32x4){0.f, 0.f, 0.f, 0.f};

#pragma unroll
    for (int ks = 0; ks < 2; ++ks) {
        unsigned int p[8];
#pragma unroll
        for (int i = 0; i < 8; ++i) {
            int t0 = ks*32 + bq + 2*i;
            float lo = (t0     < NT) ? bio[(size_t)t0 * NH + n0 + bn]       : 0.f;
            float hi = (t0 + 1 < NT) ? bio[(size_t)(t0+1) * NH + n0 + bn]   : 0.f;
            p[i] = pk2(lo, hi);
        }
        __syncthreads();
        *(int4*)(Bsl + SW64(bn*64 + bq*2))      = make_int4(p[0], p[1], p[2], p[3]);
        *(int4*)(Bsl + SW64(bn*64 + bq*2 + 16)) = make_int4(p[4], p[5], p[6], p[7]);
        __syncthreads();

        bf16x8 af[4];
#pragma unroll
        for (int mf = 0; mf < 4; ++mf)
            af[mf] = *(const bf16x8*)(attn + (size_t)(m0 + wm + mf*16 + lr) * 64 + ks*32 + lk*8);
#pragma unroll
        for (int nf = 0; nf < 4; ++nf) {
            bf16x8 bb = *(const bf16x8*)(Bsl + SW64((wn + nf*16 + lr)*64 + lk*16));
#pragma unroll
            for (int mf = 0; mf < 4; ++mf)
                acc[mf][nf] = __builtin_amdgcn_mfma_f32_16x16x32_bf16(af[mf], bb, acc[mf][nf], 0, 0, 0);
        }
    }

#pragma unroll
    for (int mf = 0; mf < 4; ++mf)
#pragma unroll
        for (int nf = 0; nf < 4; ++nf)
#pragma unroll
            for (int r = 0; r < 4; ++r)
                awL[(wm + mf*16 + lk*4 + r) * 128 + wn + nf*16 + lr] = f2bf(acc[mf][nf][r]);
    __syncthreads();

    // region 1 (aware)
#pragma unroll
    for (int i = 0; i < 8; ++i) {
        int lin = tid + i * 256;
        int row = lin >> 4, kg = lin & 15;
        uint4 v = *(const uint4*)&awL[row * 128 + kg * 8];
        int kglob = 1024 + n0 + kg * 8;
        size_t tbase = ((size_t)tm * 48 + (kglob >> 6)) * 16384;
        *(uint4*)(Asw + tbase + TSW(row, (kglob & 63) * 2)) = v;
    }
    // regions 0 (h) and 2 (h*aware)
#pragma unroll
    for (int i = 0; i < 8; ++i) {
        int lin = tid + i * 256;
        int row = lin >> 4, kg = lin & 15;
        const float4* hp = (const float4*)&h[(size_t)(m0 + row) * NH + n0 + kg * 8];
        float4 ha = hp[0], hb = hp[1];
        float hv[8] = {ha.x, ha.y, ha.z, ha.w, hb.x, hb.y, hb.z, hb.w};
        uint4 awv = *(const uint4*)&awL[row * 128 + kg * 8];
        unsigned int awu[4] = {awv.x, awv.y, awv.z, awv.w};
        unsigned int p0[4], p2[4];
#pragma unroll
        for (int j = 0; j < 4; ++j) {
            p0[j] = pk2(hv[2*j], hv[2*j+1]);
            float lo = hv[2*j]   * bf2f(awu[j] & 0xffffu);
            float hi = hv[2*j+1] * bf2f(awu[j] >> 16);
            p2[j] = pk2(lo, hi);
        }
        int k0g = n0 + kg * 8;
        size_t tb0 = ((size_t)tm * 48 + (k0g >> 6)) * 16384;
        *(uint4*)(Asw + tb0 + TSW(row, (k0g & 63) * 2)) = make_uint4(p0[0], p0[1], p0[2], p0[3]);
        int k2g = 2048 + n0 + kg * 8;
        size_t tb2 = ((size_t)tm * 48 + (k2g >> 6)) * 16384;
        *(uint4*)(Asw + tb2 + TSW(row, (k2g & 63) * 2)) = make_uint4(p2[0], p2[1], p2[2], p2[3]);
    }
}

// ---------------------------------------------------------------------------
// Kernel W: WbT swizzled tiles: W^T[n][k] bf16, tile (tn,tk) = [128 n][64 k].
// ---------------------------------------------------------------------------
__global__ __launch_bounds__(256) void kW(const float* __restrict__ Wcat,
                                          char* __restrict__ Wsw) {
    __shared__ unsigned short wt[64 * 128];

    const int tid  = threadIdx.x;
    const int tile = blockIdx.x;
    const int tn   = tile / 48;
    const int tk   = tile - tn * 48;
    const int n00  = tn * 128;
    const int k0   = tk * 64;

#pragma unroll
    for (int i = 0; i < 8; ++i) {
        int lin = tid + i * 256;
        int kk = lin >> 5, ng = lin & 31;
        float4 v = *(const float4*)&Wcat[(size_t)(k0 + kk) * NH + n00 + ng * 4];
        unsigned int lo = pk2(v.x, v.y), hi = pk2(v.z, v.w);
        *(uint2*)&wt[kk * 128 + ng * 4] = make_uint2(lo, hi);
    }
    __syncthreads();
#pragma unroll
    for (int i = 0; i < 4; ++i) {
        int lin = tid + i * 256;
        int rn = lin >> 3, kg = lin & 7;
        unsigned short t8[8];
#pragma unroll
        for (int j = 0; j < 8; ++j) t8[j] = wt[(kg * 8 + j) * 128 + rn];
        uint4 v = *(const uint4*)t8;
        *(uint4*)(Wsw + (size_t)tile * 16384 + TSW(rn, kg * 16)) = v;
    }
}

// ---------------------------------------------------------------------------
// Kernel Bf (fast): 256x256 tile bf16 GEMM, BK=64, 8 waves, 8-phase-style
// counted-vmcnt schedule. LDS = 4 half-tile slots per operand (2 halves x
// 2 bufs x 16KB). Wave owns one 64x32 quadrant in each (A-half,B-half)
// combo, so phases consume halves progressively:
//   compute ph0:(A0,B0) ph1:(A0,B1) ph2:(A1,B0) ph3:(A1,B1)
//   stage (tile T+1) ph0:A0 ph1:B0 ph2:B1 ph3:A1  -> gap >= 3 phases
// vmcnt(6) at ph0-2 (3 stages in flight), none at ph3 -> never drains.
// ---------------------------------------------------------------------------
__global__ __launch_bounds__(512, 2) void kBf(const char* __restrict__ Asw,
                                              const char* __restrict__ Wsw,
                                              const float* __restrict__ bcat,
                                              unsigned short* __restrict__ x2) {
    __shared__ __align__(16) char lds[131072];  // A: buf*32768+h*16384; B at +65536

    const int tid  = threadIdx.x;
    const int lane = tid & 63;
    const int wid  = tid >> 6;
    const int widm = wid >> 2;       // 0..1
    const int widn = wid & 3;        // 0..3
    const int lr   = lane & 15;
    const int lk   = lane >> 4;

    const int id   = blockIdx.x;     // 256 blocks
    const int xcd  = id & 7;
    const int slot = id >> 3;        // 0..31
    const int Mt   = xcd * 8 + (slot >> 2);   // 256-row tile
    const int Nt   = slot & 3;                // 256-col tile
    const int m0   = Mt * 256, n0 = Nt * 256;
    const int soff = tid * 16;

    f32x4 acc00[4][2], acc01[4][2], acc10[4][2], acc11[4][2];
#pragma unroll
    for (int i = 0; i < 4; ++i)
#pragma unroll
        for (int j = 0; j < 2; ++j) {
            acc00[i][j] = (f32x4){0.f,0.f,0.f,0.f};
            acc01[i][j] = (f32x4){0.f,0.f,0.f,0.f};
            acc10[i][j] = (f32x4){0.f,0.f,0.f,0.f};
            acc11[i][j] = (f32x4){0.f,0.f,0.f,0.f};
        }

    // stage half 'ph' of tile T into buf T&1. ph: 0=A-h0, 1=B-h0, 2=B-h1, 3=A-h1
    auto stageHalf = [&](int T, int ph) {
        const bool isA = (ph == 0) || (ph == 3);
        const int  h   = isA ? (ph == 3 ? 1 : 0) : (ph - 1);
        const char* src = isA
            ? Asw + ((size_t)((2*Mt + h) * 48 + T)) * 16384
            : Wsw + ((size_t)((2*Nt + h) * 48 + T)) * 16384;
        char* dst = lds + (isA ? 0 : 65536) + (T & 1) * 32768 + h * 16384;
        gld16(src + soff,        dst + soff);
        gld16(src + soff + 8192, dst + soff + 8192);
    };
    auto loadA = [&](bf16x8 (&af)[4][2], int q, int half) {
        const char* base = lds + q * 32768 + half * 16384;
#pragma unroll
        for (int i = 0; i < 4; ++i) {
            int row = widm * 64 + i * 16 + lr;
#pragma unroll
            for (int kk = 0; kk < 2; ++kk)
                af[i][kk] = *(const bf16x8*)(base + TSW(row, kk * 64 + lk * 16));
        }
    };
    auto loadB = [&](bf16x8 (&bfr)[2][2], int q, int half) {
        const char* base = lds + 65536 + q * 32768 + half * 16384;
#pragma unroll
        for (int j = 0; j < 2; ++j) {
            int col = widn * 32 + j * 16 + lr;
#pragma unroll
            for (int kk = 0; kk < 2; ++kk)
                bfr[j][kk] = *(const bf16x8*)(base + TSW(col, kk * 64 + lk * 16));
        }
    };
    auto mma = [&](f32x4 (&ac)[4][2], bf16x8 (&af)[4][2], bf16x8 (&bfr)[2][2]) {
        __builtin_amdgcn_s_setprio(1);
#pragma unroll
        for (int kk = 0; kk < 2; ++kk)
#pragma unroll
            for (int i = 0; i < 4; ++i)
#pragma unroll
                for (int j = 0; j < 2; ++j)
                    ac[i][j] = __builtin_amdgcn_mfma_f32_16x16x32_bf16(
                        af[i][kk], bfr[j][kk], ac[i][j], 0, 0, 0);
        __builtin_amdgcn_s_setprio(0);
    };

    // prologue: stage tile 0 fully, drain once
    stageHalf(0, 0); stageHalf(0, 1); stageHalf(0, 2); stageHalf(0, 3);
    VMW(0);
    BARR();

    for (int T = 0; T < 47; ++T) {
        const int q = T & 1;
        bf16x8 af0[4][2], af1[4][2], bf0[2][2], bf1[2][2];
        // ph0: compute (A0,B0); stage (T+1, A0)
        stageHalf(T + 1, 0);
        VMW(6);
        BARR();
        loadA(af0, q, 0); loadB(bf0, q, 0);
        mma(acc00, af0, bf0);
        // ph1: compute (A0,B1); stage (T+1, B0)
        stageHalf(T + 1, 1);
        VMW(6);
        BARR();
        loadB(bf1, q, 1);
        mma(acc01, af0, bf1);
        // ph2: compute (A1,B0); stage (T+1, B1)
        stageHalf(T + 1, 2);
        VMW(6);
        BARR();
        loadA(af1, q, 1);
        mma(acc10, af1, bf0);
        // ph3: compute (A1,B1); stage (T+1, A1); no wait
        stageHalf(T + 1, 3);
        BARR();
        mma(acc11, af1, bf1);
    }
    {   // T = 47 (buf 1), tail waits 4/2/0
        const int q = 1;
        bf16x8 af0[4][2], af1[4][2], bf0[2][2], bf1[2][2];
        VMW(4);
        BARR();
        loadA(af0, q, 0); loadB(bf0, q, 0);
        mma(acc00, af0, bf0);
        VMW(2);
        BARR();
        loadB(bf1, q, 1);
        mma(acc01, af0, bf1);
        VMW(0);
        BARR();
        loadA(af1, q, 1);
        mma(acc10, af1, bf0);
        BARR();
        mma(acc11, af1, bf1);
    }

    // epilogue: quadrant (a,b) -> rows m0+a*128+widm*64+..., cols n0+b*128+widn*32+...
    auto writeQ = [&](f32x4 (&ac)[4][2], int a, int b) {
#pragma unroll
        for (int j = 0; j < 2; ++j) {
            const int col = n0 + b * 128 + widn * 32 + j * 16 + lr;
            const float bc = bcat[col];
#pragma unroll
            for (int i = 0; i < 4; ++i)
#pragma unroll
                for (int r = 0; r < 4; ++r) {
                    size_t row = (size_t)(m0 + a * 128 + widm * 64 + i * 16 + lk * 4 + r);
                    float x = ac[i][j][r] + bc;
                    float g = 0.5f * x * (1.0f + erff(x * 0.70710678118654752f));
                    x2[row * NH + col] = f2bf(g);
                }
        }
    };
    writeQ(acc00, 0, 0); writeQ(acc01, 0, 1); writeQ(acc10, 1, 0); writeQ(acc11, 1, 1);
}

// ---------------------------------------------------------------------------
// Kernel B (fallback): reg-staged mixed GEMM (round-4 version).
// ---------------------------------------------------------------------------
__global__ __launch_bounds__(256) void kB(const float* __restrict__ h,
                                          const unsigned short* __restrict__ aware,
                                          const float* __restrict__ Wcat,
                                          const float* __restrict__ bcat,
                                          unsigned short* __restrict__ x2) {
    __shared__ __align__(16) char lds[16384];
    char* Asl = lds;
    char* Bsl = lds + 8192;

    const int tid  = threadIdx.x;
    const int lane = tid & 63;
    const int wid  = tid >> 6;
    const int wm   = (wid >> 1) * 64;
    const int wn   = (wid & 1) * 64;
    const int lr   = lane & 15;
    const int lk   = lane >> 4;

    const int id   = blockIdx.x;
    const int xcd  = id & 7;
    const int slot = id >> 3;
    const int m0   = (xcd * 16 + (slot >> 3)) * 128;
    const int n0   = (slot & 7) * 128;

    const int am = tid >> 1;
    const int ak = (tid & 1) * 16;
    const int bn = tid & 127;
    const int bk = (tid >> 7) * 16;

    f32x4 acc[4][4];
#pragma unroll
    for (int i = 0; i < 4; ++i)
#pragma unroll
        for (int j = 0; j < 4; ++j) acc[i][j] = (f32x4){0.f, 0.f, 0.f, 0.f};

    const float*          hrow = h     + (size_t)(m0 + am) * NH + ak;
    const unsigned short* arow = aware + (size_t)(m0 + am) * NH + ak;
    const float*          wcol = Wcat  + (size_t)bk * NH + n0 + bn;

    float hv[16];
    unsigned int aw[8];
    float wv[16];

    auto stage = [&](int kt) {
        const int region = kt >> 10;
        const int kb = kt & 1023;
        if (region != 1) {
            const float4* hp = (const float4*)(hrow + kb);
            float4 a = hp[0], b = hp[1], c = hp[2], d = hp[3];
            hv[0]=a.x; hv[1]=a.y; hv[2]=a.z; hv[3]=a.w;
            hv[4]=b.x; hv[5]=b.y; hv[6]=b.z; hv[7]=b.w;
            hv[8]=c.x; hv[9]=c.y; hv[10]=c.z; hv[11]=c.w;
            hv[12]=d.x; hv[13]=d.y; hv[14]=d.z; hv[15]=d.w;
        }
        if (region >= 1) {
            const uint4* ap = (const uint4*)(arow + kb);
            uint4 a0 = ap[0], a1 = ap[1];
            aw[0]=a0.x; aw[1]=a0.y; aw[2]=a0.z; aw[3]=a0.w;
            aw[4]=a1.x; aw[5]=a1.y; aw[6]=a1.z; aw[7]=a1.w;
        }
        {
            const float* wp = wcol + (size_t)kt * NH;
#pragma unroll
            for (int j = 0; j < 16; ++j) wv[j] = wp[(size_t)j * NH];
        }
    };

    auto writeStage = [&](int kt) {
        const int region = kt >> 10;
        unsigned int p[8];
        if (region == 0) {
#pragma unroll
            for (int i = 0; i < 8; ++i) p[i] = pk2(hv[2*i], hv[2*i+1]);
        } else if (region == 1) {
#pragma unroll
            for (int i = 0; i < 8; ++i) p[i] = aw[i];
        } else {
#pragma unroll
            for (int i = 0; i < 8; ++i) {
                float lo = hv[2*i]   * bf2f(aw[i] & 0xffffu);
                float hi = hv[2*i+1] * bf2f(aw[i] >> 16);
                p[i] = pk2(lo, hi);
            }
        }
        *(int4*)(Asl + SW64(am*64 + ak*2))      = make_int4(p[0], p[1], p[2], p[3]);
        *(int4*)(Asl + SW64(am*64 + ak*2 + 16)) = make_int4(p[4], p[5], p[6], p[7]);
        unsigned int q[8];
#pragma unroll
        for (int i = 0; i < 8; ++i) q[i] = pk2(wv[2*i], wv[2*i+1]);
        *(int4*)(Bsl + SW64(bn*64 + bk*2))      = make_int4(q[0], q[1], q[2], q[3]);
        *(int4*)(Bsl + SW64(bn*64 + bk*2 + 16)) = make_int4(q[4], q[5], q[6], q[7]);
    };

    stage(0);
    for (int kt = 0; kt < 3072; kt += 32) {
        __syncthreads();
        writeStage(kt);
        __syncthreads();
        if (kt + 32 < 3072) stage(kt + 32);

        bf16x8 af[4], bfr[4];
#pragma unroll
        for (int mf = 0; mf < 4; ++mf)
            af[mf] = *(const bf16x8*)(Asl + SW64((wm + mf*16 + lr)*64 + lk*16));
#pragma unroll
        for (int nf = 0; nf < 4; ++nf)
            bfr[nf] = *(const bf16x8*)(Bsl + SW64((wn + nf*16 + lr)*64 + lk*16));
#pragma unroll
        for (int mf = 0; mf < 4; ++mf)
#pragma unroll
            for (int nf = 0; nf < 4; ++nf)
                acc[mf][nf] = __builtin_amdgcn_mfma_f32_16x16x32_bf16(af[mf], bfr[nf], acc[mf][nf], 0, 0, 0);
    }

#pragma unroll
    for (int nf = 0; nf < 4; ++nf) {
        const int col = n0 + wn + nf*16 + lr;
        const float bc = bcat[col];
#pragma unroll
        for (int mf = 0; mf < 4; ++mf)
#pragma unroll
            for (int r = 0; r < 4; ++r) {
                size_t row = (size_t)(m0 + wm + mf*16 + lk*4 + r);
                float x = acc[mf][nf][r] + bc;
                float g = 0.5f * x * (1.0f + erff(x * 0.70710678118654752f));
                x2[row * NH + col] = f2bf(g);
            }
    }
}

// ---------------------------------------------------------------------------
// Kernel C: ner_scores = [x2 @ W_crf + b_crf, -10000, -10000]  (MFMA, N=48)
// ---------------------------------------------------------------------------
__global__ __launch_bounds__(256) void kC(const unsigned short* __restrict__ x2,
                                          const float* __restrict__ Wcrf,
                                          const float* __restrict__ bcrf,
                                          float* __restrict__ out) {
    __shared__ __align__(16) char Asl[8192];
    __shared__ __align__(16) char Bsl[3072];

    const int tid  = threadIdx.x;
    const int lane = tid & 63;
    const int wid  = tid >> 6;
    const int lr   = lane & 15;
    const int lk   = lane >> 4;
    const int m0   = blockIdx.x * 128;
    const int am   = tid >> 1;
    const int ak   = (tid & 1) * 16;

    for (int i = tid; i < 192; i += 256) *(int4*)(Bsl + i*16) = make_int4(0, 0, 0, 0);

    f32x4 acc[2][3];
#pragma unroll
    for (int i = 0; i < 2; ++i)
#pragma unroll
        for (int j = 0; j < 3; ++j) acc[i][j] = (f32x4){0.f, 0.f, 0.f, 0.f};

    const unsigned short* xrow = x2 + (size_t)(m0 + am) * NH + ak;

    for (int kt = 0; kt < NH; kt += 32) {
        const uint4* xp = (const uint4*)(xrow + kt);
        uint4 x0 = xp[0], x1 = xp[1];
        float wv[5];
#pragma unroll
        for (int p = 0; p < 5; ++p) {
            int i = tid + p * 256;
            wv[p] = (i < 32*NT) ? Wcrf[(size_t)kt * NT + i] : 0.f;
        }
        __syncthreads();
        *(uint4*)(Asl + SW64(am*64 + ak*2))      = x0;
        *(uint4*)(Asl + SW64(am*64 + ak*2 + 16)) = x1;
#pragma unroll
        for (int p = 0; p < 5; ++p) {
            int i = tid + p * 256;
            if (i < 32*NT) {
                int kk = i / NT;
                int t  = i - kk * NT;
                *(unsigned short*)(Bsl + SW64(t*64 + kk*2)) = f2bf(wv[p]);
            }
        }
        __syncthreads();
        bf16x8 af[2], bfr[3];
#pragma unroll
        for (int mf = 0; mf < 2; ++mf)
            af[mf] = *(const bf16x8*)(Asl + SW64((wid*32 + mf*16 + lr)*64 + lk*16));
#pragma unroll
        for (int nf = 0; nf < 3; ++nf)
            bfr[nf] = *(const bf16x8*)(Bsl + SW64((nf*16 + lr)*64 + lk*16));
#pragma unroll
        for (int mf = 0; mf < 2; ++mf)
#pragma unroll
            for (int nf = 0; nf < 3; ++nf)
                acc[mf][nf] = __builtin_amdgcn_mfma_f32_16x16x32_bf16(af[mf], bfr[nf], acc[mf][nf], 0, 0, 0);
    }

#pragma unroll
    for (int nf = 0; nf < 3; ++nf) {
        const int t = nf*16 + lr;
        const float bc = (t < NT) ? bcrf[t] : 0.f;
#pragma unroll
        for (int mf = 0; mf < 2; ++mf)
#pragma unroll
            for (int r = 0; r < 4; ++r) {
                size_t row = (size_t)(m0 + wid*32 + mf*16 + lk*4 + r);
                if (t < NT)       out[row * NLP + t] = acc[mf][nf][r] + bc;
                else if (t < NLP) out[row * NLP + t] = -10000.0f;
            }
    }
}

// ---------------------------------------------------------------------------
// Kernel D: CRF log-likelihood, exp-domain scan, scores staged in LDS.
// ---------------------------------------------------------------------------
#define CRFSTEP(EL) do {                                   \
    float c0 = 0.f, c1 = 0.f, c2 = 0.f, c3 = 0.f;          \
    _Pragma("unroll")                                      \
    for (int f_ = 0; f_ < 36; f_ += 4) {                   \
        c0 = fmaf(rl(a, f_    ), trow[f_    ], c0);        \
        c1 = fmaf(rl(a, f_ + 1), trow[f_ + 1], c1);        \
        c2 = fmaf(rl(a, f_ + 2), trow[f_ + 2], c2);        \
        c3 = fmaf(rl(a, f_ + 3), trow[f_ + 3], c3);        \
    }                                                      \
    c0 = fmaf(rl(a, 36), trow[36], c0);                    \
    a = (EL) * ((c0 + c1) + (c2 + c3));                    \
} while (0)

__global__ __launch_bounds__(256) void kD(const float* __restrict__ scores,
                                          const int* __restrict__ labels,
                                          const int* __restrict__ lens,
                                          const float* __restrict__ trans,
                                          float* __restrict__ loss) {
    __shared__ float S[NS * NLP];      // 79872 B, packed [t][39]
    __shared__ float trL[39 * 41];     // 6396 B
    __shared__ int   labL[NS];         // 2048 B
    __shared__ float gred[4];

    const int b    = blockIdx.x;
    const int tid  = threadIdx.x;
    const int lane = tid & 63;
    const int wid  = tid >> 6;
    const int len  = lens[b];
    const float* sb = scores + (size_t)b * NS * NLP;

    {
        const float4* src = (const float4*)sb;
        float4* dst = (float4*)S;
        for (int i = tid; i < NS * NLP / 4; i += 256) dst[i] = src[i];
    }
    for (int i = tid; i < NS; i += 256) labL[i] = labels[b * NS + i];
    for (int idx = tid; idx < 39 * 39; idx += 256) {
        int to = idx / 39, f = idx - to * 39;
        trL[to * 41 + f] = trans[idx];
    }
    __syncthreads();

    float g = 0.0f;
    for (int t = tid; t < len; t += 256) g += S[t * NLP + labL[t]];
    for (int i = tid; i <= len; i += 256) {
        int frm = (i == 0) ? 37 : labL[i - 1];
        int to  = (i == len) ? 38 : labL[i];
        g += trL[to * 41 + frm];
    }
#pragma unroll
    for (int off = 32; off > 0; off >>= 1) g += __shfl_xor(g, off, 64);
    if (lane == 0) gred[wid] = g;
    __syncthreads();

    if (wid != 0) return;

    const float gold = (gred[0] + gred[1]) + (gred[2] + gred[3]);

    const int myrow = (lane < 39) ? lane : 0;
    float trow[39];
#pragma unroll
    for (int f = 0; f < 39; ++f) trow[f] = __expf(trL[myrow * 41 + f]);
    const float trEnd = (lane < 39) ? trL[38 * 41 + lane] : 0.f;
    const bool act = (lane < 39);

    float l0 = act ? S[lane] : -10000.f;
    float a = act ? __expf(l0) * trow[37] : 0.f;
    float C = 0.0f;

    auto ldrow = [&](int r) {
        r = (r < len) ? r : (len - 1);
        return S[act ? (r * NLP + lane) : 0];
    };
    float lg0 = ldrow(1), lg1 = ldrow(2), lg2 = ldrow(3), lg3 = ldrow(4);

    int t = 1;
    for (; t + 3 < len; t += 4) {
        float e0 = __expf(lg0), e1 = __expf(lg1), e2 = __expf(lg2), e3 = __expf(lg3);
        lg0 = ldrow(t + 4); lg1 = ldrow(t + 5); lg2 = ldrow(t + 6); lg3 = ldrow(t + 7);
        CRFSTEP(e0); CRFSTEP(e1); CRFSTEP(e2); CRFSTEP(e3);
        float s = rl(a, 0);
        float rr = __builtin_amdgcn_rcpf(s);
        a *= rr; C -= __logf(rr);
    }
    for (; t < len; ++t) {
        float el = __expf(ldrow(t));
        CRFSTEP(el);
    }

    float aend = (act && a > 0.f) ? C + __logf(a) + trEnd : -1e30f;
    float mx = aend;
#pragma unroll
    for (int off = 32; off > 0; off >>= 1) mx = fmaxf(mx, __shfl_xor(mx, off, 64));
    float es = act ? __expf(aend - mx) : 0.0f;
#pragma unroll
    for (int off = 32; off > 0; off >>= 1) es += __shfl_xor(es, off, 64);
    float norm = mx + __logf(es);

    if (lane == 0) loss[b] = gold - norm;
}

// ---------------------------------------------------------------------------
extern "C" void kernel_launch(void* const* d_in, const int* in_sizes, int n_in,
                              void* d_out, int out_size, void* d_ws, size_t ws_size,
                              hipStream_t stream) {
    const float* h        = (const float*)d_in[0];
    const int* token_nums = (const int*)d_in[2];
    const int* labels     = (const int*)d_in[3];
    const float* bio      = (const float*)d_in[4];
    const float* Wcat     = (const float*)d_in[5];
    const float* bcat     = (const float*)d_in[6];
    const float* Wcrf     = (const float*)d_in[7];
    const float* bcrf     = (const float*)d_in[8];
    const float* trans    = (const float*)d_in[9];

    float* out = (float*)d_out;
    unsigned short* attn  = (unsigned short*)d_out;  // 2MB scratch, overwritten by kC

    const size_t ASW_BYTES = (size_t)128 * 48 * 16384;        // 96 MB
    const size_t X2_BYTES  = (size_t)NM * NH * 2;             // 32 MB
    const size_t WSW_BYTES = (size_t)8 * 48 * 16384;          // 6 MB
    const bool fast = ws_size >= ASW_BYTES + X2_BYTES + WSW_BYTES;

    hipLaunchKernelGGL(kA1, dim3(NM / 64), dim3(256), 0, stream, h, bio, attn);

    if (fast) {
        char* Asw           = (char*)d_ws;
        unsigned short* x2  = (unsigned short*)((char*)d_ws + ASW_BYTES);
        char* Wsw           = (char*)d_ws + ASW_BYTES + X2_BYTES;

        hipLaunchKernelGGL(kW, dim3(8 * 48), dim3(256), 0, stream, Wcat, Wsw);
        hipLaunchKernelGGL(kA2f, dim3(NH / 128, NM / 128), dim3(256), 0, stream,
                           attn, bio, h, Asw);
        hipLaunchKernelGGL(kBf, dim3(256), dim3(512), 0, stream, Asw, Wsw, bcat, x2);
        hipLaunchKernelGGL(kC, dim3(NM / 128), dim3(256), 0, stream, x2, Wcrf, bcrf, out);
    } else {
        unsigned short* aware = (unsigned short*)d_ws;
        unsigned short* x2    = aware + (size_t)NM * NH;

        hipLaunchKernelGGL(kA2, dim3(NH / 128, NM / 128), dim3(256), 0, stream, attn, bio, aware);
        hipLaunchKernelGGL(kB, dim3((NH / 128) * (NM / 128)), dim3(256), 0, stream,
                           h, aware, Wcat, bcat, x2);
        hipLaunchKernelGGL(kC, dim3(NM / 128), dim3(256), 0, stream, x2, Wcrf, bcrf, out);
    }

    hipLaunchKernelGGL(kD, dim3(NB), dim3(256), 0, stream, out, labels, token_nums, trans,
                       out + (size_t)NM * NLP);
}

// Round 10
// 273.813 us; speedup vs baseline: 13.7820x; 1.0928x over previous
//
#include <hip/hip_runtime.h>
#include <hip/hip_bf16.h>
#include <math.h>

#define NB 32
#define NS 512
#define NH 1024
#define NT 37
#define NLP 39
#define NM (NB*NS)   // 16384

typedef __attribute__((ext_vector_type(8))) short bf16x8;
typedef __attribute__((ext_vector_type(4))) float f32x4;

__device__ __forceinline__ float bf2f(unsigned int u) {
    unsigned int x = u << 16;
    float f;
    __builtin_memcpy(&f, &x, 4);
    return f;
}
__device__ __forceinline__ unsigned short f2bf(float f) {
    __hip_bfloat16 hb = __float2bfloat16(f);
    unsigned short u;
    __builtin_memcpy(&u, &hb, 2);
    return u;
}
__device__ __forceinline__ unsigned int pk2(float lo, float hi) {
    return ((unsigned int)f2bf(hi) << 16) | (unsigned int)f2bf(lo);
}
// bijective XOR swizzle for [row][64B] bf16 LDS tiles
__device__ __forceinline__ int SW64(int b)  { return b ^ ((b >> 2) & 0x70); }
// tile swizzle for [128/256 row][64 k] bf16 tiles (row stride 128B)
__device__ __forceinline__ int TSW(int row, int kcolByte) {
    return (row * 128 + kcolByte) ^ ((row & 7) << 4);
}
__device__ __forceinline__ float rl(float x, int l) {
    return __int_as_float(__builtin_amdgcn_readlane(__float_as_int(x), l));
}
__device__ __forceinline__ void gld16(const void* g, void* l) {
    __builtin_amdgcn_global_load_lds((const __attribute__((address_space(1))) void*)g,
                                     (__attribute__((address_space(3))) void*)l, 16, 0, 0);
}
#define VMW(N) asm volatile("s_waitcnt vmcnt(" #N ")" ::: "memory")
#define BARR() do { __builtin_amdgcn_s_barrier(); __builtin_amdgcn_sched_barrier(0); } while (0)

// ---------------------------------------------------------------------------
// Kernel A1: scores = h@bio^T /32 -> softmax -> attn (bf16, [NM][64], zero-pad)
// ---------------------------------------------------------------------------
__global__ __launch_bounds__(256) void kA1(const float* __restrict__ h,
                                           const float* __restrict__ bio,
                                           unsigned short* __restrict__ attn) {
    __shared__ __align__(16) char Asl[64 * 64];
    __shared__ __align__(16) char Bsl[48 * 64];

    const int tid  = threadIdx.x;
    const int lane = tid & 63;
    const int wid  = tid >> 6;
    const int lr   = lane & 15;
    const int lk   = lane >> 4;
    const int m0   = blockIdx.x * 64;

    const int arow = tid >> 2;
    const int aq   = (tid & 3) * 8;
    const int brow = tid >> 1;
    const int bkh  = (tid & 1) * 16;

    f32x4 sacc[3];
#pragma unroll
    for (int j = 0; j < 3; ++j) sacc[j] = (f32x4){0.f, 0.f, 0.f, 0.f};

    const float* hrow = h + (size_t)(m0 + arow) * NH + aq;

    for (int kt = 0; kt < NH; kt += 32) {
        float hv[8];
        {
            const float4* hp = (const float4*)(hrow + kt);
            float4 a = hp[0], b = hp[1];
            hv[0]=a.x; hv[1]=a.y; hv[2]=a.z; hv[3]=a.w;
            hv[4]=b.x; hv[5]=b.y; hv[6]=b.z; hv[7]=b.w;
        }
        float bv[16];
        if (tid < 96) {
            if (brow < NT) {
                const float4* bp = (const float4*)(bio + (size_t)brow * NH + kt + bkh);
                float4 a = bp[0], b = bp[1], c = bp[2], d = bp[3];
                bv[0]=a.x; bv[1]=a.y; bv[2]=a.z; bv[3]=a.w;
                bv[4]=b.x; bv[5]=b.y; bv[6]=b.z; bv[7]=b.w;
                bv[8]=c.x; bv[9]=c.y; bv[10]=c.z; bv[11]=c.w;
                bv[12]=d.x; bv[13]=d.y; bv[14]=d.z; bv[15]=d.w;
            } else {
#pragma unroll
                for (int i = 0; i < 16; ++i) bv[i] = 0.f;
            }
        }
        __syncthreads();
        {
            unsigned int p[4];
#pragma unroll
            for (int i = 0; i < 4; ++i) p[i] = pk2(hv[2*i], hv[2*i+1]);
            *(int4*)(Asl + SW64(arow*64 + aq*2)) = make_int4(p[0], p[1], p[2], p[3]);
        }
        if (tid < 96) {
            unsigned int p[8];
#pragma unroll
            for (int i = 0; i < 8; ++i) p[i] = pk2(bv[2*i], bv[2*i+1]);
            *(int4*)(Bsl + SW64(brow*64 + bkh*2))      = make_int4(p[0], p[1], p[2], p[3]);
            *(int4*)(Bsl + SW64(brow*64 + bkh*2 + 16)) = make_int4(p[4], p[5], p[6], p[7]);
        }
        __syncthreads();
        bf16x8 af = *(const bf16x8*)(Asl + SW64((wid*16 + lr)*64 + lk*16));
#pragma unroll
        for (int nf = 0; nf < 3; ++nf) {
            bf16x8 bfr = *(const bf16x8*)(Bsl + SW64((nf*16 + lr)*64 + lk*16));
            sacc[nf] = __builtin_amdgcn_mfma_f32_16x16x32_bf16(af, bfr, sacc[nf], 0, 0, 0);
        }
    }

#pragma unroll
    for (int r = 0; r < 4; ++r) {
        const int row = wid*16 + lk*4 + r;
        float s0 = sacc[0][r] * 0.03125f;
        float s1 = sacc[1][r] * 0.03125f;
        float s2 = sacc[2][r] * 0.03125f;
        const bool v2 = (lr < 5);
        float mx = fmaxf(fmaxf(s0, s1), v2 ? s2 : -1e30f);
#pragma unroll
        for (int d = 1; d < 16; d <<= 1) mx = fmaxf(mx, __shfl_xor(mx, d, 64));
        float e0 = __expf(s0 - mx), e1 = __expf(s1 - mx);
        float e2 = v2 ? __expf(s2 - mx) : 0.f;
        float sm = e0 + e1 + e2;
#pragma unroll
        for (int d = 1; d < 16; d <<= 1) sm += __shfl_xor(sm, d, 64);
        float inv = 1.f / sm;
        size_t g = (size_t)(m0 + row) * 64;
        attn[g + lr]      = f2bf(e0 * inv);
        attn[g + 16 + lr] = f2bf(e1 * inv);
        attn[g + 32 + lr] = f2bf(e2 * inv);
        attn[g + 48 + lr] = 0;
    }
}

// ---------------------------------------------------------------------------
// Kernel A2 (fallback): aware = attn @ bio, plain bf16 row-major out.
// ---------------------------------------------------------------------------
__global__ __launch_bounds__(256) void kA2(const unsigned short* __restrict__ attn,
                                           const float* __restrict__ bio,
                                           unsigned short* __restrict__ aware) {
    __shared__ __align__(16) char Bsl[128 * 64];

    const int tid  = threadIdx.x;
    const int lane = tid & 63;
    const int wid  = tid >> 6;
    const int wm   = (wid >> 1) * 64;
    const int wn   = (wid & 1) * 64;
    const int lr   = lane & 15;
    const int lk   = lane >> 4;
    const int n0   = blockIdx.x * 128;
    const int m0   = blockIdx.y * 128;

    const int bn = tid & 127;
    const int bq = (tid >> 7) * 16;

    f32x4 acc[4][4];
#pragma unroll
    for (int i = 0; i < 4; ++i)
#pragma unroll
        for (int j = 0; j < 4; ++j) acc[i][j] = (f32x4){0.f, 0.f, 0.f, 0.f};

#pragma unroll
    for (int ks = 0; ks < 2; ++ks) {
        unsigned int p[8];
#pragma unroll
        for (int i = 0; i < 8; ++i) {
            int t0 = ks*32 + bq + 2*i;
            float lo = (t0     < NT) ? bio[(size_t)t0 * NH + n0 + bn]       : 0.f;
            float hi = (t0 + 1 < NT) ? bio[(size_t)(t0+1) * NH + n0 + bn]   : 0.f;
            p[i] = pk2(lo, hi);
        }
        __syncthreads();
        *(int4*)(Bsl + SW64(bn*64 + bq*2))      = make_int4(p[0], p[1], p[2], p[3]);
        *(int4*)(Bsl + SW64(bn*64 + bq*2 + 16)) = make_int4(p[4], p[5], p[6], p[7]);
        __syncthreads();

        bf16x8 af[4];
#pragma unroll
        for (int mf = 0; mf < 4; ++mf)
            af[mf] = *(const bf16x8*)(attn + (size_t)(m0 + wm + mf*16 + lr) * 64 + ks*32 + lk*8);
#pragma unroll
        for (int nf = 0; nf < 4; ++nf) {
            bf16x8 bb = *(const bf16x8*)(Bsl + SW64((wn + nf*16 + lr)*64 + lk*16));
#pragma unroll
            for (int mf = 0; mf < 4; ++mf)
                acc[mf][nf] = __builtin_amdgcn_mfma_f32_16x16x32_bf16(af[mf], bb, acc[mf][nf], 0, 0, 0);
        }
    }

#pragma unroll
    for (int mf = 0; mf < 4; ++mf)
#pragma unroll
        for (int nf = 0; nf < 4; ++nf)
#pragma unroll
            for (int r = 0; r < 4; ++r) {
                size_t row = (size_t)(m0 + wm + mf*16 + lk*4 + r);
                aware[row * NH + n0 + wn + nf*16 + lr] = f2bf(acc[mf][nf][r]);
            }
}

// ---------------------------------------------------------------------------
// Kernel A2f (fast): computes aware chunk AND writes the full concat-A
// [h | aware | h*aware] in bf16, tile-major (128x64 tiles) with TSW swizzle.
// ---------------------------------------------------------------------------
__global__ __launch_bounds__(256) void kA2f(const unsigned short* __restrict__ attn,
                                            const float* __restrict__ bio,
                                            const float* __restrict__ h,
                                            char* __restrict__ Asw) {
    __shared__ __align__(16) char Bsl[128 * 64];
    __shared__ __align__(16) unsigned short awL[128 * 128];  // 32KB aware chunk

    const int tid  = threadIdx.x;
    const int lane = tid & 63;
    const int wid  = tid >> 6;
    const int wm   = (wid >> 1) * 64;
    const int wn   = (wid & 1) * 64;
    const int lr   = lane & 15;
    const int lk   = lane >> 4;
    const int n0   = blockIdx.x * 128;
    const int m0   = blockIdx.y * 128;
    const int tm   = blockIdx.y;

    const int bn = tid & 127;
    const int bq = (tid >> 7) * 16;

    f32x4 acc[4][4];
#pragma unroll
    for (int i = 0; i < 4; ++i)
#pragma unroll
        for (int j = 0; j < 4; ++j) acc[i][j] = (f32x4){0.f, 0.f, 0.f, 0.f};

#pragma unroll
    for (int ks = 0; ks < 2; ++ks) {
        unsigned int p[8];
#pragma unroll
        for (int i = 0; i < 8; ++i) {
            int t0 = ks*32 + bq + 2*i;
            float lo = (t0     < NT) ? bio[(size_t)t0 * NH + n0 + bn]       : 0.f;
            float hi = (t0 + 1 < NT) ? bio[(size_t)(t0+1) * NH + n0 + bn]   : 0.f;
            p[i] = pk2(lo, hi);
        }
        __syncthreads();
        *(int4*)(Bsl + SW64(bn*64 + bq*2))      = make_int4(p[0], p[1], p[2], p[3]);
        *(int4*)(Bsl + SW64(bn*64 + bq*2 + 16)) = make_int4(p[4], p[5], p[6], p[7]);
        __syncthreads();

        bf16x8 af[4];
#pragma unroll
        for (int mf = 0; mf < 4; ++mf)
            af[mf] = *(const bf16x8*)(attn + (size_t)(m0 + wm + mf*16 + lr) * 64 + ks*32 + lk*8);
#pragma unroll
        for (int nf = 0; nf < 4; ++nf) {
            bf16x8 bb = *(const bf16x8*)(Bsl + SW64((wn + nf*16 + lr)*64 + lk*16));
#pragma unroll
            for (int mf = 0; mf < 4; ++mf)
                acc[mf][nf] = __builtin_amdgcn_mfma_f32_16x16x32_bf16(af[mf], bb, acc[mf][nf], 0, 0, 0);
        }
    }

#pragma unroll
    for (int mf = 0; mf < 4; ++mf)
#pragma unroll
        for (int nf = 0; nf < 4; ++nf)
#pragma unroll
            for (int r = 0; r < 4; ++r)
                awL[(wm + mf*16 + lk*4 + r) * 128 + wn + nf*16 + lr] = f2bf(acc[mf][nf][r]);
    __syncthreads();

    // region 1 (aware)
#pragma unroll
    for (int i = 0; i < 8; ++i) {
        int lin = tid + i * 256;
        int row = lin >> 4, kg = lin & 15;
        uint4 v = *(const uint4*)&awL[row * 128 + kg * 8];
        int kglob = 1024 + n0 + kg * 8;
        size_t tbase = ((size_t)tm * 48 + (kglob >> 6)) * 16384;
        *(uint4*)(Asw + tbase + TSW(row, (kglob & 63) * 2)) = v;
    }
    // regions 0 (h) and 2 (h*aware)
#pragma unroll
    for (int i = 0; i < 8; ++i) {
        int lin = tid + i * 256;
        int row = lin >> 4, kg = lin & 15;
        const float4* hp = (const float4*)&h[(size_t)(m0 + row) * NH + n0 + kg * 8];
        float4 ha = hp[0], hb = hp[1];
        float hv[8] = {ha.x, ha.y, ha.z, ha.w, hb.x, hb.y, hb.z, hb.w};
        uint4 awv = *(const uint4*)&awL[row * 128 + kg * 8];
        unsigned int awu[4] = {awv.x, awv.y, awv.z, awv.w};
        unsigned int p0[4], p2[4];
#pragma unroll
        for (int j = 0; j < 4; ++j) {
            p0[j] = pk2(hv[2*j], hv[2*j+1]);
            float lo = hv[2*j]   * bf2f(awu[j] & 0xffffu);
            float hi = hv[2*j+1] * bf2f(awu[j] >> 16);
            p2[j] = pk2(lo, hi);
        }
        int k0g = n0 + kg * 8;
        size_t tb0 = ((size_t)tm * 48 + (k0g >> 6)) * 16384;
        *(uint4*)(Asw + tb0 + TSW(row, (k0g & 63) * 2)) = make_uint4(p0[0], p0[1], p0[2], p0[3]);
        int k2g = 2048 + n0 + kg * 8;
        size_t tb2 = ((size_t)tm * 48 + (k2g >> 6)) * 16384;
        *(uint4*)(Asw + tb2 + TSW(row, (k2g & 63) * 2)) = make_uint4(p2[0], p2[1], p2[2], p2[3]);
    }
}

// ---------------------------------------------------------------------------
// Kernel W: WbT swizzled tiles: W^T[n][k] bf16, tile (tn,tk) = [128 n][64 k].
// ---------------------------------------------------------------------------
__global__ __launch_bounds__(256) void kW(const float* __restrict__ Wcat,
                                          char* __restrict__ Wsw) {
    __shared__ unsigned short wt[64 * 128];

    const int tid  = threadIdx.x;
    const int tile = blockIdx.x;
    const int tn   = tile / 48;
    const int tk   = tile - tn * 48;
    const int n00  = tn * 128;
    const int k0   = tk * 64;

#pragma unroll
    for (int i = 0; i < 8; ++i) {
        int lin = tid + i * 256;
        int kk = lin >> 5, ng = lin & 31;
        float4 v = *(const float4*)&Wcat[(size_t)(k0 + kk) * NH + n00 + ng * 4];
        unsigned int lo = pk2(v.x, v.y), hi = pk2(v.z, v.w);
        *(uint2*)&wt[kk * 128 + ng * 4] = make_uint2(lo, hi);
    }
    __syncthreads();
#pragma unroll
    for (int i = 0; i < 4; ++i) {
        int lin = tid + i * 256;
        int rn = lin >> 3, kg = lin & 7;
        unsigned short t8[8];
#pragma unroll
        for (int j = 0; j < 8; ++j) t8[j] = wt[(kg * 8 + j) * 128 + rn];
        uint4 v = *(const uint4*)t8;
        *(uint4*)(Wsw + (size_t)tile * 16384 + TSW(rn, kg * 16)) = v;
    }
}

// ---------------------------------------------------------------------------
// Kernel Bf (fast): 256x256 tile bf16 GEMM, BK=64, 8 waves, counted-vmcnt
// 4-phase schedule (proven 101us) + FUSED kC epilogue: gelu'd x2 tile goes to
// LDS (same TSW format), each wave MFMAs it against Wcrf^T and writes a
// split-K partial P[Nt] (no x2 HBM round trip, no separate kC GEMM).
// ---------------------------------------------------------------------------
__global__ __launch_bounds__(512, 2) void kBf(const char* __restrict__ Asw,
                                              const char* __restrict__ Wsw,
                                              const float* __restrict__ bcat,
                                              const float* __restrict__ Wcrf,
                                              float* __restrict__ P) {
    __shared__ __align__(16) char lds[131072];  // A: buf*32768+h*16384; B at +65536

    const int tid  = threadIdx.x;
    const int lane = tid & 63;
    const int wid  = tid >> 6;
    const int widm = wid >> 2;       // 0..1
    const int widn = wid & 3;        // 0..3
    const int lr   = lane & 15;
    const int lk   = lane >> 4;

    const int id   = blockIdx.x;     // 256 blocks
    const int xcd  = id & 7;
    const int slot = id >> 3;        // 0..31
    const int Mt   = xcd * 8 + (slot >> 2);   // 256-row tile
    const int Nt   = slot & 3;                // 256-col tile
    const int m0   = Mt * 256, n0 = Nt * 256;
    const int soff = tid * 16;

    f32x4 acc00[4][2], acc01[4][2], acc10[4][2], acc11[4][2];
#pragma unroll
    for (int i = 0; i < 4; ++i)
#pragma unroll
        for (int j = 0; j < 2; ++j) {
            acc00[i][j] = (f32x4){0.f,0.f,0.f,0.f};
            acc01[i][j] = (f32x4){0.f,0.f,0.f,0.f};
            acc10[i][j] = (f32x4){0.f,0.f,0.f,0.f};
            acc11[i][j] = (f32x4){0.f,0.f,0.f,0.f};
        }

    // stage half 'ph' of tile T into buf T&1. ph: 0=A-h0, 1=B-h0, 2=B-h1, 3=A-h1
    auto stageHalf = [&](int T, int ph) {
        const bool isA = (ph == 0) || (ph == 3);
        const int  h   = isA ? (ph == 3 ? 1 : 0) : (ph - 1);
        const char* src = isA
            ? Asw + ((size_t)((2*Mt + h) * 48 + T)) * 16384
            : Wsw + ((size_t)((2*Nt + h) * 48 + T)) * 16384;
        char* dst = lds + (isA ? 0 : 65536) + (T & 1) * 32768 + h * 16384;
        gld16(src + soff,        dst + soff);
        gld16(src + soff + 8192, dst + soff + 8192);
    };
    auto loadA = [&](bf16x8 (&af)[4][2], int q, int half) {
        const char* base = lds + q * 32768 + half * 16384;
#pragma unroll
        for (int i = 0; i < 4; ++i) {
            int row = widm * 64 + i * 16 + lr;
#pragma unroll
            for (int kk = 0; kk < 2; ++kk)
                af[i][kk] = *(const bf16x8*)(base + TSW(row, kk * 64 + lk * 16));
        }
    };
    auto loadB = [&](bf16x8 (&bfr)[2][2], int q, int half) {
        const char* base = lds + 65536 + q * 32768 + half * 16384;
#pragma unroll
        for (int j = 0; j < 2; ++j) {
            int col = widn * 32 + j * 16 + lr;
#pragma unroll
            for (int kk = 0; kk < 2; ++kk)
                bfr[j][kk] = *(const bf16x8*)(base + TSW(col, kk * 64 + lk * 16));
        }
    };
    auto mma = [&](f32x4 (&ac)[4][2], bf16x8 (&af)[4][2], bf16x8 (&bfr)[2][2]) {
        __builtin_amdgcn_s_setprio(1);
#pragma unroll
        for (int kk = 0; kk < 2; ++kk)
#pragma unroll
            for (int i = 0; i < 4; ++i)
#pragma unroll
                for (int j = 0; j < 2; ++j)
                    ac[i][j] = __builtin_amdgcn_mfma_f32_16x16x32_bf16(
                        af[i][kk], bfr[j][kk], ac[i][j], 0, 0, 0);
        __builtin_amdgcn_s_setprio(0);
    };

    // prologue: stage tile 0 fully, drain once
    stageHalf(0, 0); stageHalf(0, 1); stageHalf(0, 2); stageHalf(0, 3);
    VMW(0);
    BARR();

    for (int T = 0; T < 47; ++T) {
        const int q = T & 1;
        bf16x8 af0[4][2], af1[4][2], bf0[2][2], bf1[2][2];
        stageHalf(T + 1, 0);
        VMW(6);
        BARR();
        loadA(af0, q, 0); loadB(bf0, q, 0);
        mma(acc00, af0, bf0);
        stageHalf(T + 1, 1);
        VMW(6);
        BARR();
        loadB(bf1, q, 1);
        mma(acc01, af0, bf1);
        stageHalf(T + 1, 2);
        VMW(6);
        BARR();
        loadA(af1, q, 1);
        mma(acc10, af1, bf0);
        stageHalf(T + 1, 3);
        BARR();
        mma(acc11, af1, bf1);
    }
    {   // T = 47 (buf 1), tail waits 4/2/0
        const int q = 1;
        bf16x8 af0[4][2], af1[4][2], bf0[2][2], bf1[2][2];
        VMW(4);
        BARR();
        loadA(af0, q, 0); loadB(bf0, q, 0);
        mma(acc00, af0, bf0);
        VMW(2);
        BARR();
        loadB(bf1, q, 1);
        mma(acc01, af0, bf1);
        VMW(0);
        BARR();
        loadA(af1, q, 1);
        mma(acc10, af1, bf0);
        BARR();
        mma(acc11, af1, bf1);
    }

    // ---------------- fused kC epilogue ----------------
    // 1) gelu(acc + bcat) -> bf16 into LDS as 4 chunks [256 rows][64 k] TSW
    //    (chunk kc at lds + kc*32768). All main-loop ds_reads are register-
    //    consumed before the last barrier, so overwriting LDS is safe after
    //    a full __syncthreads().
    __syncthreads();
    auto stashQ = [&](f32x4 (&ac)[4][2], int a, int b) {
#pragma unroll
        for (int j = 0; j < 2; ++j) {
            const int lcol = b * 128 + widn * 32 + j * 16 + lr;
            const int kc = lcol >> 6, kk = lcol & 63;
            const float bc = bcat[n0 + lcol];
#pragma unroll
            for (int i = 0; i < 4; ++i)
#pragma unroll
                for (int r = 0; r < 4; ++r) {
                    int lrow = a * 128 + widm * 64 + i * 16 + lk * 4 + r;
                    float x = ac[i][j][r] + bc;
                    float g = 0.5f * x * (1.0f + erff(x * 0.70710678118654752f));
                    *(unsigned short*)(lds + kc * 32768 + TSW(lrow, kk * 2)) = f2bf(g);
                }
        }
    };
    stashQ(acc00, 0, 0); stashQ(acc01, 0, 1); stashQ(acc10, 1, 0); stashQ(acc11, 1, 1);
    __syncthreads();

    // 2) Wcrf^T fragments (registers, from L2-hot global), t>=37 zero-padded
    union U8 { unsigned int u[4]; bf16x8 v; };
    bf16x8 wfrag[3][8];
#pragma unroll
    for (int tt = 0; tt < 3; ++tt) {
        const int t = tt * 16 + lr;
        const bool vt = (t < NT);
#pragma unroll
        for (int ks = 0; ks < 8; ++ks) {
            U8 cv;
#pragma unroll
            for (int e = 0; e < 4; ++e) {
                int k0 = n0 + ks * 32 + lk * 8 + 2 * e;
                float lo = vt ? Wcrf[(size_t)k0 * NT + t] : 0.f;
                float hi = vt ? Wcrf[(size_t)(k0 + 1) * NT + t] : 0.f;
                cv.u[e] = pk2(lo, hi);
            }
            wfrag[tt][ks] = cv.v;
        }
    }

    // 3) per-wave: rows [wid*32, wid*32+32) x 48 t-cols, K=256 from LDS
    f32x4 pacc[2][3];
#pragma unroll
    for (int i = 0; i < 2; ++i)
#pragma unroll
        for (int j = 0; j < 3; ++j) pacc[i][j] = (f32x4){0.f, 0.f, 0.f, 0.f};
#pragma unroll
    for (int rt2 = 0; rt2 < 2; ++rt2) {
        const int lrow = wid * 32 + rt2 * 16 + lr;
#pragma unroll
        for (int ks = 0; ks < 8; ++ks) {
            const int kc = ks >> 1, kh = ks & 1;
            bf16x8 af = *(const bf16x8*)(lds + kc * 32768 + TSW(lrow, kh * 64 + lk * 16));
#pragma unroll
            for (int tt = 0; tt < 3; ++tt)
                pacc[rt2][tt] = __builtin_amdgcn_mfma_f32_16x16x32_bf16(
                    af, wfrag[tt][ks], pacc[rt2][tt], 0, 0, 0);
        }
    }

    // 4) write split-K partial P[Nt][Mt*256 + row][48]
    float* Pb = P + (size_t)Nt * NM * 48;
#pragma unroll
    for (int rt2 = 0; rt2 < 2; ++rt2)
#pragma unroll
        for (int tt = 0; tt < 3; ++tt)
#pragma unroll
            for (int r = 0; r < 4; ++r) {
                int row = Mt * 256 + wid * 32 + rt2 * 16 + lk * 4 + r;
                Pb[(size_t)row * 48 + tt * 16 + lr] = pacc[rt2][tt][r];
            }
}

// ---------------------------------------------------------------------------
// Kernel Cr: out = sum_Nt P[Nt] + b_crf, pads -10000.
// ---------------------------------------------------------------------------
__global__ __launch_bounds__(256) void kCr(const float* __restrict__ P,
                                           const float* __restrict__ bcrf,
                                           float* __restrict__ out) {
    const int g = blockIdx.x * 256 + threadIdx.x;   // 65536 threads
    const size_t STRIDE = (size_t)NM * 48;
#pragma unroll
    for (int s = 0; s < 12; ++s) {
        int flat = g * 12 + s;                      // 0 .. 786431
        int row = flat / 48, t = flat - row * 48;
        float v = P[flat] + P[STRIDE + flat] + P[2*STRIDE + flat] + P[3*STRIDE + flat];
        if (t < NT)       out[(size_t)row * NLP + t] = v + bcrf[t];
        else if (t < NLP) out[(size_t)row * NLP + t] = -10000.0f;
    }
}

// ---------------------------------------------------------------------------
// Kernel B (fallback): reg-staged mixed GEMM (round-4 version).
// ---------------------------------------------------------------------------
__global__ __launch_bounds__(256) void kB(const float* __restrict__ h,
                                          const unsigned short* __restrict__ aware,
                                          const float* __restrict__ Wcat,
                                          const float* __restrict__ bcat,
                                          unsigned short* __restrict__ x2) {
    __shared__ __align__(16) char lds[16384];
    char* Asl = lds;
    char* Bsl = lds + 8192;

    const int tid  = threadIdx.x;
    const int lane = tid & 63;
    const int wid  = tid >> 6;
    const int wm   = (wid >> 1) * 64;
    const int wn   = (wid & 1) * 64;
    const int lr   = lane & 15;
    const int lk   = lane >> 4;

    const int id   = blockIdx.x;
    const int xcd  = id & 7;
    const int slot = id >> 3;
    const int m0   = (xcd * 16 + (slot >> 3)) * 128;
    const int n0   = (slot & 7) * 128;

    const int am = tid >> 1;
    const int ak = (tid & 1) * 16;
    const int bn = tid & 127;
    const int bk = (tid >> 7) * 16;

    f32x4 acc[4][4];
#pragma unroll
    for (int i = 0; i < 4; ++i)
#pragma unroll
        for (int j = 0; j < 4; ++j) acc[i][j] = (f32x4){0.f, 0.f, 0.f, 0.f};

    const float*          hrow = h     + (size_t)(m0 + am) * NH + ak;
    const unsigned short* arow = aware + (size_t)(m0 + am) * NH + ak;
    const float*          wcol = Wcat  + (size_t)bk * NH + n0 + bn;

    float hv[16];
    unsigned int aw[8];
    float wv[16];

    auto stage = [&](int kt) {
        const int region = kt >> 10;
        const int kb = kt & 1023;
        if (region != 1) {
            const float4* hp = (const float4*)(hrow + kb);
            float4 a = hp[0], b = hp[1], c = hp[2], d = hp[3];
            hv[0]=a.x; hv[1]=a.y; hv[2]=a.z; hv[3]=a.w;
            hv[4]=b.x; hv[5]=b.y; hv[6]=b.z; hv[7]=b.w;
            hv[8]=c.x; hv[9]=c.y; hv[10]=c.z; hv[11]=c.w;
            hv[12]=d.x; hv[13]=d.y; hv[14]=d.z; hv[15]=d.w;
        }
        if (region >= 1) {
            const uint4* ap = (const uint4*)(arow + kb);
            uint4 a0 = ap[0], a1 = ap[1];
            aw[0]=a0.x; aw[1]=a0.y; aw[2]=a0.z; aw[3]=a0.w;
            aw[4]=a1.x; aw[5]=a1.y; aw[6]=a1.z; aw[7]=a1.w;
        }
        {
            const float* wp = wcol + (size_t)kt * NH;
#pragma unroll
            for (int j = 0; j < 16; ++j) wv[j] = wp[(size_t)j * NH];
        }
    };

    auto writeStage = [&](int kt) {
        const int region = kt >> 10;
        unsigned int p[8];
        if (region == 0) {
#pragma unroll
            for (int i = 0; i < 8; ++i) p[i] = pk2(hv[2*i], hv[2*i+1]);
        } else if (region == 1) {
#pragma unroll
            for (int i = 0; i < 8; ++i) p[i] = aw[i];
        } else {
#pragma unroll
            for (int i = 0; i < 8; ++i) {
                float lo = hv[2*i]   * bf2f(aw[i] & 0xffffu);
                float hi = hv[2*i+1] * bf2f(aw[i] >> 16);
                p[i] = pk2(lo, hi);
            }
        }
        *(int4*)(Asl + SW64(am*64 + ak*2))      = make_int4(p[0], p[1], p[2], p[3]);
        *(int4*)(Asl + SW64(am*64 + ak*2 + 16)) = make_int4(p[4], p[5], p[6], p[7]);
        unsigned int q[8];
#pragma unroll
        for (int i = 0; i < 8; ++i) q[i] = pk2(wv[2*i], wv[2*i+1]);
        *(int4*)(Bsl + SW64(bn*64 + bk*2))      = make_int4(q[0], q[1], q[2], q[3]);
        *(int4*)(Bsl + SW64(bn*64 + bk*2 + 16)) = make_int4(q[4], q[5], q[6], q[7]);
    };

    stage(0);
    for (int kt = 0; kt < 3072; kt += 32) {
        __syncthreads();
        writeStage(kt);
        __syncthreads();
        if (kt + 32 < 3072) stage(kt + 32);

        bf16x8 af[4], bfr[4];
#pragma unroll
        for (int mf = 0; mf < 4; ++mf)
            af[mf] = *(const bf16x8*)(Asl + SW64((wm + mf*16 + lr)*64 + lk*16));
#pragma unroll
        for (int nf = 0; nf < 4; ++nf)
            bfr[nf] = *(const bf16x8*)(Bsl + SW64((wn + nf*16 + lr)*64 + lk*16));
#pragma unroll
        for (int mf = 0; mf < 4; ++mf)
#pragma unroll
            for (int nf = 0; nf < 4; ++nf)
                acc[mf][nf] = __builtin_amdgcn_mfma_f32_16x16x32_bf16(af[mf], bfr[nf], acc[mf][nf], 0, 0, 0);
    }

#pragma unroll
    for (int nf = 0; nf < 4; ++nf) {
        const int col = n0 + wn + nf*16 + lr;
        const float bc = bcat[col];
#pragma unroll
        for (int mf = 0; mf < 4; ++mf)
#pragma unroll
            for (int r = 0; r < 4; ++r) {
                size_t row = (size_t)(m0 + wm + mf*16 + lk*4 + r);
                float x = acc[mf][nf][r] + bc;
                float g = 0.5f * x * (1.0f + erff(x * 0.70710678118654752f));
                x2[row * NH + col] = f2bf(g);
            }
    }
}

// ---------------------------------------------------------------------------
// Kernel C (fallback): ner_scores = [x2 @ W_crf + b_crf, -10000, -10000]
// ---------------------------------------------------------------------------
__global__ __launch_bounds__(256) void kC(const unsigned short* __restrict__ x2,
                                          const float* __restrict__ Wcrf,
                                          const float* __restrict__ bcrf,
                                          float* __restrict__ out) {
    __shared__ __align__(16) char Asl[8192];
    __shared__ __align__(16) char Bsl[3072];

    const int tid  = threadIdx.x;
    const int lane = tid & 63;
    const int wid  = tid >> 6;
    const int lr   = lane & 15;
    const int lk   = lane >> 4;
    const int m0   = blockIdx.x * 128;
    const int am   = tid >> 1;
    const int ak   = (tid & 1) * 16;

    for (int i = tid; i < 192; i += 256) *(int4*)(Bsl + i*16) = make_int4(0, 0, 0, 0);

    f32x4 acc[2][3];
#pragma unroll
    for (int i = 0; i < 2; ++i)
#pragma unroll
        for (int j = 0; j < 3; ++j) acc[i][j] = (f32x4){0.f, 0.f, 0.f, 0.f};

    const unsigned short* xrow = x2 + (size_t)(m0 + am) * NH + ak;

    for (int kt = 0; kt < NH; kt += 32) {
        const uint4* xp = (const uint4*)(xrow + kt);
        uint4 x0 = xp[0], x1 = xp[1];
        float wv[5];
#pragma unroll
        for (int p = 0; p < 5; ++p) {
            int i = tid + p * 256;
            wv[p] = (i < 32*NT) ? Wcrf[(size_t)kt * NT + i] : 0.f;
        }
        __syncthreads();
        *(uint4*)(Asl + SW64(am*64 + ak*2))      = x0;
        *(uint4*)(Asl + SW64(am*64 + ak*2 + 16)) = x1;
#pragma unroll
        for (int p = 0; p < 5; ++p) {
            int i = tid + p * 256;
            if (i < 32*NT) {
                int kk = i / NT;
                int t  = i - kk * NT;
                *(unsigned short*)(Bsl + SW64(t*64 + kk*2)) = f2bf(wv[p]);
            }
        }
        __syncthreads();
        bf16x8 af[2], bfr[3];
#pragma unroll
        for (int mf = 0; mf < 2; ++mf)
            af[mf] = *(const bf16x8*)(Asl + SW64((wid*32 + mf*16 + lr)*64 + lk*16));
#pragma unroll
        for (int nf = 0; nf < 3; ++nf)
            bfr[nf] = *(const bf16x8*)(Bsl + SW64((nf*16 + lr)*64 + lk*16));
#pragma unroll
        for (int mf = 0; mf < 2; ++mf)
#pragma unroll
            for (int nf = 0; nf < 3; ++nf)
                acc[mf][nf] = __builtin_amdgcn_mfma_f32_16x16x32_bf16(af[mf], bfr[nf], acc[mf][nf], 0, 0, 0);
    }

#pragma unroll
    for (int nf = 0; nf < 3; ++nf) {
        const int t = nf*16 + lr;
        const float bc = (t < NT) ? bcrf[t] : 0.f;
#pragma unroll
        for (int mf = 0; mf < 2; ++mf)
#pragma unroll
            for (int r = 0; r < 4; ++r) {
                size_t row = (size_t)(m0 + wid*32 + mf*16 + lk*4 + r);
                if (t < NT)       out[row * NLP + t] = acc[mf][nf][r] + bc;
                else if (t < NLP) out[row * NLP + t] = -10000.0f;
            }
    }
}

// ---------------------------------------------------------------------------
// Kernel D: CRF log-likelihood, exp-domain scan, scores staged in LDS.
// ---------------------------------------------------------------------------
#define CRFSTEP(EL) do {                                   \
    float c0 = 0.f, c1 = 0.f, c2 = 0.f, c3 = 0.f;          \
    _Pragma("unroll")                                      \
    for (int f_ = 0; f_ < 36; f_ += 4) {                   \
        c0 = fmaf(rl(a, f_    ), trow[f_    ], c0);        \
        c1 = fmaf(rl(a, f_ + 1), trow[f_ + 1], c1);        \
        c2 = fmaf(rl(a, f_ + 2), trow[f_ + 2], c2);        \
        c3 = fmaf(rl(a, f_ + 3), trow[f_ + 3], c3);        \
    }                                                      \
    c0 = fmaf(rl(a, 36), trow[36], c0);                    \
    a = (EL) * ((c0 + c1) + (c2 + c3));                    \
} while (0)

__global__ __launch_bounds__(256) void kD(const float* __restrict__ scores,
                                          const int* __restrict__ labels,
                                          const int* __restrict__ lens,
                                          const float* __restrict__ trans,
                                          float* __restrict__ loss) {
    __shared__ float S[NS * NLP];      // 79872 B, packed [t][39]
    __shared__ float trL[39 * 41];     // 6396 B
    __shared__ int   labL[NS];         // 2048 B
    __shared__ float gred[4];

    const int b    = blockIdx.x;
    const int tid  = threadIdx.x;
    const int lane = tid & 63;
    const int wid  = tid >> 6;
    const int len  = lens[b];
    const float* sb = scores + (size_t)b * NS * NLP;

    {
        const float4* src = (const float4*)sb;
        float4* dst = (float4*)S;
        for (int i = tid; i < NS * NLP / 4; i += 256) dst[i] = src[i];
    }
    for (int i = tid; i < NS; i += 256) labL[i] = labels[b * NS + i];
    for (int idx = tid; idx < 39 * 39; idx += 256) {
        int to = idx / 39, f = idx - to * 39;
        trL[to * 41 + f] = trans[idx];
    }
    __syncthreads();

    float g = 0.0f;
    for (int t = tid; t < len; t += 256) g += S[t * NLP + labL[t]];
    for (int i = tid; i <= len; i += 256) {
        int frm = (i == 0) ? 37 : labL[i - 1];
        int to  = (i == len) ? 38 : labL[i];
        g += trL[to * 41 + frm];
    }
#pragma unroll
    for (int off = 32; off > 0; off >>= 1) g += __shfl_xor(g, off, 64);
    if (lane == 0) gred[wid] = g;
    __syncthreads();

    if (wid != 0) return;

    const float gold = (gred[0] + gred[1]) + (gred[2] + gred[3]);

    const int myrow = (lane < 39) ? lane : 0;
    float trow[39];
#pragma unroll
    for (int f = 0; f < 39; ++f) trow[f] = __expf(trL[myrow * 41 + f]);
    const float trEnd = (lane < 39) ? trL[38 * 41 + lane] : 0.f;
    const bool act = (lane < 39);

    float l0 = act ? S[lane] : -10000.f;
    float a = act ? __expf(l0) * trow[37] : 0.f;
    float C = 0.0f;

    auto ldrow = [&](int r) {
        r = (r < len) ? r : (len - 1);
        return S[act ? (r * NLP + lane) : 0];
    };
    float lg0 = ldrow(1), lg1 = ldrow(2), lg2 = ldrow(3), lg3 = ldrow(4);

    int t = 1;
    for (; t + 3 < len; t += 4) {
        float e0 = __expf(lg0), e1 = __expf(lg1), e2 = __expf(lg2), e3 = __expf(lg3);
        lg0 = ldrow(t + 4); lg1 = ldrow(t + 5); lg2 = ldrow(t + 6); lg3 = ldrow(t + 7);
        CRFSTEP(e0); CRFSTEP(e1); CRFSTEP(e2); CRFSTEP(e3);
        float s = rl(a, 0);
        float rr = __builtin_amdgcn_rcpf(s);
        a *= rr; C -= __logf(rr);
    }
    for (; t < len; ++t) {
        float el = __expf(ldrow(t));
        CRFSTEP(el);
    }

    float aend = (act && a > 0.f) ? C + __logf(a) + trEnd : -1e30f;
    float mx = aend;
#pragma unroll
    for (int off = 32; off > 0; off >>= 1) mx = fmaxf(mx, __shfl_xor(mx, off, 64));
    float es = act ? __expf(aend - mx) : 0.0f;
#pragma unroll
    for (int off = 32; off > 0; off >>= 1) es += __shfl_xor(es, off, 64);
    float norm = mx + __logf(es);

    if (lane == 0) loss[b] = gold - norm;
}

// ---------------------------------------------------------------------------
extern "C" void kernel_launch(void* const* d_in, const int* in_sizes, int n_in,
                              void* d_out, int out_size, void* d_ws, size_t ws_size,
                              hipStream_t stream) {
    const float* h        = (const float*)d_in[0];
    const int* token_nums = (const int*)d_in[2];
    const int* labels     = (const int*)d_in[3];
    const float* bio      = (const float*)d_in[4];
    const float* Wcat     = (const float*)d_in[5];
    const float* bcat     = (const float*)d_in[6];
    const float* Wcrf     = (const float*)d_in[7];
    const float* bcrf     = (const float*)d_in[8];
    const float* trans    = (const float*)d_in[9];

    float* out = (float*)d_out;
    unsigned short* attn  = (unsigned short*)d_out;  // 2MB scratch, overwritten by kCr

    const size_t ASW_BYTES = (size_t)128 * 48 * 16384;        // 96 MB
    const size_t P_BYTES   = (size_t)4 * NM * 48 * 4;         // 12.6 MB
    const size_t WSW_BYTES = (size_t)8 * 48 * 16384;          // 6 MB
    const bool fast = ws_size >= ASW_BYTES + P_BYTES + WSW_BYTES;

    hipLaunchKernelGGL(kA1, dim3(NM / 64), dim3(256), 0, stream, h, bio, attn);

    if (fast) {
        char*  Asw = (char*)d_ws;
        float* P   = (float*)((char*)d_ws + ASW_BYTES);
        char*  Wsw = (char*)d_ws + ASW_BYTES + P_BYTES;

        hipLaunchKernelGGL(kW, dim3(8 * 48), dim3(256), 0, stream, Wcat, Wsw);
        hipLaunchKernelGGL(kA2f, dim3(NH / 128, NM / 128), dim3(256), 0, stream,
                           attn, bio, h, Asw);
        hipLaunchKernelGGL(kBf, dim3(256), dim3(512), 0, stream, Asw, Wsw, bcat, Wcrf, P);
        hipLaunchKernelGGL(kCr, dim3(256), dim3(256), 0, stream, P, bcrf, out);
    } else {
        unsigned short* aware = (unsigned short*)d_ws;
        unsigned short* x2    = aware + (size_t)NM * NH;

        hipLaunchKernelGGL(kA2, dim3(NH / 128, NM / 128), dim3(256), 0, stream, attn, bio, aware);
        hipLaunchKernelGGL(kB, dim3((NH / 128) * (NM / 128)), dim3(256), 0, stream,
                           h, aware, Wcat, bcat, x2);
        hipLaunchKernelGGL(kC, dim3(NM / 128), dim3(256), 0, stream, x2, Wcrf, bcrf, out);
    }

    hipLaunchKernelGGL(kD, dim3(NB), dim3(256), 0, stream, out, labels, token_nums, trans,
                       out + (size_t)NM * NLP);
}

// Round 11
// 262.664 us; speedup vs baseline: 14.3670x; 1.0424x over previous
//
#include <hip/hip_runtime.h>
#include <hip/hip_bf16.h>
#include <math.h>

#define NB 32
#define NS 512
#define NH 1024
#define NT 37
#define NLP 39
#define NM (NB*NS)   // 16384

typedef __attribute__((ext_vector_type(8))) short bf16x8;
typedef __attribute__((ext_vector_type(4))) float f32x4;

__device__ __forceinline__ float bf2f(unsigned int u) {
    unsigned int x = u << 16;
    float f;
    __builtin_memcpy(&f, &x, 4);
    return f;
}
__device__ __forceinline__ unsigned short f2bf(float f) {
    __hip_bfloat16 hb = __float2bfloat16(f);
    unsigned short u;
    __builtin_memcpy(&u, &hb, 2);
    return u;
}
__device__ __forceinline__ unsigned int pk2(float lo, float hi) {
    return ((unsigned int)f2bf(hi) << 16) | (unsigned int)f2bf(lo);
}
// bijective XOR swizzle for [row][64B] bf16 LDS tiles
__device__ __forceinline__ int SW64(int b)  { return b ^ ((b >> 2) & 0x70); }
// tile swizzle for [128/256 row][64 k] bf16 tiles (row stride 128B)
__device__ __forceinline__ int TSW(int row, int kcolByte) {
    return (row * 128 + kcolByte) ^ ((row & 7) << 4);
}
__device__ __forceinline__ float rl(float x, int l) {
    return __int_as_float(__builtin_amdgcn_readlane(__float_as_int(x), l));
}
__device__ __forceinline__ void gld16(const void* g, void* l) {
    __builtin_amdgcn_global_load_lds((const __attribute__((address_space(1))) void*)g,
                                     (__attribute__((address_space(3))) void*)l, 16, 0, 0);
}
#define VMW(N) asm volatile("s_waitcnt vmcnt(" #N ")" ::: "memory")
#define BARR() do { __builtin_amdgcn_s_barrier(); __builtin_amdgcn_sched_barrier(0); } while (0)

// ---------------------------------------------------------------------------
// Kernel A1 (v2): scores = h@bio^T /32 -> softmax -> attn (bf16 [NM][64]).
// bio staged ONCE in 96KB LDS (bf16, XOR-swizzled, rows 37-47 zero); K-loop is
// barrier-free with A-fragments direct from global (dist-1 prefetch).
// 128 rows/block, 512 threads (8 waves, wave = 16 rows).
// ---------------------------------------------------------------------------
__global__ __launch_bounds__(512) void kA1(const float* __restrict__ h,
                                           const float* __restrict__ bio,
                                           unsigned short* __restrict__ attn) {
    __shared__ __align__(16) char Bl[48 * 2048];   // 96KB: [t][1024k] bf16, ^(t&7)<<4

    const int tid  = threadIdx.x;
    const int lane = tid & 63;
    const int wid  = tid >> 6;
    const int lr   = lane & 15;
    const int lk   = lane >> 4;
    const int m0   = blockIdx.x * 128;

    // stage bio rows 0..36 (coalesced float4 -> bf16 uint2)
    for (int idx = tid; idx < 37 * 256; idx += 512) {
        int t = idx >> 8, k4 = idx & 255;
        float4 v = *(const float4*)&bio[(size_t)t * NH + k4 * 4];
        int byte = (t * 2048 + k4 * 8) ^ ((t & 7) << 4);
        *(uint2*)(Bl + byte) = make_uint2(pk2(v.x, v.y), pk2(v.z, v.w));
    }
    // zero rows 37..47
    for (int idx = tid; idx < 11 * 256; idx += 512) {
        int t = 37 + (idx >> 8), k4 = idx & 255;
        int byte = (t * 2048 + k4 * 8) ^ ((t & 7) << 4);
        *(uint2*)(Bl + byte) = make_uint2(0, 0);
    }
    __syncthreads();

    const int arow = m0 + wid * 16 + lr;
    const float* hp = h + (size_t)arow * NH + lk * 8;

    f32x4 sacc[3];
#pragma unroll
    for (int j = 0; j < 3; ++j) sacc[j] = (f32x4){0.f, 0.f, 0.f, 0.f};

    float4 p0 = *(const float4*)(hp);
    float4 p1 = *(const float4*)(hp + 4);
    for (int kt = 0; kt < NH; kt += 32) {
        float4 c0 = p0, c1 = p1;
        if (kt + 32 < NH) {
            p0 = *(const float4*)(hp + kt + 32);
            p1 = *(const float4*)(hp + kt + 36);
        }
        union { unsigned int u[4]; bf16x8 v; } af;
        af.u[0] = pk2(c0.x, c0.y); af.u[1] = pk2(c0.z, c0.w);
        af.u[2] = pk2(c1.x, c1.y); af.u[3] = pk2(c1.z, c1.w);
#pragma unroll
        for (int nf = 0; nf < 3; ++nf) {
            int t = nf * 16 + lr;
            int byte = (t * 2048 + (kt + lk * 8) * 2) ^ ((t & 7) << 4);
            bf16x8 bf = *(const bf16x8*)(Bl + byte);
            sacc[nf] = __builtin_amdgcn_mfma_f32_16x16x32_bf16(af.v, bf, sacc[nf], 0, 0, 0);
        }
    }

#pragma unroll
    for (int r = 0; r < 4; ++r) {
        const int orow = wid * 16 + lk * 4 + r;
        float s0 = sacc[0][r] * 0.03125f;
        float s1 = sacc[1][r] * 0.03125f;
        float s2 = sacc[2][r] * 0.03125f;
        const bool v2 = (lr < 5);
        float mx = fmaxf(fmaxf(s0, s1), v2 ? s2 : -1e30f);
#pragma unroll
        for (int d = 1; d < 16; d <<= 1) mx = fmaxf(mx, __shfl_xor(mx, d, 64));
        float e0 = __expf(s0 - mx), e1 = __expf(s1 - mx);
        float e2 = v2 ? __expf(s2 - mx) : 0.f;
        float sm = e0 + e1 + e2;
#pragma unroll
        for (int d = 1; d < 16; d <<= 1) sm += __shfl_xor(sm, d, 64);
        float inv = 1.f / sm;
        size_t g = (size_t)(m0 + orow) * 64;
        attn[g + lr]      = f2bf(e0 * inv);
        attn[g + 16 + lr] = f2bf(e1 * inv);
        attn[g + 32 + lr] = f2bf(e2 * inv);
        attn[g + 48 + lr] = 0;
    }
}

// ---------------------------------------------------------------------------
// Kernel A2 (fallback): aware = attn @ bio, plain bf16 row-major out.
// ---------------------------------------------------------------------------
__global__ __launch_bounds__(256) void kA2(const unsigned short* __restrict__ attn,
                                           const float* __restrict__ bio,
                                           unsigned short* __restrict__ aware) {
    __shared__ __align__(16) char Bsl[128 * 64];

    const int tid  = threadIdx.x;
    const int lane = tid & 63;
    const int wid  = tid >> 6;
    const int wm   = (wid >> 1) * 64;
    const int wn   = (wid & 1) * 64;
    const int lr   = lane & 15;
    const int lk   = lane >> 4;
    const int n0   = blockIdx.x * 128;
    const int m0   = blockIdx.y * 128;

    const int bn = tid & 127;
    const int bq = (tid >> 7) * 16;

    f32x4 acc[4][4];
#pragma unroll
    for (int i = 0; i < 4; ++i)
#pragma unroll
        for (int j = 0; j < 4; ++j) acc[i][j] = (f32x4){0.f, 0.f, 0.f, 0.f};

#pragma unroll
    for (int ks = 0; ks < 2; ++ks) {
        unsigned int p[8];
#pragma unroll
        for (int i = 0; i < 8; ++i) {
            int t0 = ks*32 + bq + 2*i;
            float lo = (t0     < NT) ? bio[(size_t)t0 * NH + n0 + bn]       : 0.f;
            float hi = (t0 + 1 < NT) ? bio[(size_t)(t0+1) * NH + n0 + bn]   : 0.f;
            p[i] = pk2(lo, hi);
        }
        __syncthreads();
        *(int4*)(Bsl + SW64(bn*64 + bq*2))      = make_int4(p[0], p[1], p[2], p[3]);
        *(int4*)(Bsl + SW64(bn*64 + bq*2 + 16)) = make_int4(p[4], p[5], p[6], p[7]);
        __syncthreads();

        bf16x8 af[4];
#pragma unroll
        for (int mf = 0; mf < 4; ++mf)
            af[mf] = *(const bf16x8*)(attn + (size_t)(m0 + wm + mf*16 + lr) * 64 + ks*32 + lk*8);
#pragma unroll
        for (int nf = 0; nf < 4; ++nf) {
            bf16x8 bb = *(const bf16x8*)(Bsl + SW64((wn + nf*16 + lr)*64 + lk*16));
#pragma unroll
            for (int mf = 0; mf < 4; ++mf)
                acc[mf][nf] = __builtin_amdgcn_mfma_f32_16x16x32_bf16(af[mf], bb, acc[mf][nf], 0, 0, 0);
        }
    }

#pragma unroll
    for (int mf = 0; mf < 4; ++mf)
#pragma unroll
        for (int nf = 0; nf < 4; ++nf)
#pragma unroll
            for (int r = 0; r < 4; ++r) {
                size_t row = (size_t)(m0 + wm + mf*16 + lk*4 + r);
                aware[row * NH + n0 + wn + nf*16 + lr] = f2bf(acc[mf][nf][r]);
            }
}

// ---------------------------------------------------------------------------
// Kernel A2f (fast): computes aware chunk AND writes the full concat-A
// [h | aware | h*aware] in bf16, tile-major (128x64 tiles) with TSW swizzle.
// ---------------------------------------------------------------------------
__global__ __launch_bounds__(256) void kA2f(const unsigned short* __restrict__ attn,
                                            const float* __restrict__ bio,
                                            const float* __restrict__ h,
                                            char* __restrict__ Asw) {
    __shared__ __align__(16) char Bsl[128 * 64];
    __shared__ __align__(16) unsigned short awL[128 * 128];  // 32KB aware chunk

    const int tid  = threadIdx.x;
    const int lane = tid & 63;
    const int wid  = tid >> 6;
    const int wm   = (wid >> 1) * 64;
    const int wn   = (wid & 1) * 64;
    const int lr   = lane & 15;
    const int lk   = lane >> 4;
    const int n0   = blockIdx.x * 128;
    const int m0   = blockIdx.y * 128;
    const int tm   = blockIdx.y;

    const int bn = tid & 127;
    const int bq = (tid >> 7) * 16;

    f32x4 acc[4][4];
#pragma unroll
    for (int i = 0; i < 4; ++i)
#pragma unroll
        for (int j = 0; j < 4; ++j) acc[i][j] = (f32x4){0.f, 0.f, 0.f, 0.f};

#pragma unroll
    for (int ks = 0; ks < 2; ++ks) {
        unsigned int p[8];
#pragma unroll
        for (int i = 0; i < 8; ++i) {
            int t0 = ks*32 + bq + 2*i;
            float lo = (t0     < NT) ? bio[(size_t)t0 * NH + n0 + bn]       : 0.f;
            float hi = (t0 + 1 < NT) ? bio[(size_t)(t0+1) * NH + n0 + bn]   : 0.f;
            p[i] = pk2(lo, hi);
        }
        __syncthreads();
        *(int4*)(Bsl + SW64(bn*64 + bq*2))      = make_int4(p[0], p[1], p[2], p[3]);
        *(int4*)(Bsl + SW64(bn*64 + bq*2 + 16)) = make_int4(p[4], p[5], p[6], p[7]);
        __syncthreads();

        bf16x8 af[4];
#pragma unroll
        for (int mf = 0; mf < 4; ++mf)
            af[mf] = *(const bf16x8*)(attn + (size_t)(m0 + wm + mf*16 + lr) * 64 + ks*32 + lk*8);
#pragma unroll
        for (int nf = 0; nf < 4; ++nf) {
            bf16x8 bb = *(const bf16x8*)(Bsl + SW64((wn + nf*16 + lr)*64 + lk*16));
#pragma unroll
            for (int mf = 0; mf < 4; ++mf)
                acc[mf][nf] = __builtin_amdgcn_mfma_f32_16x16x32_bf16(af[mf], bb, acc[mf][nf], 0, 0, 0);
        }
    }

#pragma unroll
    for (int mf = 0; mf < 4; ++mf)
#pragma unroll
        for (int nf = 0; nf < 4; ++nf)
#pragma unroll
            for (int r = 0; r < 4; ++r)
                awL[(wm + mf*16 + lk*4 + r) * 128 + wn + nf*16 + lr] = f2bf(acc[mf][nf][r]);
    __syncthreads();

    // region 1 (aware)
#pragma unroll
    for (int i = 0; i < 8; ++i) {
        int lin = tid + i * 256;
        int row = lin >> 4, kg = lin & 15;
        uint4 v = *(const uint4*)&awL[row * 128 + kg * 8];
        int kglob = 1024 + n0 + kg * 8;
        size_t tbase = ((size_t)tm * 48 + (kglob >> 6)) * 16384;
        *(uint4*)(Asw + tbase + TSW(row, (kglob & 63) * 2)) = v;
    }
    // regions 0 (h) and 2 (h*aware)
#pragma unroll
    for (int i = 0; i < 8; ++i) {
        int lin = tid + i * 256;
        int row = lin >> 4, kg = lin & 15;
        const float4* hp = (const float4*)&h[(size_t)(m0 + row) * NH + n0 + kg * 8];
        float4 ha = hp[0], hb = hp[1];
        float hv[8] = {ha.x, ha.y, ha.z, ha.w, hb.x, hb.y, hb.z, hb.w};
        uint4 awv = *(const uint4*)&awL[row * 128 + kg * 8];
        unsigned int awu[4] = {awv.x, awv.y, awv.z, awv.w};
        unsigned int p0[4], p2[4];
#pragma unroll
        for (int j = 0; j < 4; ++j) {
            p0[j] = pk2(hv[2*j], hv[2*j+1]);
            float lo = hv[2*j]   * bf2f(awu[j] & 0xffffu);
            float hi = hv[2*j+1] * bf2f(awu[j] >> 16);
            p2[j] = pk2(lo, hi);
        }
        int k0g = n0 + kg * 8;
        size_t tb0 = ((size_t)tm * 48 + (k0g >> 6)) * 16384;
        *(uint4*)(Asw + tb0 + TSW(row, (k0g & 63) * 2)) = make_uint4(p0[0], p0[1], p0[2], p0[3]);
        int k2g = 2048 + n0 + kg * 8;
        size_t tb2 = ((size_t)tm * 48 + (k2g >> 6)) * 16384;
        *(uint4*)(Asw + tb2 + TSW(row, (k2g & 63) * 2)) = make_uint4(p2[0], p2[1], p2[2], p2[3]);
    }
}

// ---------------------------------------------------------------------------
// Kernel W: WbT swizzled tiles: W^T[n][k] bf16, tile (tn,tk) = [128 n][64 k].
// ---------------------------------------------------------------------------
__global__ __launch_bounds__(256) void kW(const float* __restrict__ Wcat,
                                          char* __restrict__ Wsw) {
    __shared__ unsigned short wt[64 * 128];

    const int tid  = threadIdx.x;
    const int tile = blockIdx.x;
    const int tn   = tile / 48;
    const int tk   = tile - tn * 48;
    const int n00  = tn * 128;
    const int k0   = tk * 64;

#pragma unroll
    for (int i = 0; i < 8; ++i) {
        int lin = tid + i * 256;
        int kk = lin >> 5, ng = lin & 31;
        float4 v = *(const float4*)&Wcat[(size_t)(k0 + kk) * NH + n00 + ng * 4];
        unsigned int lo = pk2(v.x, v.y), hi = pk2(v.z, v.w);
        *(uint2*)&wt[kk * 128 + ng * 4] = make_uint2(lo, hi);
    }
    __syncthreads();
#pragma unroll
    for (int i = 0; i < 4; ++i) {
        int lin = tid + i * 256;
        int rn = lin >> 3, kg = lin & 7;
        unsigned short t8[8];
#pragma unroll
        for (int j = 0; j < 8; ++j) t8[j] = wt[(kg * 8 + j) * 128 + rn];
        uint4 v = *(const uint4*)t8;
        *(uint4*)(Wsw + (size_t)tile * 16384 + TSW(rn, kg * 16)) = v;
    }
}

// ---------------------------------------------------------------------------
// Kernel W2: prepack Wcrf^T as bf16 [48][3072] (t-major, k contiguous),
// rows t>=37 zeroed — fragment-order for kBf's fused epilogue.
// ---------------------------------------------------------------------------
__global__ __launch_bounds__(256) void kW2(const float* __restrict__ Wcrf,
                                           unsigned short* __restrict__ WT) {
    const int idx = blockIdx.x * 256 + threadIdx.x;   // 48*384 = 18432
    if (idx >= 48 * 384) return;
    const int t = idx / 384, kg = idx - t * 384;
    unsigned short v[8];
#pragma unroll
    for (int e = 0; e < 8; ++e) {
        int k = kg * 8 + e;
        v[e] = (t < NT) ? f2bf(Wcrf[(size_t)k * NT + t]) : (unsigned short)0;
    }
    uint4 w;
    __builtin_memcpy(&w, v, 16);
    *(uint4*)(WT + (size_t)t * 3072 + kg * 8) = w;
}

// ---------------------------------------------------------------------------
// Kernel Bf (fast): 256x256 tile bf16 GEMM, BK=64, 8 waves, counted-vmcnt
// 4-phase schedule (proven 101us) + fused kC epilogue (prepacked Wcrf^T).
// ---------------------------------------------------------------------------
__global__ __launch_bounds__(512, 2) void kBf(const char* __restrict__ Asw,
                                              const char* __restrict__ Wsw,
                                              const float* __restrict__ bcat,
                                              const unsigned short* __restrict__ WT,
                                              float* __restrict__ P) {
    __shared__ __align__(16) char lds[131072];  // A: buf*32768+h*16384; B at +65536

    const int tid  = threadIdx.x;
    const int lane = tid & 63;
    const int wid  = tid >> 6;
    const int widm = wid >> 2;       // 0..1
    const int widn = wid & 3;        // 0..3
    const int lr   = lane & 15;
    const int lk   = lane >> 4;

    const int id   = blockIdx.x;     // 256 blocks
    const int xcd  = id & 7;
    const int slot = id >> 3;        // 0..31
    const int Mt   = xcd * 8 + (slot >> 2);
    const int Nt   = slot & 3;
    const int m0   = Mt * 256, n0 = Nt * 256;
    const int soff = tid * 16;

    f32x4 acc00[4][2], acc01[4][2], acc10[4][2], acc11[4][2];
#pragma unroll
    for (int i = 0; i < 4; ++i)
#pragma unroll
        for (int j = 0; j < 2; ++j) {
            acc00[i][j] = (f32x4){0.f,0.f,0.f,0.f};
            acc01[i][j] = (f32x4){0.f,0.f,0.f,0.f};
            acc10[i][j] = (f32x4){0.f,0.f,0.f,0.f};
            acc11[i][j] = (f32x4){0.f,0.f,0.f,0.f};
        }

    auto stageHalf = [&](int T, int ph) {
        const bool isA = (ph == 0) || (ph == 3);
        const int  h   = isA ? (ph == 3 ? 1 : 0) : (ph - 1);
        const char* src = isA
            ? Asw + ((size_t)((2*Mt + h) * 48 + T)) * 16384
            : Wsw + ((size_t)((2*Nt + h) * 48 + T)) * 16384;
        char* dst = lds + (isA ? 0 : 65536) + (T & 1) * 32768 + h * 16384;
        gld16(src + soff,        dst + soff);
        gld16(src + soff + 8192, dst + soff + 8192);
    };
    auto loadA = [&](bf16x8 (&af)[4][2], int q, int half) {
        const char* base = lds + q * 32768 + half * 16384;
#pragma unroll
        for (int i = 0; i < 4; ++i) {
            int row = widm * 64 + i * 16 + lr;
#pragma unroll
            for (int kk = 0; kk < 2; ++kk)
                af[i][kk] = *(const bf16x8*)(base + TSW(row, kk * 64 + lk * 16));
        }
    };
    auto loadB = [&](bf16x8 (&bfr)[2][2], int q, int half) {
        const char* base = lds + 65536 + q * 32768 + half * 16384;
#pragma unroll
        for (int j = 0; j < 2; ++j) {
            int col = widn * 32 + j * 16 + lr;
#pragma unroll
            for (int kk = 0; kk < 2; ++kk)
                bfr[j][kk] = *(const bf16x8*)(base + TSW(col, kk * 64 + lk * 16));
        }
    };
    auto mma = [&](f32x4 (&ac)[4][2], bf16x8 (&af)[4][2], bf16x8 (&bfr)[2][2]) {
        __builtin_amdgcn_s_setprio(1);
#pragma unroll
        for (int kk = 0; kk < 2; ++kk)
#pragma unroll
            for (int i = 0; i < 4; ++i)
#pragma unroll
                for (int j = 0; j < 2; ++j)
                    ac[i][j] = __builtin_amdgcn_mfma_f32_16x16x32_bf16(
                        af[i][kk], bfr[j][kk], ac[i][j], 0, 0, 0);
        __builtin_amdgcn_s_setprio(0);
    };

    stageHalf(0, 0); stageHalf(0, 1); stageHalf(0, 2); stageHalf(0, 3);
    VMW(0);
    BARR();

    for (int T = 0; T < 47; ++T) {
        const int q = T & 1;
        bf16x8 af0[4][2], af1[4][2], bf0[2][2], bf1[2][2];
        stageHalf(T + 1, 0);
        VMW(6);
        BARR();
        loadA(af0, q, 0); loadB(bf0, q, 0);
        mma(acc00, af0, bf0);
        stageHalf(T + 1, 1);
        VMW(6);
        BARR();
        loadB(bf1, q, 1);
        mma(acc01, af0, bf1);
        stageHalf(T + 1, 2);
        VMW(6);
        BARR();
        loadA(af1, q, 1);
        mma(acc10, af1, bf0);
        stageHalf(T + 1, 3);
        BARR();
        mma(acc11, af1, bf1);
    }
    {   // T = 47 (buf 1), tail waits 4/2/0
        const int q = 1;
        bf16x8 af0[4][2], af1[4][2], bf0[2][2], bf1[2][2];
        VMW(4);
        BARR();
        loadA(af0, q, 0); loadB(bf0, q, 0);
        mma(acc00, af0, bf0);
        VMW(2);
        BARR();
        loadB(bf1, q, 1);
        mma(acc01, af0, bf1);
        VMW(0);
        BARR();
        loadA(af1, q, 1);
        mma(acc10, af1, bf0);
        BARR();
        mma(acc11, af1, bf1);
    }

    // ---------------- fused kC epilogue ----------------
    __syncthreads();
    auto stashQ = [&](f32x4 (&ac)[4][2], int a, int b) {
#pragma unroll
        for (int j = 0; j < 2; ++j) {
            const int lcol = b * 128 + widn * 32 + j * 16 + lr;
            const int kc = lcol >> 6, kk = lcol & 63;
            const float bc = bcat[n0 + lcol];
#pragma unroll
            for (int i = 0; i < 4; ++i)
#pragma unroll
                for (int r = 0; r < 4; ++r) {
                    int lrow = a * 128 + widm * 64 + i * 16 + lk * 4 + r;
                    float x = ac[i][j][r] + bc;
                    float g = 0.5f * x * (1.0f + erff(x * 0.70710678118654752f));
                    *(unsigned short*)(lds + kc * 32768 + TSW(lrow, kk * 2)) = f2bf(g);
                }
        }
    };
    stashQ(acc00, 0, 0); stashQ(acc01, 0, 1); stashQ(acc10, 1, 0); stashQ(acc11, 1, 1);
    __syncthreads();

    // Wcrf^T fragments from prepacked bf16 buffer (24 vector loads)
    bf16x8 wfrag[3][8];
#pragma unroll
    for (int tt = 0; tt < 3; ++tt) {
        const int t = tt * 16 + lr;
#pragma unroll
        for (int ks = 0; ks < 8; ++ks)
            wfrag[tt][ks] = *(const bf16x8*)(WT + (size_t)t * 3072 + n0 + ks * 32 + lk * 8);
    }

    f32x4 pacc[2][3];
#pragma unroll
    for (int i = 0; i < 2; ++i)
#pragma unroll
        for (int j = 0; j < 3; ++j) pacc[i][j] = (f32x4){0.f, 0.f, 0.f, 0.f};
#pragma unroll
    for (int rt2 = 0; rt2 < 2; ++rt2) {
        const int lrow = wid * 32 + rt2 * 16 + lr;
#pragma unroll
        for (int ks = 0; ks < 8; ++ks) {
            const int kc = ks >> 1, kh = ks & 1;
            bf16x8 af = *(const bf16x8*)(lds + kc * 32768 + TSW(lrow, kh * 64 + lk * 16));
#pragma unroll
            for (int tt = 0; tt < 3; ++tt)
                pacc[rt2][tt] = __builtin_amdgcn_mfma_f32_16x16x32_bf16(
                    af, wfrag[tt][ks], pacc[rt2][tt], 0, 0, 0);
        }
    }

    float* Pb = P + (size_t)Nt * NM * 48;
#pragma unroll
    for (int rt2 = 0; rt2 < 2; ++rt2)
#pragma unroll
        for (int tt = 0; tt < 3; ++tt)
#pragma unroll
            for (int r = 0; r < 4; ++r) {
                int row = Mt * 256 + wid * 32 + rt2 * 16 + lk * 4 + r;
                Pb[(size_t)row * 48 + tt * 16 + lr] = pacc[rt2][tt][r];
            }
}

// ---------------------------------------------------------------------------
// Kernel Cr: out = sum_Nt P[Nt] + b_crf, pads -10000.
// ---------------------------------------------------------------------------
__global__ __launch_bounds__(256) void kCr(const float* __restrict__ P,
                                           const float* __restrict__ bcrf,
                                           float* __restrict__ out) {
    const int g = blockIdx.x * 256 + threadIdx.x;
    const size_t STRIDE = (size_t)NM * 48;
#pragma unroll
    for (int s = 0; s < 12; ++s) {
        int flat = g * 12 + s;
        int row = flat / 48, t = flat - row * 48;
        float v = P[flat] + P[STRIDE + flat] + P[2*STRIDE + flat] + P[3*STRIDE + flat];
        if (t < NT)       out[(size_t)row * NLP + t] = v + bcrf[t];
        else if (t < NLP) out[(size_t)row * NLP + t] = -10000.0f;
    }
}

// ---------------------------------------------------------------------------
// Kernel B (fallback): reg-staged mixed GEMM (round-4 version).
// ---------------------------------------------------------------------------
__global__ __launch_bounds__(256) void kB(const float* __restrict__ h,
                                          const unsigned short* __restrict__ aware,
                                          const float* __restrict__ Wcat,
                                          const float* __restrict__ bcat,
                                          unsigned short* __restrict__ x2) {
    __shared__ __align__(16) char lds[16384];
    char* Asl = lds;
    char* Bsl = lds + 8192;

    const int tid  = threadIdx.x;
    const int lane = tid & 63;
    const int wid  = tid >> 6;
    const int wm   = (wid >> 1) * 64;
    const int wn   = (wid & 1) * 64;
    const int lr   = lane & 15;
    const int lk   = lane >> 4;

    const int id   = blockIdx.x;
    const int xcd  = id & 7;
    const int slot = id >> 3;
    const int m0   = (xcd * 16 + (slot >> 3)) * 128;
    const int n0   = (slot & 7) * 128;

    const int am = tid >> 1;
    const int ak = (tid & 1) * 16;
    const int bn = tid & 127;
    const int bk = (tid >> 7) * 16;

    f32x4 acc[4][4];
#pragma unroll
    for (int i = 0; i < 4; ++i)
#pragma unroll
        for (int j = 0; j < 4; ++j) acc[i][j] = (f32x4){0.f, 0.f, 0.f, 0.f};

    const float*          hrow = h     + (size_t)(m0 + am) * NH + ak;
    const unsigned short* arow = aware + (size_t)(m0 + am) * NH + ak;
    const float*          wcol = Wcat  + (size_t)bk * NH + n0 + bn;

    float hv[16];
    unsigned int aw[8];
    float wv[16];

    auto stage = [&](int kt) {
        const int region = kt >> 10;
        const int kb = kt & 1023;
        if (region != 1) {
            const float4* hp = (const float4*)(hrow + kb);
            float4 a = hp[0], b = hp[1], c = hp[2], d = hp[3];
            hv[0]=a.x; hv[1]=a.y; hv[2]=a.z; hv[3]=a.w;
            hv[4]=b.x; hv[5]=b.y; hv[6]=b.z; hv[7]=b.w;
            hv[8]=c.x; hv[9]=c.y; hv[10]=c.z; hv[11]=c.w;
            hv[12]=d.x; hv[13]=d.y; hv[14]=d.z; hv[15]=d.w;
        }
        if (region >= 1) {
            const uint4* ap = (const uint4*)(arow + kb);
            uint4 a0 = ap[0], a1 = ap[1];
            aw[0]=a0.x; aw[1]=a0.y; aw[2]=a0.z; aw[3]=a0.w;
            aw[4]=a1.x; aw[5]=a1.y; aw[6]=a1.z; aw[7]=a1.w;
        }
        {
            const float* wp = wcol + (size_t)kt * NH;
#pragma unroll
            for (int j = 0; j < 16; ++j) wv[j] = wp[(size_t)j * NH];
        }
    };

    auto writeStage = [&](int kt) {
        const int region = kt >> 10;
        unsigned int p[8];
        if (region == 0) {
#pragma unroll
            for (int i = 0; i < 8; ++i) p[i] = pk2(hv[2*i], hv[2*i+1]);
        } else if (region == 1) {
#pragma unroll
            for (int i = 0; i < 8; ++i) p[i] = aw[i];
        } else {
#pragma unroll
            for (int i = 0; i < 8; ++i) {
                float lo = hv[2*i]   * bf2f(aw[i] & 0xffffu);
                float hi = hv[2*i+1] * bf2f(aw[i] >> 16);
                p[i] = pk2(lo, hi);
            }
        }
        *(int4*)(Asl + SW64(am*64 + ak*2))      = make_int4(p[0], p[1], p[2], p[3]);
        *(int4*)(Asl + SW64(am*64 + ak*2 + 16)) = make_int4(p[4], p[5], p[6], p[7]);
        unsigned int q[8];
#pragma unroll
        for (int i = 0; i < 8; ++i) q[i] = pk2(wv[2*i], wv[2*i+1]);
        *(int4*)(Bsl + SW64(bn*64 + bk*2))      = make_int4(q[0], q[1], q[2], q[3]);
        *(int4*)(Bsl + SW64(bn*64 + bk*2 + 16)) = make_int4(q[4], q[5], q[6], q[7]);
    };

    stage(0);
    for (int kt = 0; kt < 3072; kt += 32) {
        __syncthreads();
        writeStage(kt);
        __syncthreads();
        if (kt + 32 < 3072) stage(kt + 32);

        bf16x8 af[4], bfr[4];
#pragma unroll
        for (int mf = 0; mf < 4; ++mf)
            af[mf] = *(const bf16x8*)(Asl + SW64((wm + mf*16 + lr)*64 + lk*16));
#pragma unroll
        for (int nf = 0; nf < 4; ++nf)
            bfr[nf] = *(const bf16x8*)(Bsl + SW64((wn + nf*16 + lr)*64 + lk*16));
#pragma unroll
        for (int mf = 0; mf < 4; ++mf)
#pragma unroll
            for (int nf = 0; nf < 4; ++nf)
                acc[mf][nf] = __builtin_amdgcn_mfma_f32_16x16x32_bf16(af[mf], bfr[nf], acc[mf][nf], 0, 0, 0);
    }

#pragma unroll
    for (int nf = 0; nf < 4; ++nf) {
        const int col = n0 + wn + nf*16 + lr;
        const float bc = bcat[col];
#pragma unroll
        for (int mf = 0; mf < 4; ++mf)
#pragma unroll
            for (int r = 0; r < 4; ++r) {
                size_t row = (size_t)(m0 + wm + mf*16 + lk*4 + r);
                float x = acc[mf][nf][r] + bc;
                float g = 0.5f * x * (1.0f + erff(x * 0.70710678118654752f));
                x2[row * NH + col] = f2bf(g);
            }
    }
}

// ---------------------------------------------------------------------------
// Kernel C (fallback): ner_scores = [x2 @ W_crf + b_crf, -10000, -10000]
// ---------------------------------------------------------------------------
__global__ __launch_bounds__(256) void kC(const unsigned short* __restrict__ x2,
                                          const float* __restrict__ Wcrf,
                                          const float* __restrict__ bcrf,
                                          float* __restrict__ out) {
    __shared__ __align__(16) char Asl[8192];
    __shared__ __align__(16) char Bsl[3072];

    const int tid  = threadIdx.x;
    const int lane = tid & 63;
    const int wid  = tid >> 6;
    const int lr   = lane & 15;
    const int lk   = lane >> 4;
    const int m0   = blockIdx.x * 128;
    const int am   = tid >> 1;
    const int ak   = (tid & 1) * 16;

    for (int i = tid; i < 192; i += 256) *(int4*)(Bsl + i*16) = make_int4(0, 0, 0, 0);

    f32x4 acc[2][3];
#pragma unroll
    for (int i = 0; i < 2; ++i)
#pragma unroll
        for (int j = 0; j < 3; ++j) acc[i][j] = (f32x4){0.f, 0.f, 0.f, 0.f};

    const unsigned short* xrow = x2 + (size_t)(m0 + am) * NH + ak;

    for (int kt = 0; kt < NH; kt += 32) {
        const uint4* xp = (const uint4*)(xrow + kt);
        uint4 x0 = xp[0], x1 = xp[1];
        float wv[5];
#pragma unroll
        for (int p = 0; p < 5; ++p) {
            int i = tid + p * 256;
            wv[p] = (i < 32*NT) ? Wcrf[(size_t)kt * NT + i] : 0.f;
        }
        __syncthreads();
        *(uint4*)(Asl + SW64(am*64 + ak*2))      = x0;
        *(uint4*)(Asl + SW64(am*64 + ak*2 + 16)) = x1;
#pragma unroll
        for (int p = 0; p < 5; ++p) {
            int i = tid + p * 256;
            if (i < 32*NT) {
                int kk = i / NT;
                int t  = i - kk * NT;
                *(unsigned short*)(Bsl + SW64(t*64 + kk*2)) = f2bf(wv[p]);
            }
        }
        __syncthreads();
        bf16x8 af[2], bfr[3];
#pragma unroll
        for (int mf = 0; mf < 2; ++mf)
            af[mf] = *(const bf16x8*)(Asl + SW64((wid*32 + mf*16 + lr)*64 + lk*16));
#pragma unroll
        for (int nf = 0; nf < 3; ++nf)
            bfr[nf] = *(const bf16x8*)(Bsl + SW64((nf*16 + lr)*64 + lk*16));
#pragma unroll
        for (int mf = 0; mf < 2; ++mf)
#pragma unroll
            for (int nf = 0; nf < 3; ++nf)
                acc[mf][nf] = __builtin_amdgcn_mfma_f32_16x16x32_bf16(af[mf], bfr[nf], acc[mf][nf], 0, 0, 0);
    }

#pragma unroll
    for (int nf = 0; nf < 3; ++nf) {
        const int t = nf*16 + lr;
        const float bc = (t < NT) ? bcrf[t] : 0.f;
#pragma unroll
        for (int mf = 0; mf < 2; ++mf)
#pragma unroll
            for (int r = 0; r < 4; ++r) {
                size_t row = (size_t)(m0 + wid*32 + mf*16 + lk*4 + r);
                if (t < NT)       out[row * NLP + t] = acc[mf][nf][r] + bc;
                else if (t < NLP) out[row * NLP + t] = -10000.0f;
            }
    }
}

// ---------------------------------------------------------------------------
// Kernel D: CRF log-likelihood, exp-domain scan, scores staged in LDS.
// CRFSTEP batches all 37 readlanes BEFORE the fma chains (avoids per-pair
// VALU->SGPR->VALU hazard serialization), pinned with sched_barrier.
// ---------------------------------------------------------------------------
#define CRFSTEP(EL) do {                                   \
    float as_[37];                                         \
    _Pragma("unroll")                                      \
    for (int f_ = 0; f_ < 37; ++f_) as_[f_] = rl(a, f_);   \
    __builtin_amdgcn_sched_barrier(0);                     \
    float c0 = 0.f, c1 = 0.f, c2 = 0.f, c3 = 0.f;          \
    _Pragma("unroll")                                      \
    for (int f_ = 0; f_ < 36; f_ += 4) {                   \
        c0 = fmaf(as_[f_    ], trow[f_    ], c0);          \
        c1 = fmaf(as_[f_ + 1], trow[f_ + 1], c1);          \
        c2 = fmaf(as_[f_ + 2], trow[f_ + 2], c2);          \
        c3 = fmaf(as_[f_ + 3], trow[f_ + 3], c3);          \
    }                                                      \
    c0 = fmaf(as_[36], trow[36], c0);                      \
    a = (EL) * ((c0 + c1) + (c2 + c3));                    \
} while (0)

__global__ __launch_bounds__(256) void kD(const float* __restrict__ scores,
                                          const int* __restrict__ labels,
                                          const int* __restrict__ lens,
                                          const float* __restrict__ trans,
                                          float* __restrict__ loss) {
    __shared__ float S[NS * NLP];      // 79872 B, packed [t][39]
    __shared__ float trL[39 * 41];     // 6396 B
    __shared__ int   labL[NS];         // 2048 B
    __shared__ float gred[4];

    const int b    = blockIdx.x;
    const int tid  = threadIdx.x;
    const int lane = tid & 63;
    const int wid  = tid >> 6;
    const int len  = lens[b];
    const float* sb = scores + (size_t)b * NS * NLP;

    {
        const int n4 = (len * NLP + 3) >> 2;   // only rows < len are ever read
        const float4* src = (const float4*)sb;
        float4* dst = (float4*)S;
        for (int i = tid; i < n4; i += 256) dst[i] = src[i];
    }
    for (int i = tid; i < NS; i += 256) labL[i] = labels[b * NS + i];
    for (int idx = tid; idx < 39 * 39; idx += 256) {
        int to = idx / 39, f = idx - to * 39;
        trL[to * 41 + f] = trans[idx];
    }
    __syncthreads();

    float g = 0.0f;
    for (int t = tid; t < len; t += 256) g += S[t * NLP + labL[t]];
    for (int i = tid; i <= len; i += 256) {
        int frm = (i == 0) ? 37 : labL[i - 1];
        int to  = (i == len) ? 38 : labL[i];
        g += trL[to * 41 + frm];
    }
#pragma unroll
    for (int off = 32; off > 0; off >>= 1) g += __shfl_xor(g, off, 64);
    if (lane == 0) gred[wid] = g;
    __syncthreads();

    if (wid != 0) return;

    const float gold = (gred[0] + gred[1]) + (gred[2] + gred[3]);

    const int myrow = (lane < 39) ? lane : 0;
    float trow[39];
#pragma unroll
    for (int f = 0; f < 39; ++f) trow[f] = __expf(trL[myrow * 41 + f]);
    const float trEnd = (lane < 39) ? trL[38 * 41 + lane] : 0.f;
    const bool act = (lane < 39);

    float l0 = act ? S[lane] : -10000.f;
    float a = act ? __expf(l0) * trow[37] : 0.f;
    float C = 0.0f;

    auto ldrow = [&](int r) {
        r = (r < len) ? r : (len - 1);
        return S[act ? (r * NLP + lane) : 0];
    };
    float lg0 = ldrow(1), lg1 = ldrow(2), lg2 = ldrow(3), lg3 = ldrow(4);

    int t = 1;
    for (; t + 3 < len; t += 4) {
        float e0 = __expf(lg0), e1 = __expf(lg1), e2 = __expf(lg2), e3 = __expf(lg3);
        lg0 = ldrow(t + 4); lg1 = ldrow(t + 5); lg2 = ldrow(t + 6); lg3 = ldrow(t + 7);
        CRFSTEP(e0); CRFSTEP(e1); CRFSTEP(e2); CRFSTEP(e3);
        float s = rl(a, 0);
        float rr = __builtin_amdgcn_rcpf(s);
        a *= rr; C -= __logf(rr);
    }
    for (; t < len; ++t) {
        float el = __expf(ldrow(t));
        CRFSTEP(el);
    }

    float aend = (act && a > 0.f) ? C + __logf(a) + trEnd : -1e30f;
    float mx = aend;
#pragma unroll
    for (int off = 32; off > 0; off >>= 1) mx = fmaxf(mx, __shfl_xor(mx, off, 64));
    float es = act ? __expf(aend - mx) : 0.0f;
#pragma unroll
    for (int off = 32; off > 0; off >>= 1) es += __shfl_xor(es, off, 64);
    float norm = mx + __logf(es);

    if (lane == 0) loss[b] = gold - norm;
}

// ---------------------------------------------------------------------------
extern "C" void kernel_launch(void* const* d_in, const int* in_sizes, int n_in,
                              void* d_out, int out_size, void* d_ws, size_t ws_size,
                              hipStream_t stream) {
    const float* h        = (const float*)d_in[0];
    const int* token_nums = (const int*)d_in[2];
    const int* labels     = (const int*)d_in[3];
    const float* bio      = (const float*)d_in[4];
    const float* Wcat     = (const float*)d_in[5];
    const float* bcat     = (const float*)d_in[6];
    const float* Wcrf     = (const float*)d_in[7];
    const float* bcrf     = (const float*)d_in[8];
    const float* trans    = (const float*)d_in[9];

    float* out = (float*)d_out;
    unsigned short* attn  = (unsigned short*)d_out;  // 2MB scratch, overwritten by kCr

    const size_t ASW_BYTES = (size_t)128 * 48 * 16384;        // 96 MB
    const size_t P_BYTES   = (size_t)4 * NM * 48 * 4;         // 12.6 MB
    const size_t WSW_BYTES = (size_t)8 * 48 * 16384;          // 6 MB
    const size_t WT_BYTES  = (size_t)48 * 3072 * 2;           // 288 KB
    const bool fast = ws_size >= ASW_BYTES + P_BYTES + WSW_BYTES + WT_BYTES;

    hipLaunchKernelGGL(kA1, dim3(NM / 128), dim3(512), 0, stream, h, bio, attn);

    if (fast) {
        char*  Asw = (char*)d_ws;
        float* P   = (float*)((char*)d_ws + ASW_BYTES);
        char*  Wsw = (char*)d_ws + ASW_BYTES + P_BYTES;
        unsigned short* WT = (unsigned short*)((char*)d_ws + ASW_BYTES + P_BYTES + WSW_BYTES);

        hipLaunchKernelGGL(kW, dim3(8 * 48), dim3(256), 0, stream, Wcat, Wsw);
        hipLaunchKernelGGL(kW2, dim3(72), dim3(256), 0, stream, Wcrf, WT);
        hipLaunchKernelGGL(kA2f, dim3(NH / 128, NM / 128), dim3(256), 0, stream,
                           attn, bio, h, Asw);
        hipLaunchKernelGGL(kBf, dim3(256), dim3(512), 0, stream, Asw, Wsw, bcat, WT, P);
        hipLaunchKernelGGL(kCr, dim3(256), dim3(256), 0, stream, P, bcrf, out);
    } else {
        unsigned short* aware = (unsigned short*)d_ws;
        unsigned short* x2    = aware + (size_t)NM * NH;

        hipLaunchKernelGGL(kA2, dim3(NH / 128, NM / 128), dim3(256), 0, stream, attn, bio, aware);
        hipLaunchKernelGGL(kB, dim3((NH / 128) * (NM / 128)), dim3(256), 0, stream,
                           h, aware, Wcat, bcat, x2);
        hipLaunchKernelGGL(kC, dim3(NM / 128), dim3(256), 0, stream, x2, Wcrf, bcrf, out);
    }

    hipLaunchKernelGGL(kD, dim3(NB), dim3(256), 0, stream, out, labels, token_nums, trans,
                       out + (size_t)NM * NLP);
}